// Round 14
// baseline (1074.453 us; speedup 1.0000x reference)
//
#include <hip/hip_runtime.h>
#include <hip/hip_bf16.h>
#include <cstddef>
#include <cstdint>

#define DEV __device__ __forceinline__

DEV float lrelu_f(float z){ return z >= 0.f ? z : 0.1f*z; }

typedef __bf16 bf16x8 __attribute__((ext_vector_type(8)));
typedef float  f32x4  __attribute__((ext_vector_type(4)));

DEV unsigned short bf_bits(float v){
    __hip_bfloat16 h = __float2bfloat16(v);
    unsigned short s; __builtin_memcpy(&s, &h, 2); return s;
}
DEV unsigned short bf_bits(__hip_bfloat16 v){
    unsigned short s; __builtin_memcpy(&s, &v, 2); return s;
}
DEV float bf_val(const char* p){
    unsigned short s = *(const unsigned short*)p;
    __hip_bfloat16 h; __builtin_memcpy(&h, &s, 2);
    return __bfloat162float(h);
}

// ---------------- K1: encoder conv1 (y -> e1), 3x3 s2 p1 + bias + BN + lrelu ----
__global__ __launch_bounds__(256) void k_enc1(
    const float* __restrict__ y, const float* __restrict__ w,
    const float* __restrict__ bias, const float* __restrict__ g,
    const float* __restrict__ bb, const float* __restrict__ m,
    const float* __restrict__ v, float* __restrict__ e1)
{
    int idx = blockIdx.x*256 + threadIdx.x;     // [4,128,32,32]
    int ow = idx & 31, oh = (idx>>5)&31, co = (idx>>10)&127, b = idx>>17;
    float acc = 0.f;
    const float* wp = w + co*576;
    const float* yb = y + (size_t)b*64*4096;
    for (int ci=0; ci<64; ++ci){
        const float* yp = yb + ci*4096;
        const float* wr = wp + ci*9;
        #pragma unroll
        for (int kh=0; kh<3; ++kh){
            int ih = oh*2 + kh - 1;
            if (ih < 0 || ih > 63) continue;
            #pragma unroll
            for (int kw=0; kw<3; ++kw){
                int iw = ow*2 + kw - 1;
                if (iw < 0 || iw > 63) continue;
                acc += yp[ih*64+iw] * wr[kh*3+kw];
            }
        }
    }
    float s = g[co] / sqrtf(v[co] + 1e-5f);
    float val = (acc + bias[co] - m[co])*s + bb[co];
    e1[idx] = lrelu_f(val);
}

// ---------------- K2: encoder conv2 (e1 -> per-(b,co) mean), 3x3 s1 p0 --------
__global__ __launch_bounds__(256) void k_enc2(
    const float* __restrict__ e1, const float* __restrict__ w,
    const float* __restrict__ bias, const float* __restrict__ g,
    const float* __restrict__ bb, const float* __restrict__ m,
    const float* __restrict__ v, float* __restrict__ fvec)
{
    __shared__ float red[256];
    int co = blockIdx.x, b = blockIdx.y, tid = threadIdx.x;
    float s  = g[co] / sqrtf(v[co] + 1e-5f);
    float bs = (bias[co]-m[co])*s + bb[co];
    const float* wp = w + co*1152;
    float lsum = 0.f;
    const float* eb = e1 + (size_t)b*128*1024;
    for (int p=tid; p<900; p+=256){
        int oh = p/30, ow = p - oh*30;
        float acc = 0.f;
        const float* ep = eb + oh*32 + ow;
        for (int ci=0; ci<128; ++ci){
            const float* row = ep + ci*1024;
            const float* wr  = wp + ci*9;
            acc += row[0]*wr[0]  + row[1]*wr[1]  + row[2]*wr[2]
                 + row[32]*wr[3] + row[33]*wr[4] + row[34]*wr[5]
                 + row[64]*wr[6] + row[65]*wr[7] + row[66]*wr[8];
        }
        lsum += lrelu_f(acc*s + bs);
    }
    red[tid] = lsum; __syncthreads();
    for (int st=128; st>0; st>>=1){
        if (tid < st) red[tid] += red[tid+st];
        __syncthreads();
    }
    if (tid==0) fvec[b*256+co] = red[0] * (1.f/900.f);
}

// ---------------- K3: MLP + kernel-prediction head ---------------------------
__global__ __launch_bounds__(256) void k_mlp(
    const float* __restrict__ fvec,
    const float* __restrict__ mw1, const float* __restrict__ mb1,
    const float* __restrict__ mw2, const float* __restrict__ mb2,
    const float* __restrict__ kw1, const float* __restrict__ kw2,
    float* __restrict__ kern)
{
    __shared__ float fs[256], h1[256], emb[256], k1[128];
    int b = blockIdx.x, t = threadIdx.x;
    fs[t] = fvec[b*256+t];
    __syncthreads();
    {
        float acc = mb1[t];
        const float* wr = mw1 + t*256;
        for (int i=0;i<256;++i) acc += fs[i]*wr[i];
        h1[t] = lrelu_f(acc);
    }
    __syncthreads();
    {
        float acc = mb2[t];
        const float* wr = mw2 + t*256;
        for (int i=0;i<256;++i) acc += h1[i]*wr[i];
        emb[t] = acc;
    }
    __syncthreads();
    if (t < 128){
        float acc = 0.f;
        const float* wr = kw1 + t*256;
        for (int i=0;i<256;++i) acc += emb[i]*wr[i];
        k1[t] = lrelu_f(acc);
    }
    __syncthreads();
    for (int o=t; o<576; o+=256){
        float acc = 0.f;
        const float* wr = kw2 + o*128;
        for (int i=0;i<128;++i) acc += k1[i]*wr[i];
        kern[b*576+o] = acc;
    }
}

// ---------------- K4: fused {dyn depthwise + 1x1 + CA + combine}, MFMA --------
__global__ __launch_bounds__(256) void k_fuse(
    const float* __restrict__ x, const float* __restrict__ kern,
    const float* __restrict__ cw, const float* __restrict__ cb,
    const float* __restrict__ caw1, const float* __restrict__ caw2,
    __hip_bfloat16* __restrict__ buf)
{
    __shared__ __align__(16) char lA [6*18*128];   // x tile [r][c][slot^(c&7)][8ci]
    __shared__ __align__(16) char lD [64*128];     // dw    [px][slot^(px&7)][8ci]
    __shared__ __align__(16) char lA1[64*64];      // a1    [px][slot^(px&3)][8j]
    __shared__ __align__(16) char lW1[64*128];     // cw    [co][slot^(co&7)][8ci]
    __shared__ __align__(16) char lWc[32*128];     // caw1  [co][slot^(co&7)][8ci]
    __shared__ __align__(16) char lW2[64*64];      // caw2  [co][slot^(co&3)][8j]
    __shared__ float kern_s[576];

    const int tid = threadIdx.x;
    const int wid = tid >> 6, lane = tid & 63;
    const int l15 = lane & 15, lg = lane >> 4;
    const int b = blockIdx.y;
    const int toh = (blockIdx.x >> 4) * 4;
    const int tow = (blockIdx.x & 15) * 16;
    const int row0 = toh - 1, col0 = tow - 1;

    for (int i = tid; i < 6*18*64; i += 256){
        int c  = i % 18;
        int t  = i / 18;
        int r  = t % 6;
        int ci = t / 6;
        int ih = row0 + r, iw = col0 + c;
        unsigned short bits = 0;
        if (ih >= 0 && ih < 256 && iw >= 0 && iw < 256)
            bits = bf_bits(x[((size_t)(b*64+ci) << 16) + ih*256 + iw]);
        *(unsigned short*)(lA + ((r*18+c)*8 + ((ci>>3) ^ (c&7)))*16 + (ci&7)*2) = bits;
    }
    for (int i = tid; i < 4096; i += 256){
        int co = i >> 6, ci = i & 63;
        *(unsigned short*)(lW1 + (co*8 + ((ci>>3) ^ (co&7)))*16 + (ci&7)*2) = bf_bits(cw[co*64+ci]);
    }
    for (int i = tid; i < 2048; i += 256){
        int co = i >> 6, ci = i & 63;
        *(unsigned short*)(lWc + (co*8 + ((ci>>3) ^ (co&7)))*16 + (ci&7)*2) = bf_bits(caw1[co*64+ci]);
    }
    for (int i = tid; i < 2048; i += 256){
        int co = i >> 5, j = i & 31;
        *(unsigned short*)(lW2 + (co*4 + ((j>>3) ^ (co&3)))*16 + (j&7)*2) = bf_bits(caw2[co*32+j]);
    }
    for (int i = tid; i < 576; i += 256) kern_s[i] = kern[b*576 + i];
    __syncthreads();

    const int m1 = wid & 1;
    const int nb = (wid >> 1) * 2;
    f32x4 a1acc[2] = {{0.f,0.f,0.f,0.f},{0.f,0.f,0.f,0.f}};
    const int coA1 = m1*16 + l15;
    #pragma unroll
    for (int ch = 0; ch < 2; ++ch){
        bf16x8 aA = *(const bf16x8*)(lWc + (coA1*8 + ((ch*4+lg) ^ (coA1&7)))*16);
        #pragma unroll
        for (int t = 0; t < 2; ++t){
            int n = nb + t;
            int cc = l15 + 1, rr = n + 1;
            bf16x8 bX = *(const bf16x8*)(lA + ((rr*18+cc)*8 + ((ch*4+lg) ^ (cc&7)))*16);
            a1acc[t] = __builtin_amdgcn_mfma_f32_16x16x32_bf16(aA, bX, a1acc[t], 0,0,0);
        }
    }

    {
        const int px = tid & 63;
        const int prow = px >> 4, pcol = px & 15;
        const int ci0 = (tid >> 6) * 16;
        #pragma unroll
        for (int j = 0; j < 16; ++j){
            int ci = ci0 + j;
            const float* kr = kern_s + ci*9;
            float acc = 0.f;
            #pragma unroll
            for (int kh = 0; kh < 3; ++kh)
                #pragma unroll
                for (int kw = 0; kw < 3; ++kw){
                    int r = prow + kh, c = pcol + kw;
                    float xv = bf_val(lA + ((r*18+c)*8 + ((ci>>3) ^ (c&7)))*16 + (ci&7)*2);
                    acc += xv * kr[kh*3+kw];
                }
            *(unsigned short*)(lD + (px*8 + ((ci>>3) ^ (px&7)))*16 + (ci&7)*2)
                = bf_bits(lrelu_f(acc));
        }
    }

    #pragma unroll
    for (int t = 0; t < 2; ++t){
        int n = nb + t;
        int px = n*16 + l15;
        #pragma unroll
        for (int r = 0; r < 4; ++r){
            int j = m1*16 + lg*4 + r;
            *(unsigned short*)(lA1 + (px*4 + ((j>>3) ^ (px&3)))*16 + (j&7)*2)
                = bf_bits(lrelu_f(a1acc[t][r]));
        }
    }
    __syncthreads();

    f32x4 dynacc[4] = {{0.f,0.f,0.f,0.f},{0.f,0.f,0.f,0.f},{0.f,0.f,0.f,0.f},{0.f,0.f,0.f,0.f}};
    f32x4 attacc[4] = {{0.f,0.f,0.f,0.f},{0.f,0.f,0.f,0.f},{0.f,0.f,0.f,0.f},{0.f,0.f,0.f,0.f}};
    const int coA = wid*16 + l15;
    #pragma unroll
    for (int ch = 0; ch < 2; ++ch){
        bf16x8 aW = *(const bf16x8*)(lW1 + (coA*8 + ((ch*4+lg) ^ (coA&7)))*16);
        #pragma unroll
        for (int n = 0; n < 4; ++n){
            int px = n*16 + l15;
            bf16x8 bD = *(const bf16x8*)(lD + (px*8 + ((ch*4+lg) ^ (px&7)))*16);
            dynacc[n] = __builtin_amdgcn_mfma_f32_16x16x32_bf16(aW, bD, dynacc[n], 0,0,0);
        }
    }
    {
        bf16x8 aW2 = *(const bf16x8*)(lW2 + (coA*4 + (lg ^ (coA&3)))*16);
        #pragma unroll
        for (int n = 0; n < 4; ++n){
            int px = n*16 + l15;
            bf16x8 bA1 = *(const bf16x8*)(lA1 + (px*4 + (lg ^ (px&3)))*16);
            attacc[n] = __builtin_amdgcn_mfma_f32_16x16x32_bf16(aW2, bA1, attacc[n], 0,0,0);
        }
    }

    #pragma unroll
    for (int n = 0; n < 4; ++n){
        int oh = toh + n, ow = tow + l15;
        #pragma unroll
        for (int r = 0; r < 4; ++r){
            int co = wid*16 + lg*4 + r;
            size_t oi = ((size_t)(b*64+co) << 16) + oh*256 + ow;
            float att = fmaxf(attacc[n][r], 0.f);
            float v = lrelu_f(dynacc[n][r] + cb[co] + x[oi]*att);
            buf[oi] = __float2bfloat16(v);
        }
    }
}

// ---------------- K5 v2: MFMA implicit-GEMM conv, stage-once ------------------
// Tile: TH x 16 px (TH=16 stride1, 8 stride2) x 64 co, 4 waves.
// LDS: input halo lA (verified swizzle) + FULL weight tensor lW (18 x 64co x
// 32ci, per-(ch,pos) blocks in the verified sub-layout). One barrier total.
// Wave: preloads its 18 A-frags (16-co slice) to regs; per output row n:
// 18 ds_read B + 18 MFMA, epilogue immediately (single live acc).
template<typename TIN, int STRIDE, int RESMODE, int ACT, int OUTBF>
__global__ __launch_bounds__(256) void k_conv_mfma(
    const TIN* __restrict__ in, const float* __restrict__ w,
    const float* __restrict__ bias, const void* __restrict__ res,
    void* __restrict__ outp, int H, int W, int Ho, int Wo)
{
    constexpr int TH   = (STRIDE==1) ? 16 : 8;
    constexpr int ROWS = (STRIDE==1) ? TH+2 : 2*TH+1;
    constexpr int COLS = (STRIDE==1) ? 18 : 33;
    __shared__ __align__(16) char lA[ROWS*COLS*128];
    __shared__ __align__(16) char lW[18*64*64];     // 73728 B
    const int tid  = threadIdx.x;
    const int wid  = tid >> 6, lane = tid & 63;
    const int l15  = lane & 15, g = lane >> 4;
    const int b    = blockIdx.y;
    const int tilesW = Wo >> 4;
    const int toh  = (blockIdx.x / tilesW) * TH;
    const int tow  = (blockIdx.x % tilesW) * 16;
    const int row0 = toh*STRIDE - 1;
    const int col0 = tow*STRIDE - 1;

    // stage input halo (verified layout)
    for (int i = tid; i < ROWS*COLS*64; i += 256){
        int c  = i % COLS;
        int t  = i / COLS;
        int r  = t % ROWS;
        int ci = t / ROWS;
        int ih = row0 + r, iw = col0 + c;
        unsigned short bits = 0;
        if (ih >= 0 && ih < H && iw >= 0 && iw < W)
            bits = bf_bits(in[((size_t)(b*64+ci))*H*W + (size_t)ih*W + iw]);
        *(unsigned short*)(lA + ((r*COLS + c)*8 + ((ci>>3) ^ (c & 7)))*16 + (ci&7)*2) = bits;
    }
    // stage full weights once: f = ch*9+pos blocks, each 64co x 32ci
    for (int i = tid; i < 36864; i += 256){
        int co  = i / 576;
        int rem = i - co*576;
        int ci  = rem / 9;
        int pos = rem - ci*9;
        int ch  = ci >> 5, cil = ci & 31;
        *(unsigned short*)(lW + ((ch*9+pos)*64 + co)*64
                               + ((cil>>3) ^ ((co>>1)&3))*16 + (cil&7)*2) = bf_bits(w[i]);
    }
    __syncthreads();

    // preload this wave's 18 A-frags (weights, 16-co slice) into registers
    const int coA = wid*16 + l15;
    const int aswz = (g ^ ((coA>>1)&3))*16;
    bf16x8 aw[18];
    #pragma unroll
    for (int f = 0; f < 18; ++f)
        aw[f] = *(const bf16x8*)(lW + (f*64 + coA)*64 + aswz);

    float bv[4];
    #pragma unroll
    for (int r = 0; r < 4; ++r) bv[r] = bias[wid*16 + g*4 + r];

    const float*          resF = (const float*)res;
    const __hip_bfloat16* resB = (const __hip_bfloat16*)res;

    #pragma unroll
    for (int n = 0; n < TH; ++n){
        f32x4 acc = {0.f,0.f,0.f,0.f};
        #pragma unroll
        for (int ch = 0; ch < 2; ++ch)
            #pragma unroll
            for (int pos = 0; pos < 9; ++pos){
                const int kh = pos/3, kw = pos - 3*(pos/3);
                const int cc = l15*STRIDE + kw;
                const int rr = n*STRIDE + kh;
                bf16x8 bx = *(const bf16x8*)(lA + ((rr*COLS + cc)*8 + ((ch*4+g) ^ (cc&7)))*16);
                acc = __builtin_amdgcn_mfma_f32_16x16x32_bf16(aw[ch*9+pos], bx, acc, 0, 0, 0);
            }
        const int oh = toh + n, ow = tow + l15;
        #pragma unroll
        for (int r = 0; r < 4; ++r){
            int co = wid*16 + g*4 + r;
            size_t oi = ((size_t)(b*64+co)*Ho + oh)*Wo + ow;
            float v = acc[r] + bv[r];
            if (ACT) v = fmaxf(v, 0.f);
            if (RESMODE == 1) v += resF[oi];
            if (RESMODE == 2) v += __bfloat162float(resB[oi]);
            if (OUTBF) ((__hip_bfloat16*)outp)[oi] = __float2bfloat16(v);
            else       ((float*)outp)[oi] = v;
        }
    }
}

// ---------------- host ---------------------------------------------------------
extern "C" void kernel_launch(void* const* d_in, const int* in_sizes, int n_in,
                              void* d_out, int out_size, void* d_ws, size_t ws_size,
                              hipStream_t stream) {
    const float* x    = (const float*)d_in[0];
    const float* y    = (const float*)d_in[1];
    const float* ew1  = (const float*)d_in[2];
    const float* eb1  = (const float*)d_in[3];
    const float* bn1g = (const float*)d_in[4];
    const float* bn1b = (const float*)d_in[5];
    const float* bn1m = (const float*)d_in[6];
    const float* bn1v = (const float*)d_in[7];
    const float* ew2  = (const float*)d_in[8];
    const float* eb2  = (const float*)d_in[9];
    const float* bn2g = (const float*)d_in[10];
    const float* bn2b = (const float*)d_in[11];
    const float* bn2m = (const float*)d_in[12];
    const float* bn2v = (const float*)d_in[13];
    const float* mw1  = (const float*)d_in[14];
    const float* mb1  = (const float*)d_in[15];
    const float* mw2  = (const float*)d_in[16];
    const float* mb2  = (const float*)d_in[17];
    const float* kw1  = (const float*)d_in[18];
    const float* kw2  = (const float*)d_in[19];
    const float* cw   = (const float*)d_in[20];
    const float* cb   = (const float*)d_in[21];
    const float* caw1 = (const float*)d_in[22];
    const float* caw2 = (const float*)d_in[23];
    const float* c1w  = (const float*)d_in[24];
    const float* c1b  = (const float*)d_in[25];
    const float* c2w  = (const float*)d_in[26];
    const float* c2b  = (const float*)d_in[27];
    const float* r1w  = (const float*)d_in[28];
    const float* r1b  = (const float*)d_in[29];
    const float* r2w  = (const float*)d_in[30];
    const float* r2b  = (const float*)d_in[31];

    // ws layout (~33.6 MB): buf bf16 [0, 33554432); e1 f32 overlays [0, 2097152);
    // after buf dies: t2 bf16 [0, 8388608), u2 [8388608, 16777216),
    //                 t3 [16777216, 18874368), u3 [18874368, 20971520)
    // fv f32 @ 33554432, kern f32 @ 33558528
    char* wsc = (char*)d_ws;
    __hip_bfloat16* buf = (__hip_bfloat16*)wsc;
    float*          e1  = (float*)wsc;
    __hip_bfloat16* t2  = (__hip_bfloat16*)wsc;
    __hip_bfloat16* u2  = (__hip_bfloat16*)(wsc + 8388608);
    __hip_bfloat16* t3  = (__hip_bfloat16*)(wsc + 16777216);
    __hip_bfloat16* u3  = (__hip_bfloat16*)(wsc + 18874368);
    float*          fv  = (float*)(wsc + 33554432);
    float*          kern= (float*)(wsc + 33558528);

    float* ob   = (float*)d_out;            // out  (4,64,256,256) f32
    float* ob1  = ob + 16777216;            // out2 (4,64,128,128) f32
    float* ob2  = ob + 20971520;            // out3 (4,64,64,64)   f32

    k_enc1<<<dim3(2048),256,0,stream>>>(y, ew1, eb1, bn1g, bn1b, bn1m, bn1v, e1);
    k_enc2<<<dim3(256,4),256,0,stream>>>(e1, ew2, eb2, bn2g, bn2b, bn2m, bn2v, fv);
    k_mlp<<<dim3(4),256,0,stream>>>(fv, mw1, mb1, mw2, mb2, kw1, kw2, kern);
    k_fuse<<<dim3(1024,4),256,0,stream>>>(x, kern, cw, cb, caw1, caw2, buf);

    // out0 = conv3x3(pre) + bias + x  -> f32 d_out     (16x16 tiles: 16*16)
    k_conv_mfma<__hip_bfloat16,1,1,0,0><<<dim3(256,4),256,0,stream>>>(buf, c1w, c1b, x, ob, 256,256,256,256);
    // t2 = conv3x3 s2 (out0 f32) -> bf16              (8x16 tiles: 16*8)
    k_conv_mfma<float,2,0,0,1><<<dim3(128,4),256,0,stream>>>(ob, c2w, c2b, nullptr, t2, 256,256,128,128);
    // u2 = relu(conv3x3(t2)) -> bf16                  (8*8)
    k_conv_mfma<__hip_bfloat16,1,0,1,1><<<dim3(64,4),256,0,stream>>>(t2, r1w, r1b, nullptr, u2, 128,128,128,128);
    // out2 = t2 + conv3x3(u2) -> f32 d_out
    k_conv_mfma<__hip_bfloat16,1,2,0,0><<<dim3(64,4),256,0,stream>>>(u2, r2w, r2b, t2, ob1, 128,128,128,128);
    // t3 = conv3x3 s2 (out2 f32) -> bf16              (8*4)
    k_conv_mfma<float,2,0,0,1><<<dim3(32,4),256,0,stream>>>(ob1, c2w, c2b, nullptr, t3, 128,128,64,64);
    // u3 = relu(conv3x3(t3)) -> bf16                  (4*4)
    k_conv_mfma<__hip_bfloat16,1,0,1,1><<<dim3(16,4),256,0,stream>>>(t3, r1w, r1b, nullptr, u3, 64,64,64,64);
    // out3 = t3 + conv3x3(u3) -> f32 d_out
    k_conv_mfma<__hip_bfloat16,1,2,0,0><<<dim3(16,4),256,0,stream>>>(u3, r2w, r2b, t3, ob2, 64,64,64,64);
}

// Round 15
// 821.662 us; speedup vs baseline: 1.3077x; 1.3077x over previous
//
#include <hip/hip_runtime.h>
#include <hip/hip_bf16.h>
#include <cstddef>
#include <cstdint>

#define DEV __device__ __forceinline__

DEV float lrelu_f(float z){ return z >= 0.f ? z : 0.1f*z; }

typedef __bf16 bf16x8 __attribute__((ext_vector_type(8)));
typedef float  f32x4  __attribute__((ext_vector_type(4)));
typedef unsigned short u16x8 __attribute__((ext_vector_type(8)));

DEV unsigned short bf_bits(float v){
    __hip_bfloat16 h = __float2bfloat16(v);
    unsigned short s; __builtin_memcpy(&s, &h, 2); return s;
}
DEV unsigned short bf_bits(__hip_bfloat16 v){
    unsigned short s; __builtin_memcpy(&s, &v, 2); return s;
}
DEV float bf_val(const char* p){
    unsigned short s = *(const unsigned short*)p;
    __hip_bfloat16 h; __builtin_memcpy(&h, &s, 2);
    return __bfloat162float(h);
}

// ---------------- K1: encoder conv1 (y -> e1), 3x3 s2 p1 + bias + BN + lrelu ----
__global__ __launch_bounds__(256) void k_enc1(
    const float* __restrict__ y, const float* __restrict__ w,
    const float* __restrict__ bias, const float* __restrict__ g,
    const float* __restrict__ bb, const float* __restrict__ m,
    const float* __restrict__ v, float* __restrict__ e1)
{
    int idx = blockIdx.x*256 + threadIdx.x;     // [4,128,32,32]
    int ow = idx & 31, oh = (idx>>5)&31, co = (idx>>10)&127, b = idx>>17;
    float acc = 0.f;
    const float* wp = w + co*576;
    const float* yb = y + (size_t)b*64*4096;
    for (int ci=0; ci<64; ++ci){
        const float* yp = yb + ci*4096;
        const float* wr = wp + ci*9;
        #pragma unroll
        for (int kh=0; kh<3; ++kh){
            int ih = oh*2 + kh - 1;
            if (ih < 0 || ih > 63) continue;
            #pragma unroll
            for (int kw=0; kw<3; ++kw){
                int iw = ow*2 + kw - 1;
                if (iw < 0 || iw > 63) continue;
                acc += yp[ih*64+iw] * wr[kh*3+kw];
            }
        }
    }
    float s = g[co] / sqrtf(v[co] + 1e-5f);
    float val = (acc + bias[co] - m[co])*s + bb[co];
    e1[idx] = lrelu_f(val);
}

// ---------------- K2: encoder conv2 (e1 -> per-(b,co) mean), 3x3 s1 p0 --------
__global__ __launch_bounds__(256) void k_enc2(
    const float* __restrict__ e1, const float* __restrict__ w,
    const float* __restrict__ bias, const float* __restrict__ g,
    const float* __restrict__ bb, const float* __restrict__ m,
    const float* __restrict__ v, float* __restrict__ fvec)
{
    __shared__ float red[256];
    int co = blockIdx.x, b = blockIdx.y, tid = threadIdx.x;
    float s  = g[co] / sqrtf(v[co] + 1e-5f);
    float bs = (bias[co]-m[co])*s + bb[co];
    const float* wp = w + co*1152;
    float lsum = 0.f;
    const float* eb = e1 + (size_t)b*128*1024;
    for (int p=tid; p<900; p+=256){
        int oh = p/30, ow = p - oh*30;
        float acc = 0.f;
        const float* ep = eb + oh*32 + ow;
        for (int ci=0; ci<128; ++ci){
            const float* row = ep + ci*1024;
            const float* wr  = wp + ci*9;
            acc += row[0]*wr[0]  + row[1]*wr[1]  + row[2]*wr[2]
                 + row[32]*wr[3] + row[33]*wr[4] + row[34]*wr[5]
                 + row[64]*wr[6] + row[65]*wr[7] + row[66]*wr[8];
        }
        lsum += lrelu_f(acc*s + bs);
    }
    red[tid] = lsum; __syncthreads();
    for (int st=128; st>0; st>>=1){
        if (tid < st) red[tid] += red[tid+st];
        __syncthreads();
    }
    if (tid==0) fvec[b*256+co] = red[0] * (1.f/900.f);
}

// ---------------- K3: MLP + kernel-prediction head ---------------------------
__global__ __launch_bounds__(256) void k_mlp(
    const float* __restrict__ fvec,
    const float* __restrict__ mw1, const float* __restrict__ mb1,
    const float* __restrict__ mw2, const float* __restrict__ mb2,
    const float* __restrict__ kw1, const float* __restrict__ kw2,
    float* __restrict__ kern)
{
    __shared__ float fs[256], h1[256], emb[256], k1[128];
    int b = blockIdx.x, t = threadIdx.x;
    fs[t] = fvec[b*256+t];
    __syncthreads();
    {
        float acc = mb1[t];
        const float* wr = mw1 + t*256;
        for (int i=0;i<256;++i) acc += fs[i]*wr[i];
        h1[t] = lrelu_f(acc);
    }
    __syncthreads();
    {
        float acc = mb2[t];
        const float* wr = mw2 + t*256;
        for (int i=0;i<256;++i) acc += h1[i]*wr[i];
        emb[t] = acc;
    }
    __syncthreads();
    if (t < 128){
        float acc = 0.f;
        const float* wr = kw1 + t*256;
        for (int i=0;i<256;++i) acc += emb[i]*wr[i];
        k1[t] = lrelu_f(acc);
    }
    __syncthreads();
    for (int o=t; o<576; o+=256){
        float acc = 0.f;
        const float* wr = kw2 + o*128;
        for (int i=0;i<128;++i) acc += k1[i]*wr[i];
        kern[b*576+o] = acc;
    }
}

// ---------------- K4: fused {dyn depthwise + 1x1 + CA + combine}, MFMA --------
__global__ __launch_bounds__(256) void k_fuse(
    const float* __restrict__ x, const float* __restrict__ kern,
    const float* __restrict__ cw, const float* __restrict__ cb,
    const float* __restrict__ caw1, const float* __restrict__ caw2,
    __hip_bfloat16* __restrict__ buf)
{
    __shared__ __align__(16) char lA [6*18*128];   // x tile [r][c][slot^(c&7)][8ci]
    __shared__ __align__(16) char lD [64*128];     // dw    [px][slot^(px&7)][8ci]
    __shared__ __align__(16) char lA1[64*64];      // a1    [px][slot^(px&3)][8j]
    __shared__ __align__(16) char lW1[64*128];     // cw    [co][slot^(co&7)][8ci]
    __shared__ __align__(16) char lWc[32*128];     // caw1  [co][slot^(co&7)][8ci]
    __shared__ __align__(16) char lW2[64*64];      // caw2  [co][slot^(co&3)][8j]
    __shared__ float kern_s[576];

    const int tid = threadIdx.x;
    const int wid = tid >> 6, lane = tid & 63;
    const int l15 = lane & 15, lg = lane >> 4;
    const int b = blockIdx.y;
    const int toh = (blockIdx.x >> 4) * 4;
    const int tow = (blockIdx.x & 15) * 16;
    const int row0 = toh - 1, col0 = tow - 1;

    for (int i = tid; i < 6*18*64; i += 256){
        int c  = i % 18;
        int t  = i / 18;
        int r  = t % 6;
        int ci = t / 6;
        int ih = row0 + r, iw = col0 + c;
        unsigned short bits = 0;
        if (ih >= 0 && ih < 256 && iw >= 0 && iw < 256)
            bits = bf_bits(x[((size_t)(b*64+ci) << 16) + ih*256 + iw]);
        *(unsigned short*)(lA + ((r*18+c)*8 + ((ci>>3) ^ (c&7)))*16 + (ci&7)*2) = bits;
    }
    for (int i = tid; i < 4096; i += 256){
        int co = i >> 6, ci = i & 63;
        *(unsigned short*)(lW1 + (co*8 + ((ci>>3) ^ (co&7)))*16 + (ci&7)*2) = bf_bits(cw[co*64+ci]);
    }
    for (int i = tid; i < 2048; i += 256){
        int co = i >> 6, ci = i & 63;
        *(unsigned short*)(lWc + (co*8 + ((ci>>3) ^ (co&7)))*16 + (ci&7)*2) = bf_bits(caw1[co*64+ci]);
    }
    for (int i = tid; i < 2048; i += 256){
        int co = i >> 5, j = i & 31;
        *(unsigned short*)(lW2 + (co*4 + ((j>>3) ^ (co&3)))*16 + (j&7)*2) = bf_bits(caw2[co*32+j]);
    }
    for (int i = tid; i < 576; i += 256) kern_s[i] = kern[b*576 + i];
    __syncthreads();

    const int m1 = wid & 1;
    const int nb = (wid >> 1) * 2;
    f32x4 a1acc[2] = {{0.f,0.f,0.f,0.f},{0.f,0.f,0.f,0.f}};
    const int coA1 = m1*16 + l15;
    #pragma unroll
    for (int ch = 0; ch < 2; ++ch){
        bf16x8 aA = *(const bf16x8*)(lWc + (coA1*8 + ((ch*4+lg) ^ (coA1&7)))*16);
        #pragma unroll
        for (int t = 0; t < 2; ++t){
            int n = nb + t;
            int cc = l15 + 1, rr = n + 1;
            bf16x8 bX = *(const bf16x8*)(lA + ((rr*18+cc)*8 + ((ch*4+lg) ^ (cc&7)))*16);
            a1acc[t] = __builtin_amdgcn_mfma_f32_16x16x32_bf16(aA, bX, a1acc[t], 0,0,0);
        }
    }

    {
        const int px = tid & 63;
        const int prow = px >> 4, pcol = px & 15;
        const int ci0 = (tid >> 6) * 16;
        #pragma unroll
        for (int j = 0; j < 16; ++j){
            int ci = ci0 + j;
            const float* kr = kern_s + ci*9;
            float acc = 0.f;
            #pragma unroll
            for (int kh = 0; kh < 3; ++kh)
                #pragma unroll
                for (int kw = 0; kw < 3; ++kw){
                    int r = prow + kh, c = pcol + kw;
                    float xv = bf_val(lA + ((r*18+c)*8 + ((ci>>3) ^ (c&7)))*16 + (ci&7)*2);
                    acc += xv * kr[kh*3+kw];
                }
            *(unsigned short*)(lD + (px*8 + ((ci>>3) ^ (px&7)))*16 + (ci&7)*2)
                = bf_bits(lrelu_f(acc));
        }
    }

    #pragma unroll
    for (int t = 0; t < 2; ++t){
        int n = nb + t;
        int px = n*16 + l15;
        #pragma unroll
        for (int r = 0; r < 4; ++r){
            int j = m1*16 + lg*4 + r;
            *(unsigned short*)(lA1 + (px*4 + ((j>>3) ^ (px&3)))*16 + (j&7)*2)
                = bf_bits(lrelu_f(a1acc[t][r]));
        }
    }
    __syncthreads();

    f32x4 dynacc[4] = {{0.f,0.f,0.f,0.f},{0.f,0.f,0.f,0.f},{0.f,0.f,0.f,0.f},{0.f,0.f,0.f,0.f}};
    f32x4 attacc[4] = {{0.f,0.f,0.f,0.f},{0.f,0.f,0.f,0.f},{0.f,0.f,0.f,0.f},{0.f,0.f,0.f,0.f}};
    const int coA = wid*16 + l15;
    #pragma unroll
    for (int ch = 0; ch < 2; ++ch){
        bf16x8 aW = *(const bf16x8*)(lW1 + (coA*8 + ((ch*4+lg) ^ (coA&7)))*16);
        #pragma unroll
        for (int n = 0; n < 4; ++n){
            int px = n*16 + l15;
            bf16x8 bD = *(const bf16x8*)(lD + (px*8 + ((ch*4+lg) ^ (px&7)))*16);
            dynacc[n] = __builtin_amdgcn_mfma_f32_16x16x32_bf16(aW, bD, dynacc[n], 0,0,0);
        }
    }
    {
        bf16x8 aW2 = *(const bf16x8*)(lW2 + (coA*4 + (lg ^ (coA&3)))*16);
        #pragma unroll
        for (int n = 0; n < 4; ++n){
            int px = n*16 + l15;
            bf16x8 bA1 = *(const bf16x8*)(lA1 + (px*4 + (lg ^ (px&3)))*16);
            attacc[n] = __builtin_amdgcn_mfma_f32_16x16x32_bf16(aW2, bA1, attacc[n], 0,0,0);
        }
    }

    #pragma unroll
    for (int n = 0; n < 4; ++n){
        int oh = toh + n, ow = tow + l15;
        #pragma unroll
        for (int r = 0; r < 4; ++r){
            int co = wid*16 + lg*4 + r;
            size_t oi = ((size_t)(b*64+co) << 16) + oh*256 + ow;
            float att = fmaxf(attacc[n][r], 0.f);
            float v = lrelu_f(dynacc[n][r] + cb[co] + x[oi]*att);
            buf[oi] = __float2bfloat16(v);
        }
    }
}

// ---------------- K_wprep: pack conv weights into MFMA A-fragment layout ------
// wp[((f*4+g)*64 + coA)*8 + e] = bf16(w[coA][ch*32 + g*8 + e][pos]), f=ch*9+pos
__global__ __launch_bounds__(256) void k_wprep(
    const float* __restrict__ w, __hip_bfloat16* __restrict__ wp)
{
    int i = blockIdx.x*256 + threadIdx.x;      // [0, 36864)
    int e   = i & 7;
    int coA = (i >> 3) & 63;
    int g   = (i >> 9) & 3;
    int f   = i >> 11;
    int ch  = (f >= 9) ? 1 : 0;
    int pos = f - 9*ch;
    wp[i] = __float2bfloat16(w[coA*576 + (ch*32 + g*8 + e)*9 + pos]);
}

// ---------------- K5 v3: MFMA implicit-GEMM conv ------------------------------
// Weights pre-packed (k_wprep) -> per-lane 16B global loads (L2-resident);
// LDS = input halo only (verified layout). Vectorized aligned staging with
// guarded edge path. Stride-1: sliding-window B-frags (3x fewer ds_reads).
template<typename TIN, int STRIDE, int RESMODE, int ACT, int OUTBF>
__global__ __launch_bounds__(256) void k_conv_mfma(
    const TIN* __restrict__ in, const __hip_bfloat16* __restrict__ wp,
    const float* __restrict__ bias, const void* __restrict__ res,
    void* __restrict__ outp, int H, int W, int Ho, int Wo)
{
    constexpr int TH   = (STRIDE==1) ? 16 : 8;
    constexpr int ROWS = (STRIDE==1) ? TH+2 : 2*TH+1;   // 18 / 17
    constexpr int COLS = (STRIDE==1) ? 18 : 33;
    constexpr int EPC  = (sizeof(TIN)==2) ? 8 : 4;      // elems per 16B chunk
    constexpr int NC   = (COLS + 2*EPC - 2) / EPC;      // chunks per halo row
    __shared__ __align__(16) char lA[ROWS*COLS*128];
    const int tid = threadIdx.x;
    const int wid = tid >> 6, lane = tid & 63;
    const int l15 = lane & 15, g = lane >> 4;
    const int b   = blockIdx.y;
    const int tilesW = Wo >> 4;
    const int toh = (blockIdx.x / tilesW) * TH;
    const int tow = (blockIdx.x % tilesW) * 16;
    const int row0 = toh*STRIDE - 1;
    const int col0 = tow*STRIDE - 1;

    // ---- A-frags (weights) from prepped global, issued early ----------------
    bf16x8 aw[18];
    const int coA = wid*16 + l15;
    #pragma unroll
    for (int f = 0; f < 18; ++f)
        aw[f] = *(const bf16x8*)(wp + ((f*4 + g)*64 + coA)*8);

    // ---- stage input halo -----------------------------------------------------
    const int astart = tow*STRIDE - EPC;                 // aligned; col0-astart = EPC-1
    const bool cfast = (astart >= 0) && (astart + NC*EPC <= W);
    for (int i = tid; i < ROWS*64; i += 256){
        const int ci = i & 63, r = i >> 6;
        const int ih = row0 + r;
        if (ih < 0 || ih >= H){
            #pragma unroll
            for (int c = 0; c < COLS; ++c)
                *(unsigned short*)(lA + ((r*COLS+c)*8 + ((ci>>3)^(c&7)))*16 + (ci&7)*2) = 0;
        } else {
            const TIN* srow = in + ((size_t)(b*64+ci))*H*W + (size_t)ih*W;
            if (cfast){
                if constexpr (sizeof(TIN) == 2){
                    u16x8 chk[NC];
                    #pragma unroll
                    for (int k = 0; k < NC; ++k)
                        chk[k] = *(const u16x8*)(srow + astart + k*8);
                    #pragma unroll
                    for (int c = 0; c < COLS; ++c){
                        const int idx = 7 + c;
                        unsigned short bits = chk[idx>>3][idx&7];
                        *(unsigned short*)(lA + ((r*COLS+c)*8 + ((ci>>3)^(c&7)))*16 + (ci&7)*2) = bits;
                    }
                } else {
                    f32x4 chk[NC];
                    #pragma unroll
                    for (int k = 0; k < NC; ++k)
                        chk[k] = *(const f32x4*)(srow + astart + k*4);
                    #pragma unroll
                    for (int c = 0; c < COLS; ++c){
                        const int idx = 3 + c;
                        unsigned short bits = bf_bits(chk[idx>>2][idx&3]);
                        *(unsigned short*)(lA + ((r*COLS+c)*8 + ((ci>>3)^(c&7)))*16 + (ci&7)*2) = bits;
                    }
                }
            } else {
                #pragma unroll
                for (int c = 0; c < COLS; ++c){
                    int iw = col0 + c;
                    unsigned short bits = 0;
                    if (iw >= 0 && iw < W) bits = bf_bits(srow[iw]);
                    *(unsigned short*)(lA + ((r*COLS+c)*8 + ((ci>>3)^(c&7)))*16 + (ci&7)*2) = bits;
                }
            }
        }
    }
    __syncthreads();

    float bv[4];
    #pragma unroll
    for (int r = 0; r < 4; ++r) bv[r] = bias[wid*16 + g*4 + r];
    const float*          resF = (const float*)res;
    const __hip_bfloat16* resB = (const __hip_bfloat16*)res;

    if constexpr (STRIDE == 1){
        bf16x8 Bw[3][2][3];                      // [rowslot][ch][kw]
        auto ldrow = [&](int rr, int slot){
            #pragma unroll
            for (int ch = 0; ch < 2; ++ch)
                #pragma unroll
                for (int kw = 0; kw < 3; ++kw){
                    const int cc = l15 + kw;
                    Bw[slot][ch][kw] = *(const bf16x8*)(lA + ((rr*COLS + cc)*8 + ((ch*4+g) ^ (cc&7)))*16);
                }
        };
        ldrow(0, 0);
        ldrow(1, 1);
        #pragma unroll
        for (int n = 0; n < TH; ++n){
            ldrow(n+2, (n+2)%3);
            f32x4 acc = {0.f,0.f,0.f,0.f};
            #pragma unroll
            for (int kh = 0; kh < 3; ++kh)
                #pragma unroll
                for (int ch = 0; ch < 2; ++ch)
                    #pragma unroll
                    for (int kw = 0; kw < 3; ++kw)
                        acc = __builtin_amdgcn_mfma_f32_16x16x32_bf16(
                                aw[ch*9 + kh*3 + kw], Bw[(n+kh)%3][ch][kw], acc, 0, 0, 0);
            const int oh = toh + n, ow = tow + l15;
            #pragma unroll
            for (int r = 0; r < 4; ++r){
                int co = wid*16 + g*4 + r;
                size_t oi = ((size_t)(b*64+co)*Ho + oh)*Wo + ow;
                float v = acc[r] + bv[r];
                if (ACT) v = fmaxf(v, 0.f);
                if (RESMODE == 1) v += resF[oi];
                if (RESMODE == 2) v += __bfloat162float(resB[oi]);
                if (OUTBF) ((__hip_bfloat16*)outp)[oi] = __float2bfloat16(v);
                else       ((float*)outp)[oi] = v;
            }
        }
    } else {
        #pragma unroll
        for (int n = 0; n < TH; ++n){
            f32x4 acc = {0.f,0.f,0.f,0.f};
            #pragma unroll
            for (int ch = 0; ch < 2; ++ch)
                #pragma unroll
                for (int pos = 0; pos < 9; ++pos){
                    const int kh = pos/3, kw = pos - 3*(pos/3);
                    const int cc = l15*STRIDE + kw;
                    const int rr = n*STRIDE + kh;
                    bf16x8 bx = *(const bf16x8*)(lA + ((rr*COLS + cc)*8 + ((ch*4+g) ^ (cc&7)))*16);
                    acc = __builtin_amdgcn_mfma_f32_16x16x32_bf16(aw[ch*9+pos], bx, acc, 0, 0, 0);
                }
            const int oh = toh + n, ow = tow + l15;
            #pragma unroll
            for (int r = 0; r < 4; ++r){
                int co = wid*16 + g*4 + r;
                size_t oi = ((size_t)(b*64+co)*Ho + oh)*Wo + ow;
                float v = acc[r] + bv[r];
                if (ACT) v = fmaxf(v, 0.f);
                if (RESMODE == 1) v += resF[oi];
                if (RESMODE == 2) v += __bfloat162float(resB[oi]);
                if (OUTBF) ((__hip_bfloat16*)outp)[oi] = __float2bfloat16(v);
                else       ((float*)outp)[oi] = v;
            }
        }
    }
}

// ---------------- host ---------------------------------------------------------
extern "C" void kernel_launch(void* const* d_in, const int* in_sizes, int n_in,
                              void* d_out, int out_size, void* d_ws, size_t ws_size,
                              hipStream_t stream) {
    const float* x    = (const float*)d_in[0];
    const float* y    = (const float*)d_in[1];
    const float* ew1  = (const float*)d_in[2];
    const float* eb1  = (const float*)d_in[3];
    const float* bn1g = (const float*)d_in[4];
    const float* bn1b = (const float*)d_in[5];
    const float* bn1m = (const float*)d_in[6];
    const float* bn1v = (const float*)d_in[7];
    const float* ew2  = (const float*)d_in[8];
    const float* eb2  = (const float*)d_in[9];
    const float* bn2g = (const float*)d_in[10];
    const float* bn2b = (const float*)d_in[11];
    const float* bn2m = (const float*)d_in[12];
    const float* bn2v = (const float*)d_in[13];
    const float* mw1  = (const float*)d_in[14];
    const float* mb1  = (const float*)d_in[15];
    const float* mw2  = (const float*)d_in[16];
    const float* mb2  = (const float*)d_in[17];
    const float* kw1  = (const float*)d_in[18];
    const float* kw2  = (const float*)d_in[19];
    const float* cw   = (const float*)d_in[20];
    const float* cb   = (const float*)d_in[21];
    const float* caw1 = (const float*)d_in[22];
    const float* caw2 = (const float*)d_in[23];
    const float* c1w  = (const float*)d_in[24];
    const float* c1b  = (const float*)d_in[25];
    const float* c2w  = (const float*)d_in[26];
    const float* c2b  = (const float*)d_in[27];
    const float* r1w  = (const float*)d_in[28];
    const float* r1b  = (const float*)d_in[29];
    const float* r2w  = (const float*)d_in[30];
    const float* r2b  = (const float*)d_in[31];

    // ws layout (proven >= 33.57 MB):
    //   buf bf16 [0, 33554432)  (k_fuse -> c1; dead after c1)
    //     e1 f32 overlays [0, 2097152)   (dead before k_fuse)
    //     after c1: t2 bf16 [0, 8388608), u2 [8388608, 16777216),
    //               t3 [16777216, 18874368), u3 [18874368, 20971520),
    //               wpB (3 x 147456 B prepped weights) @ 29360128
    //   fv f32 @ 33554432, kern f32 @ 33558528
    char* wsc = (char*)d_ws;
    __hip_bfloat16* buf = (__hip_bfloat16*)wsc;
    float*          e1  = (float*)wsc;
    __hip_bfloat16* t2  = (__hip_bfloat16*)wsc;
    __hip_bfloat16* u2  = (__hip_bfloat16*)(wsc + 8388608);
    __hip_bfloat16* t3  = (__hip_bfloat16*)(wsc + 16777216);
    __hip_bfloat16* u3  = (__hip_bfloat16*)(wsc + 18874368);
    __hip_bfloat16* wpB0= (__hip_bfloat16*)(wsc + 29360128);
    __hip_bfloat16* wpB1= (__hip_bfloat16*)(wsc + 29360128 + 147456);
    __hip_bfloat16* wpB2= (__hip_bfloat16*)(wsc + 29360128 + 294912);
    float*          fv  = (float*)(wsc + 33554432);
    float*          kern= (float*)(wsc + 33558528);

    float* ob   = (float*)d_out;            // out  (4,64,256,256) f32
    float* ob1  = ob + 16777216;            // out2 (4,64,128,128) f32
    float* ob2  = ob + 20971520;            // out3 (4,64,64,64)   f32
    // wpA for c1w lives in the TAIL of d_out (ob2 region): only the final conv
    // writes there, long after c1 consumed wpA. 147456 B at the very end.
    __hip_bfloat16* wpA = (__hip_bfloat16*)((char*)d_out + 87932928);

    k_wprep<<<dim3(144),256,0,stream>>>(c1w, wpA);
    k_enc1<<<dim3(2048),256,0,stream>>>(y, ew1, eb1, bn1g, bn1b, bn1m, bn1v, e1);
    k_enc2<<<dim3(256,4),256,0,stream>>>(e1, ew2, eb2, bn2g, bn2b, bn2m, bn2v, fv);
    k_mlp<<<dim3(4),256,0,stream>>>(fv, mw1, mb1, mw2, mb2, kw1, kw2, kern);
    k_fuse<<<dim3(1024,4),256,0,stream>>>(x, kern, cw, cb, caw1, caw2, buf);

    // out0 = conv3x3(pre) + bias + x  -> f32 d_out   (16x16 tiles)
    k_conv_mfma<__hip_bfloat16,1,1,0,0><<<dim3(256,4),256,0,stream>>>(buf, wpA, c1b, x, ob, 256,256,256,256);
    // prep remaining weights into the now-dead buf tail
    k_wprep<<<dim3(144),256,0,stream>>>(c2w, wpB0);
    k_wprep<<<dim3(144),256,0,stream>>>(r1w, wpB1);
    k_wprep<<<dim3(144),256,0,stream>>>(r2w, wpB2);
    // t2 = conv3x3 s2 (out0 f32) -> bf16             (8x16 tiles: 16*8)
    k_conv_mfma<float,2,0,0,1><<<dim3(128,4),256,0,stream>>>(ob, wpB0, c2b, nullptr, t2, 256,256,128,128);
    // u2 = relu(conv3x3(t2)) -> bf16                 (8*8)
    k_conv_mfma<__hip_bfloat16,1,0,1,1><<<dim3(64,4),256,0,stream>>>(t2, wpB1, r1b, nullptr, u2, 128,128,128,128);
    // out2 = t2 + conv3x3(u2) -> f32 d_out
    k_conv_mfma<__hip_bfloat16,1,2,0,0><<<dim3(64,4),256,0,stream>>>(u2, wpB2, r2b, t2, ob1, 128,128,128,128);
    // t3 = conv3x3 s2 (out2 f32) -> bf16             (8*4)
    k_conv_mfma<float,2,0,0,1><<<dim3(32,4),256,0,stream>>>(ob1, wpB0, c2b, nullptr, t3, 128,128,64,64);
    // u3 = relu(conv3x3(t3)) -> bf16                 (4*4)
    k_conv_mfma<__hip_bfloat16,1,0,1,1><<<dim3(16,4),256,0,stream>>>(t3, wpB1, r1b, nullptr, u3, 64,64,64,64);
    // out3 = t3 + conv3x3(u3) -> f32 d_out
    k_conv_mfma<__hip_bfloat16,1,2,0,0><<<dim3(16,4),256,0,stream>>>(u3, wpB2, r2b, t3, ob2, 64,64,64,64);
}

// Round 16
// 719.680 us; speedup vs baseline: 1.4930x; 1.1417x over previous
//
#include <hip/hip_runtime.h>
#include <hip/hip_bf16.h>
#include <cstddef>
#include <cstdint>

#define DEV __device__ __forceinline__

DEV float lrelu_f(float z){ return z >= 0.f ? z : 0.1f*z; }

typedef __bf16 bf16x8 __attribute__((ext_vector_type(8)));
typedef float  f32x4  __attribute__((ext_vector_type(4)));
typedef unsigned short u16x8 __attribute__((ext_vector_type(8)));

DEV unsigned short bf_bits(float v){
    __hip_bfloat16 h = __float2bfloat16(v);
    unsigned short s; __builtin_memcpy(&s, &h, 2); return s;
}
DEV unsigned short bf_bits(__hip_bfloat16 v){
    unsigned short s; __builtin_memcpy(&s, &v, 2); return s;
}
DEV float bf_val(const char* p){
    unsigned short s = *(const unsigned short*)p;
    __hip_bfloat16 h; __builtin_memcpy(&h, &s, 2);
    return __bfloat162float(h);
}

// ---------------- K1: encoder conv1 (y -> e1), 3x3 s2 p1 + bias + BN + lrelu ----
__global__ __launch_bounds__(256) void k_enc1(
    const float* __restrict__ y, const float* __restrict__ w,
    const float* __restrict__ bias, const float* __restrict__ g,
    const float* __restrict__ bb, const float* __restrict__ m,
    const float* __restrict__ v, float* __restrict__ e1)
{
    int idx = blockIdx.x*256 + threadIdx.x;     // [4,128,32,32]
    int ow = idx & 31, oh = (idx>>5)&31, co = (idx>>10)&127, b = idx>>17;
    float acc = 0.f;
    const float* wp = w + co*576;
    const float* yb = y + (size_t)b*64*4096;
    for (int ci=0; ci<64; ++ci){
        const float* yp = yb + ci*4096;
        const float* wr = wp + ci*9;
        #pragma unroll
        for (int kh=0; kh<3; ++kh){
            int ih = oh*2 + kh - 1;
            if (ih < 0 || ih > 63) continue;
            #pragma unroll
            for (int kw=0; kw<3; ++kw){
                int iw = ow*2 + kw - 1;
                if (iw < 0 || iw > 63) continue;
                acc += yp[ih*64+iw] * wr[kh*3+kw];
            }
        }
    }
    float s = g[co] / sqrtf(v[co] + 1e-5f);
    float val = (acc + bias[co] - m[co])*s + bb[co];
    e1[idx] = lrelu_f(val);
}

// ---------------- K_wprep2: pack enc2 weights (BN scale folded) ---------------
// wp2[((f*4+g)*256 + co)*8 + e] = bf16(ew2[co][ch*32+g*8+e][pos] * s[co]),
// f = ch*9+pos, ch=0..3
__global__ __launch_bounds__(256) void k_wprep2(
    const float* __restrict__ w, const float* __restrict__ bng,
    const float* __restrict__ bnv, __hip_bfloat16* __restrict__ wp2)
{
    int i = blockIdx.x*256 + threadIdx.x;      // [0, 294912)
    int e   = i & 7;
    int co  = (i >> 3) & 255;
    int g   = (i >> 11) & 3;
    int f   = i >> 13;
    int ch  = f / 9;
    int pos = f - 9*ch;
    float s = bng[co] / sqrtf(bnv[co] + 1e-5f);
    wp2[i] = __float2bfloat16(w[co*1152 + (ch*32 + g*8 + e)*9 + pos] * s);
}

// ---------------- K2 v2: enc2 as MFMA conv + masked mean partials -------------
// Grid (16,4): 16 tiles (8 row x 2 col) over 30x30 valid output, per batch.
// 4 waves x 64co (4 slices of 16). Writes per-tile partial sums [b][tile][co].
__global__ __launch_bounds__(256) void k_enc2m(
    const float* __restrict__ e1, const __hip_bfloat16* __restrict__ wp2,
    const float* __restrict__ bias, const float* __restrict__ g_,
    const float* __restrict__ bb, const float* __restrict__ m_,
    const float* __restrict__ v_, float* __restrict__ partial)
{
    __shared__ __align__(16) char lA[6*18*16*16];   // 27648 B
    const int tid = threadIdx.x;
    const int wid = tid >> 6, lane = tid & 63;
    const int l15 = lane & 15, lg = lane >> 4;
    const int b = blockIdx.y, tile = blockIdx.x;
    const int toh = (tile >> 1) * 4;
    const int tow = (tile & 1) * 16;

    // stage e1 halo: rows toh..toh+5, cols tow..tow+17 (masked), 128 ci, bf16
    for (int i = tid; i < 13824; i += 256){
        int c  = i % 18;
        int t  = i / 18;
        int r  = t % 6;
        int ci = t / 6;
        int ih = toh + r, iw = tow + c;
        unsigned short bits = 0;
        if (ih < 32 && iw < 32)
            bits = bf_bits(e1[((size_t)(b*128+ci) << 10) + ih*32 + iw]);
        *(unsigned short*)(lA + ((r*18+c)*16 + ((ci>>3) ^ (c&7)))*16 + (ci&7)*2) = bits;
    }
    __syncthreads();

    f32x4 acc[4][4];
    #pragma unroll
    for (int s = 0; s < 4; ++s)
        #pragma unroll
        for (int n = 0; n < 4; ++n) acc[s][n] = (f32x4){0.f,0.f,0.f,0.f};

    #pragma unroll
    for (int ch = 0; ch < 4; ++ch){
        #pragma unroll
        for (int pos = 0; pos < 9; ++pos){
            const int f = ch*9 + pos;
            const int kh = pos/3, kw = pos - 3*(pos/3);
            bf16x8 bx[4];
            #pragma unroll
            for (int n = 0; n < 4; ++n){
                const int rr = n + kh, cc = l15 + kw;
                bx[n] = *(const bf16x8*)(lA + ((rr*18+cc)*16 + ((ch*4+lg) ^ (cc&7)))*16);
            }
            #pragma unroll
            for (int s = 0; s < 4; ++s){
                const int coA = wid*64 + s*16 + l15;
                bf16x8 aw = *(const bf16x8*)(wp2 + ((size_t)(f*4 + lg)*256 + coA)*8);
                #pragma unroll
                for (int n = 0; n < 4; ++n)
                    acc[s][n] = __builtin_amdgcn_mfma_f32_16x16x32_bf16(aw, bx[n], acc[s][n], 0,0,0);
            }
        }
    }

    // epilogue: +bs, lrelu, mask, sum over the 64-px tile, write partials
    const int ow = tow + l15;
    const bool owok = ow < 30;
    #pragma unroll
    for (int s = 0; s < 4; ++s){
        #pragma unroll
        for (int r = 0; r < 4; ++r){
            const int co = wid*64 + s*16 + lg*4 + r;
            float sb = g_[co] / sqrtf(v_[co] + 1e-5f);
            float bs = (bias[co] - m_[co])*sb + bb[co];
            float th = 0.f;
            #pragma unroll
            for (int n = 0; n < 4; ++n){
                if (owok && (toh + n) < 30)
                    th += lrelu_f(acc[s][n][r] + bs);
            }
            th += __shfl_xor(th, 1);
            th += __shfl_xor(th, 2);
            th += __shfl_xor(th, 4);
            th += __shfl_xor(th, 8);
            if (l15 == 0)
                partial[((size_t)(b*16 + tile))*256 + co] = th;
        }
    }
}

// ---------------- K2red: reduce 16 tile-partials -> mean ----------------------
__global__ __launch_bounds__(256) void k_enc2red(
    const float* __restrict__ partial, float* __restrict__ fvec)
{
    int idx = blockIdx.x*256 + threadIdx.x;    // [0,1024): b*256+co
    int b = idx >> 8, co = idx & 255;
    float s = 0.f;
    #pragma unroll
    for (int t = 0; t < 16; ++t)
        s += partial[((size_t)(b*16 + t))*256 + co];
    fvec[idx] = s * (1.f/900.f);
}

// ---------------- K3: MLP + kernel-prediction head ---------------------------
__global__ __launch_bounds__(256) void k_mlp(
    const float* __restrict__ fvec,
    const float* __restrict__ mw1, const float* __restrict__ mb1,
    const float* __restrict__ mw2, const float* __restrict__ mb2,
    const float* __restrict__ kw1, const float* __restrict__ kw2,
    float* __restrict__ kern)
{
    __shared__ float fs[256], h1[256], emb[256], k1[128];
    int b = blockIdx.x, t = threadIdx.x;
    fs[t] = fvec[b*256+t];
    __syncthreads();
    {
        float acc = mb1[t];
        const float* wr = mw1 + t*256;
        for (int i=0;i<256;++i) acc += fs[i]*wr[i];
        h1[t] = lrelu_f(acc);
    }
    __syncthreads();
    {
        float acc = mb2[t];
        const float* wr = mw2 + t*256;
        for (int i=0;i<256;++i) acc += h1[i]*wr[i];
        emb[t] = acc;
    }
    __syncthreads();
    if (t < 128){
        float acc = 0.f;
        const float* wr = kw1 + t*256;
        for (int i=0;i<256;++i) acc += emb[i]*wr[i];
        k1[t] = lrelu_f(acc);
    }
    __syncthreads();
    for (int o=t; o<576; o+=256){
        float acc = 0.f;
        const float* wr = kw2 + o*128;
        for (int i=0;i<128;++i) acc += k1[i]*wr[i];
        kern[b*576+o] = acc;
    }
}

// ---------------- K4: fused {dyn depthwise + 1x1 + CA + combine}, MFMA --------
__global__ __launch_bounds__(256) void k_fuse(
    const float* __restrict__ x, const float* __restrict__ kern,
    const float* __restrict__ cw, const float* __restrict__ cb,
    const float* __restrict__ caw1, const float* __restrict__ caw2,
    __hip_bfloat16* __restrict__ buf)
{
    __shared__ __align__(16) char lA [6*18*128];   // x tile [r][c][slot^(c&7)][8ci]
    __shared__ __align__(16) char lD [64*128];     // dw    [px][slot^(px&7)][8ci]
    __shared__ __align__(16) char lA1[64*64];      // a1    [px][slot^(px&3)][8j]
    __shared__ __align__(16) char lW1[64*128];     // cw    [co][slot^(co&7)][8ci]
    __shared__ __align__(16) char lWc[32*128];     // caw1  [co][slot^(co&7)][8ci]
    __shared__ __align__(16) char lW2[64*64];      // caw2  [co][slot^(co&3)][8j]
    __shared__ float kern_s[576];

    const int tid = threadIdx.x;
    const int wid = tid >> 6, lane = tid & 63;
    const int l15 = lane & 15, lg = lane >> 4;
    const int b = blockIdx.y;
    const int toh = (blockIdx.x >> 4) * 4;
    const int tow = (blockIdx.x & 15) * 16;
    const int row0 = toh - 1, col0 = tow - 1;

    for (int i = tid; i < 6*18*64; i += 256){
        int c  = i % 18;
        int t  = i / 18;
        int r  = t % 6;
        int ci = t / 6;
        int ih = row0 + r, iw = col0 + c;
        unsigned short bits = 0;
        if (ih >= 0 && ih < 256 && iw >= 0 && iw < 256)
            bits = bf_bits(x[((size_t)(b*64+ci) << 16) + ih*256 + iw]);
        *(unsigned short*)(lA + ((r*18+c)*8 + ((ci>>3) ^ (c&7)))*16 + (ci&7)*2) = bits;
    }
    for (int i = tid; i < 4096; i += 256){
        int co = i >> 6, ci = i & 63;
        *(unsigned short*)(lW1 + (co*8 + ((ci>>3) ^ (co&7)))*16 + (ci&7)*2) = bf_bits(cw[co*64+ci]);
    }
    for (int i = tid; i < 2048; i += 256){
        int co = i >> 6, ci = i & 63;
        *(unsigned short*)(lWc + (co*8 + ((ci>>3) ^ (co&7)))*16 + (ci&7)*2) = bf_bits(caw1[co*64+ci]);
    }
    for (int i = tid; i < 2048; i += 256){
        int co = i >> 5, j = i & 31;
        *(unsigned short*)(lW2 + (co*4 + ((j>>3) ^ (co&3)))*16 + (j&7)*2) = bf_bits(caw2[co*32+j]);
    }
    for (int i = tid; i < 576; i += 256) kern_s[i] = kern[b*576 + i];
    __syncthreads();

    const int m1 = wid & 1;
    const int nb = (wid >> 1) * 2;
    f32x4 a1acc[2] = {{0.f,0.f,0.f,0.f},{0.f,0.f,0.f,0.f}};
    const int coA1 = m1*16 + l15;
    #pragma unroll
    for (int ch = 0; ch < 2; ++ch){
        bf16x8 aA = *(const bf16x8*)(lWc + (coA1*8 + ((ch*4+lg) ^ (coA1&7)))*16);
        #pragma unroll
        for (int t = 0; t < 2; ++t){
            int n = nb + t;
            int cc = l15 + 1, rr = n + 1;
            bf16x8 bX = *(const bf16x8*)(lA + ((rr*18+cc)*8 + ((ch*4+lg) ^ (cc&7)))*16);
            a1acc[t] = __builtin_amdgcn_mfma_f32_16x16x32_bf16(aA, bX, a1acc[t], 0,0,0);
        }
    }

    {
        const int px = tid & 63;
        const int prow = px >> 4, pcol = px & 15;
        const int ci0 = (tid >> 6) * 16;
        #pragma unroll
        for (int j = 0; j < 16; ++j){
            int ci = ci0 + j;
            const float* kr = kern_s + ci*9;
            float acc = 0.f;
            #pragma unroll
            for (int kh = 0; kh < 3; ++kh)
                #pragma unroll
                for (int kw = 0; kw < 3; ++kw){
                    int r = prow + kh, c = pcol + kw;
                    float xv = bf_val(lA + ((r*18+c)*8 + ((ci>>3) ^ (c&7)))*16 + (ci&7)*2);
                    acc += xv * kr[kh*3+kw];
                }
            *(unsigned short*)(lD + (px*8 + ((ci>>3) ^ (px&7)))*16 + (ci&7)*2)
                = bf_bits(lrelu_f(acc));
        }
    }

    #pragma unroll
    for (int t = 0; t < 2; ++t){
        int n = nb + t;
        int px = n*16 + l15;
        #pragma unroll
        for (int r = 0; r < 4; ++r){
            int j = m1*16 + lg*4 + r;
            *(unsigned short*)(lA1 + (px*4 + ((j>>3) ^ (px&3)))*16 + (j&7)*2)
                = bf_bits(lrelu_f(a1acc[t][r]));
        }
    }
    __syncthreads();

    f32x4 dynacc[4] = {{0.f,0.f,0.f,0.f},{0.f,0.f,0.f,0.f},{0.f,0.f,0.f,0.f},{0.f,0.f,0.f,0.f}};
    f32x4 attacc[4] = {{0.f,0.f,0.f,0.f},{0.f,0.f,0.f,0.f},{0.f,0.f,0.f,0.f},{0.f,0.f,0.f,0.f}};
    const int coA = wid*16 + l15;
    #pragma unroll
    for (int ch = 0; ch < 2; ++ch){
        bf16x8 aW = *(const bf16x8*)(lW1 + (coA*8 + ((ch*4+lg) ^ (coA&7)))*16);
        #pragma unroll
        for (int n = 0; n < 4; ++n){
            int px = n*16 + l15;
            bf16x8 bD = *(const bf16x8*)(lD + (px*8 + ((ch*4+lg) ^ (px&7)))*16);
            dynacc[n] = __builtin_amdgcn_mfma_f32_16x16x32_bf16(aW, bD, dynacc[n], 0,0,0);
        }
    }
    {
        bf16x8 aW2 = *(const bf16x8*)(lW2 + (coA*4 + (lg ^ (coA&3)))*16);
        #pragma unroll
        for (int n = 0; n < 4; ++n){
            int px = n*16 + l15;
            bf16x8 bA1 = *(const bf16x8*)(lA1 + (px*4 + (lg ^ (px&3)))*16);
            attacc[n] = __builtin_amdgcn_mfma_f32_16x16x32_bf16(aW2, bA1, attacc[n], 0,0,0);
        }
    }

    #pragma unroll
    for (int n = 0; n < 4; ++n){
        int oh = toh + n, ow = tow + l15;
        #pragma unroll
        for (int r = 0; r < 4; ++r){
            int co = wid*16 + lg*4 + r;
            size_t oi = ((size_t)(b*64+co) << 16) + oh*256 + ow;
            float att = fmaxf(attacc[n][r], 0.f);
            float v = lrelu_f(dynacc[n][r] + cb[co] + x[oi]*att);
            buf[oi] = __float2bfloat16(v);
        }
    }
}

// ---------------- K_wprep: pack conv weights into MFMA A-fragment layout ------
__global__ __launch_bounds__(256) void k_wprep(
    const float* __restrict__ w, __hip_bfloat16* __restrict__ wp)
{
    int i = blockIdx.x*256 + threadIdx.x;      // [0, 36864)
    int e   = i & 7;
    int coA = (i >> 3) & 63;
    int g   = (i >> 9) & 3;
    int f   = i >> 11;
    int ch  = (f >= 9) ? 1 : 0;
    int pos = f - 9*ch;
    wp[i] = __float2bfloat16(w[coA*576 + (ch*32 + g*8 + e)*9 + pos]);
}

// ---------------- K5 v3: MFMA implicit-GEMM conv ------------------------------
template<typename TIN, int STRIDE, int RESMODE, int ACT, int OUTBF>
__global__ __launch_bounds__(256) void k_conv_mfma(
    const TIN* __restrict__ in, const __hip_bfloat16* __restrict__ wp,
    const float* __restrict__ bias, const void* __restrict__ res,
    void* __restrict__ outp, int H, int W, int Ho, int Wo)
{
    constexpr int TH   = (STRIDE==1) ? 16 : 8;
    constexpr int ROWS = (STRIDE==1) ? TH+2 : 2*TH+1;   // 18 / 17
    constexpr int COLS = (STRIDE==1) ? 18 : 33;
    constexpr int EPC  = (sizeof(TIN)==2) ? 8 : 4;      // elems per 16B chunk
    constexpr int NC   = (COLS + 2*EPC - 2) / EPC;      // chunks per halo row
    __shared__ __align__(16) char lA[ROWS*COLS*128];
    const int tid = threadIdx.x;
    const int wid = tid >> 6, lane = tid & 63;
    const int l15 = lane & 15, g = lane >> 4;
    const int b   = blockIdx.y;
    const int tilesW = Wo >> 4;
    const int toh = (blockIdx.x / tilesW) * TH;
    const int tow = (blockIdx.x % tilesW) * 16;
    const int row0 = toh*STRIDE - 1;
    const int col0 = tow*STRIDE - 1;

    bf16x8 aw[18];
    const int coA = wid*16 + l15;
    #pragma unroll
    for (int f = 0; f < 18; ++f)
        aw[f] = *(const bf16x8*)(wp + ((f*4 + g)*64 + coA)*8);

    const int astart = tow*STRIDE - EPC;
    const bool cfast = (astart >= 0) && (astart + NC*EPC <= W);
    for (int i = tid; i < ROWS*64; i += 256){
        const int ci = i & 63, r = i >> 6;
        const int ih = row0 + r;
        if (ih < 0 || ih >= H){
            #pragma unroll
            for (int c = 0; c < COLS; ++c)
                *(unsigned short*)(lA + ((r*COLS+c)*8 + ((ci>>3)^(c&7)))*16 + (ci&7)*2) = 0;
        } else {
            const TIN* srow = in + ((size_t)(b*64+ci))*H*W + (size_t)ih*W;
            if (cfast){
                if constexpr (sizeof(TIN) == 2){
                    u16x8 chk[NC];
                    #pragma unroll
                    for (int k = 0; k < NC; ++k)
                        chk[k] = *(const u16x8*)(srow + astart + k*8);
                    #pragma unroll
                    for (int c = 0; c < COLS; ++c){
                        const int idx = 7 + c;
                        unsigned short bits = chk[idx>>3][idx&7];
                        *(unsigned short*)(lA + ((r*COLS+c)*8 + ((ci>>3)^(c&7)))*16 + (ci&7)*2) = bits;
                    }
                } else {
                    f32x4 chk[NC];
                    #pragma unroll
                    for (int k = 0; k < NC; ++k)
                        chk[k] = *(const f32x4*)(srow + astart + k*4);
                    #pragma unroll
                    for (int c = 0; c < COLS; ++c){
                        const int idx = 3 + c;
                        unsigned short bits = bf_bits(chk[idx>>2][idx&3]);
                        *(unsigned short*)(lA + ((r*COLS+c)*8 + ((ci>>3)^(c&7)))*16 + (ci&7)*2) = bits;
                    }
                }
            } else {
                #pragma unroll
                for (int c = 0; c < COLS; ++c){
                    int iw = col0 + c;
                    unsigned short bits = 0;
                    if (iw >= 0 && iw < W) bits = bf_bits(srow[iw]);
                    *(unsigned short*)(lA + ((r*COLS+c)*8 + ((ci>>3)^(c&7)))*16 + (ci&7)*2) = bits;
                }
            }
        }
    }
    __syncthreads();

    float bv[4];
    #pragma unroll
    for (int r = 0; r < 4; ++r) bv[r] = bias[wid*16 + g*4 + r];
    const float*          resF = (const float*)res;
    const __hip_bfloat16* resB = (const __hip_bfloat16*)res;

    if constexpr (STRIDE == 1){
        bf16x8 Bw[3][2][3];
        auto ldrow = [&](int rr, int slot){
            #pragma unroll
            for (int ch = 0; ch < 2; ++ch)
                #pragma unroll
                for (int kw = 0; kw < 3; ++kw){
                    const int cc = l15 + kw;
                    Bw[slot][ch][kw] = *(const bf16x8*)(lA + ((rr*COLS + cc)*8 + ((ch*4+g) ^ (cc&7)))*16);
                }
        };
        ldrow(0, 0);
        ldrow(1, 1);
        #pragma unroll
        for (int n = 0; n < TH; ++n){
            ldrow(n+2, (n+2)%3);
            f32x4 acc = {0.f,0.f,0.f,0.f};
            #pragma unroll
            for (int kh = 0; kh < 3; ++kh)
                #pragma unroll
                for (int ch = 0; ch < 2; ++ch)
                    #pragma unroll
                    for (int kw = 0; kw < 3; ++kw)
                        acc = __builtin_amdgcn_mfma_f32_16x16x32_bf16(
                                aw[ch*9 + kh*3 + kw], Bw[(n+kh)%3][ch][kw], acc, 0, 0, 0);
            const int oh = toh + n, ow = tow + l15;
            #pragma unroll
            for (int r = 0; r < 4; ++r){
                int co = wid*16 + g*4 + r;
                size_t oi = ((size_t)(b*64+co)*Ho + oh)*Wo + ow;
                float v = acc[r] + bv[r];
                if (ACT) v = fmaxf(v, 0.f);
                if (RESMODE == 1) v += resF[oi];
                if (RESMODE == 2) v += __bfloat162float(resB[oi]);
                if (OUTBF) ((__hip_bfloat16*)outp)[oi] = __float2bfloat16(v);
                else       ((float*)outp)[oi] = v;
            }
        }
    } else {
        #pragma unroll
        for (int n = 0; n < TH; ++n){
            f32x4 acc = {0.f,0.f,0.f,0.f};
            #pragma unroll
            for (int ch = 0; ch < 2; ++ch)
                #pragma unroll
                for (int pos = 0; pos < 9; ++pos){
                    const int kh = pos/3, kw = pos - 3*(pos/3);
                    const int cc = l15*STRIDE + kw;
                    const int rr = n*STRIDE + kh;
                    bf16x8 bx = *(const bf16x8*)(lA + ((rr*COLS + cc)*8 + ((ch*4+g) ^ (cc&7)))*16);
                    acc = __builtin_amdgcn_mfma_f32_16x16x32_bf16(aw[ch*9+pos], bx, acc, 0, 0, 0);
                }
            const int oh = toh + n, ow = tow + l15;
            #pragma unroll
            for (int r = 0; r < 4; ++r){
                int co = wid*16 + g*4 + r;
                size_t oi = ((size_t)(b*64+co)*Ho + oh)*Wo + ow;
                float v = acc[r] + bv[r];
                if (ACT) v = fmaxf(v, 0.f);
                if (RESMODE == 1) v += resF[oi];
                if (RESMODE == 2) v += __bfloat162float(resB[oi]);
                if (OUTBF) ((__hip_bfloat16*)outp)[oi] = __float2bfloat16(v);
                else       ((float*)outp)[oi] = v;
            }
        }
    }
}

// ---------------- host ---------------------------------------------------------
extern "C" void kernel_launch(void* const* d_in, const int* in_sizes, int n_in,
                              void* d_out, int out_size, void* d_ws, size_t ws_size,
                              hipStream_t stream) {
    const float* x    = (const float*)d_in[0];
    const float* y    = (const float*)d_in[1];
    const float* ew1  = (const float*)d_in[2];
    const float* eb1  = (const float*)d_in[3];
    const float* bn1g = (const float*)d_in[4];
    const float* bn1b = (const float*)d_in[5];
    const float* bn1m = (const float*)d_in[6];
    const float* bn1v = (const float*)d_in[7];
    const float* ew2  = (const float*)d_in[8];
    const float* eb2  = (const float*)d_in[9];
    const float* bn2g = (const float*)d_in[10];
    const float* bn2b = (const float*)d_in[11];
    const float* bn2m = (const float*)d_in[12];
    const float* bn2v = (const float*)d_in[13];
    const float* mw1  = (const float*)d_in[14];
    const float* mb1  = (const float*)d_in[15];
    const float* mw2  = (const float*)d_in[16];
    const float* mb2  = (const float*)d_in[17];
    const float* kw1  = (const float*)d_in[18];
    const float* kw2  = (const float*)d_in[19];
    const float* cw   = (const float*)d_in[20];
    const float* cb   = (const float*)d_in[21];
    const float* caw1 = (const float*)d_in[22];
    const float* caw2 = (const float*)d_in[23];
    const float* c1w  = (const float*)d_in[24];
    const float* c1b  = (const float*)d_in[25];
    const float* c2w  = (const float*)d_in[26];
    const float* c2b  = (const float*)d_in[27];
    const float* r1w  = (const float*)d_in[28];
    const float* r1b  = (const float*)d_in[29];
    const float* r2w  = (const float*)d_in[30];
    const float* r2b  = (const float*)d_in[31];

    // ws layout (proven >= 33.57 MB):
    //   buf bf16 [0, 33554432)  (k_fuse -> c1; dead after c1)
    //     e1 f32 overlays [0, 2097152)   (dead after enc2m)
    //     wp2 (enc2 prepped weights) @ 2097152 (589824 B, dead after enc2m)
    //     enc2 partials @ 2686976 (65536 B, dead after enc2red)
    //     after c1: t2 bf16 [0, 8388608), u2 [8388608, 16777216),
    //               t3 [16777216, 18874368), u3 [18874368, 20971520),
    //               wpB (3 x 147456 B) @ 29360128
    //   fv f32 @ 33554432, kern f32 @ 33558528
    char* wsc = (char*)d_ws;
    __hip_bfloat16* buf = (__hip_bfloat16*)wsc;
    float*          e1  = (float*)wsc;
    __hip_bfloat16* wp2 = (__hip_bfloat16*)(wsc + 2097152);
    float*          part= (float*)(wsc + 2686976);
    __hip_bfloat16* t2  = (__hip_bfloat16*)wsc;
    __hip_bfloat16* u2  = (__hip_bfloat16*)(wsc + 8388608);
    __hip_bfloat16* t3  = (__hip_bfloat16*)(wsc + 16777216);
    __hip_bfloat16* u3  = (__hip_bfloat16*)(wsc + 18874368);
    __hip_bfloat16* wpB0= (__hip_bfloat16*)(wsc + 29360128);
    __hip_bfloat16* wpB1= (__hip_bfloat16*)(wsc + 29360128 + 147456);
    __hip_bfloat16* wpB2= (__hip_bfloat16*)(wsc + 29360128 + 294912);
    float*          fv  = (float*)(wsc + 33554432);
    float*          kern= (float*)(wsc + 33558528);

    float* ob   = (float*)d_out;            // out  (4,64,256,256) f32
    float* ob1  = ob + 16777216;            // out2 (4,64,128,128) f32
    float* ob2  = ob + 20971520;            // out3 (4,64,64,64)   f32
    __hip_bfloat16* wpA = (__hip_bfloat16*)((char*)d_out + 87932928);

    k_wprep<<<dim3(144),256,0,stream>>>(c1w, wpA);
    k_wprep2<<<dim3(1152),256,0,stream>>>(ew2, bn2g, bn2v, wp2);
    k_enc1<<<dim3(2048),256,0,stream>>>(y, ew1, eb1, bn1g, bn1b, bn1m, bn1v, e1);
    k_enc2m<<<dim3(16,4),256,0,stream>>>(e1, wp2, eb2, bn2g, bn2b, bn2m, bn2v, part);
    k_enc2red<<<dim3(4),256,0,stream>>>(part, fv);
    k_mlp<<<dim3(4),256,0,stream>>>(fv, mw1, mb1, mw2, mb2, kw1, kw2, kern);
    k_fuse<<<dim3(1024,4),256,0,stream>>>(x, kern, cw, cb, caw1, caw2, buf);

    // out0 = conv3x3(pre) + bias + x  -> f32 d_out   (16x16 tiles)
    k_conv_mfma<__hip_bfloat16,1,1,0,0><<<dim3(256,4),256,0,stream>>>(buf, wpA, c1b, x, ob, 256,256,256,256);
    // prep remaining weights into the now-dead buf tail
    k_wprep<<<dim3(144),256,0,stream>>>(c2w, wpB0);
    k_wprep<<<dim3(144),256,0,stream>>>(r1w, wpB1);
    k_wprep<<<dim3(144),256,0,stream>>>(r2w, wpB2);
    // t2 = conv3x3 s2 (out0 f32) -> bf16             (8x16 tiles: 16*8)
    k_conv_mfma<float,2,0,0,1><<<dim3(128,4),256,0,stream>>>(ob, wpB0, c2b, nullptr, t2, 256,256,128,128);
    // u2 = relu(conv3x3(t2)) -> bf16                 (8*8)
    k_conv_mfma<__hip_bfloat16,1,0,1,1><<<dim3(64,4),256,0,stream>>>(t2, wpB1, r1b, nullptr, u2, 128,128,128,128);
    // out2 = t2 + conv3x3(u2) -> f32 d_out
    k_conv_mfma<__hip_bfloat16,1,2,0,0><<<dim3(64,4),256,0,stream>>>(u2, wpB2, r2b, t2, ob1, 128,128,128,128);
    // t3 = conv3x3 s2 (out2 f32) -> bf16             (8*4)
    k_conv_mfma<float,2,0,0,1><<<dim3(32,4),256,0,stream>>>(ob1, wpB0, c2b, nullptr, t3, 128,128,64,64);
    // u3 = relu(conv3x3(t3)) -> bf16                 (4*4)
    k_conv_mfma<__hip_bfloat16,1,0,1,1><<<dim3(16,4),256,0,stream>>>(t3, wpB1, r1b, nullptr, u3, 64,64,64,64);
    // out3 = t3 + conv3x3(u3) -> f32 d_out
    k_conv_mfma<__hip_bfloat16,1,2,0,0><<<dim3(16,4),256,0,stream>>>(u3, wpB2, r2b, t3, ob2, 64,64,64,64);
}

// Round 17
// 540.690 us; speedup vs baseline: 1.9872x; 1.3310x over previous
//
#include <hip/hip_runtime.h>
#include <hip/hip_bf16.h>
#include <cstddef>
#include <cstdint>

#define DEV __device__ __forceinline__

DEV float lrelu_f(float z){ return z >= 0.f ? z : 0.1f*z; }

typedef __bf16 bf16x8 __attribute__((ext_vector_type(8)));
typedef float  f32x4  __attribute__((ext_vector_type(4)));
typedef unsigned short u16x8 __attribute__((ext_vector_type(8)));

DEV unsigned short bf_bits(float v){
    __hip_bfloat16 h = __float2bfloat16(v);
    unsigned short s; __builtin_memcpy(&s, &h, 2); return s;
}
DEV unsigned short bf_bits(__hip_bfloat16 v){
    unsigned short s; __builtin_memcpy(&s, &v, 2); return s;
}
DEV float u16_to_f(unsigned short s){
    unsigned int u = ((unsigned int)s) << 16;
    float f; __builtin_memcpy(&f, &u, 4); return f;
}

// ---------------- K_wprep1: pack enc1 weights (BN scale folded) ---------------
// wp1[((f*4+g)*128+co)*8+e] = bf16(ew1[co][ch*32+g*8+e][pos] * s[co]), f=ch*9+pos
__global__ __launch_bounds__(256) void k_wprep1(
    const float* __restrict__ w, const float* __restrict__ bng,
    const float* __restrict__ bnv, __hip_bfloat16* __restrict__ wp1)
{
    int i = blockIdx.x*256 + threadIdx.x;      // [0, 73728)
    int e   = i & 7;
    int co  = (i >> 3) & 127;
    int g   = (i >> 10) & 3;
    int f   = i >> 12;
    int ch  = (f >= 9) ? 1 : 0;
    int pos = f - 9*ch;
    float s = bng[co] / sqrtf(bnv[co] + 1e-5f);
    wp1[i] = __float2bfloat16(w[co*576 + (ch*32 + g*8 + e)*9 + pos] * s);
}

// ---------------- K1 v2: enc1 as MFMA conv (3x3 s2 p1 + BN + lrelu) -----------
// Grid (16,4): 16 tiles (8 row x 2 col) of 4x16 px over 32x32 out; 4 waves x
// 2 slices x 16co = 128 co. Output e1 bf16 [4,128,32,32].
__global__ __launch_bounds__(256) void k_enc1m(
    const float* __restrict__ y, const __hip_bfloat16* __restrict__ wp1,
    const float* __restrict__ eb1, const float* __restrict__ bng,
    const float* __restrict__ bnb, const float* __restrict__ bnm,
    const float* __restrict__ bnv, __hip_bfloat16* __restrict__ e1b)
{
    __shared__ __align__(16) char lA[9*33*128];   // 38016 B
    const int tid = threadIdx.x;
    const int wid = tid >> 6, lane = tid & 63;
    const int l15 = lane & 15, lg = lane >> 4;
    const int b = blockIdx.y, tile = blockIdx.x;
    const int toh = (tile >> 1) * 4;
    const int tow = (tile & 1) * 16;
    const int row0 = toh*2 - 1, col0 = tow*2 - 1;

    for (int i = tid; i < 9*33*64; i += 256){
        int c  = i % 33;
        int t  = i / 33;
        int r  = t % 9;
        int ci = t / 9;
        int ih = row0 + r, iw = col0 + c;
        unsigned short bits = 0;
        if (ih >= 0 && ih < 64 && iw >= 0 && iw < 64)
            bits = bf_bits(y[((size_t)(b*64+ci) << 12) + ih*64 + iw]);
        *(unsigned short*)(lA + ((r*33+c)*8 + ((ci>>3) ^ (c&7)))*16 + (ci&7)*2) = bits;
    }
    __syncthreads();

    f32x4 acc[2][4];
    #pragma unroll
    for (int s = 0; s < 2; ++s)
        #pragma unroll
        for (int n = 0; n < 4; ++n) acc[s][n] = (f32x4){0.f,0.f,0.f,0.f};

    #pragma unroll
    for (int ch = 0; ch < 2; ++ch){
        #pragma unroll
        for (int pos = 0; pos < 9; ++pos){
            const int f = ch*9 + pos;
            const int kh = pos/3, kw = pos - 3*(pos/3);
            bf16x8 bx[4];
            #pragma unroll
            for (int n = 0; n < 4; ++n){
                const int rr = n*2 + kh, cc = l15*2 + kw;
                bx[n] = *(const bf16x8*)(lA + ((rr*33+cc)*8 + ((ch*4+lg) ^ (cc&7)))*16);
            }
            #pragma unroll
            for (int s = 0; s < 2; ++s){
                const int coA = wid*32 + s*16 + l15;
                bf16x8 aw = *(const bf16x8*)(wp1 + ((size_t)(f*4 + lg)*128 + coA)*8);
                #pragma unroll
                for (int n = 0; n < 4; ++n)
                    acc[s][n] = __builtin_amdgcn_mfma_f32_16x16x32_bf16(aw, bx[n], acc[s][n], 0,0,0);
            }
        }
    }

    #pragma unroll
    for (int s = 0; s < 2; ++s){
        #pragma unroll
        for (int r = 0; r < 4; ++r){
            const int co = wid*32 + s*16 + lg*4 + r;
            float sb = bng[co] / sqrtf(bnv[co] + 1e-5f);
            float bs = (eb1[co] - bnm[co])*sb + bnb[co];
            #pragma unroll
            for (int n = 0; n < 4; ++n){
                int oh = toh + n, ow = tow + l15;
                e1b[((size_t)(b*128+co) << 10) + oh*32 + ow]
                    = __float2bfloat16(lrelu_f(acc[s][n][r] + bs));
            }
        }
    }
}

// ---------------- K_wprep2: pack enc2 weights (BN scale folded) ---------------
__global__ __launch_bounds__(256) void k_wprep2(
    const float* __restrict__ w, const float* __restrict__ bng,
    const float* __restrict__ bnv, __hip_bfloat16* __restrict__ wp2)
{
    int i = blockIdx.x*256 + threadIdx.x;      // [0, 294912)
    int e   = i & 7;
    int co  = (i >> 3) & 255;
    int g   = (i >> 11) & 3;
    int f   = i >> 13;
    int ch  = f / 9;
    int pos = f - 9*ch;
    float s = bng[co] / sqrtf(bnv[co] + 1e-5f);
    wp2[i] = __float2bfloat16(w[co*1152 + (ch*32 + g*8 + e)*9 + pos] * s);
}

// ---------------- K2 v2: enc2 as MFMA conv + masked mean partials -------------
__global__ __launch_bounds__(256) void k_enc2m(
    const __hip_bfloat16* __restrict__ e1b, const __hip_bfloat16* __restrict__ wp2,
    const float* __restrict__ bias, const float* __restrict__ g_,
    const float* __restrict__ bb, const float* __restrict__ m_,
    const float* __restrict__ v_, float* __restrict__ partial)
{
    __shared__ __align__(16) char lA[6*18*16*16];   // 27648 B
    const int tid = threadIdx.x;
    const int wid = tid >> 6, lane = tid & 63;
    const int l15 = lane & 15, lg = lane >> 4;
    const int b = blockIdx.y, tile = blockIdx.x;
    const int toh = (tile >> 1) * 4;
    const int tow = (tile & 1) * 16;

    for (int i = tid; i < 13824; i += 256){
        int c  = i % 18;
        int t  = i / 18;
        int r  = t % 6;
        int ci = t / 6;
        int ih = toh + r, iw = tow + c;
        unsigned short bits = 0;
        if (ih < 32 && iw < 32)
            bits = bf_bits(e1b[((size_t)(b*128+ci) << 10) + ih*32 + iw]);
        *(unsigned short*)(lA + ((r*18+c)*16 + ((ci>>3) ^ (c&7)))*16 + (ci&7)*2) = bits;
    }
    __syncthreads();

    f32x4 acc[4][4];
    #pragma unroll
    for (int s = 0; s < 4; ++s)
        #pragma unroll
        for (int n = 0; n < 4; ++n) acc[s][n] = (f32x4){0.f,0.f,0.f,0.f};

    #pragma unroll
    for (int ch = 0; ch < 4; ++ch){
        #pragma unroll
        for (int pos = 0; pos < 9; ++pos){
            const int f = ch*9 + pos;
            const int kh = pos/3, kw = pos - 3*(pos/3);
            bf16x8 bx[4];
            #pragma unroll
            for (int n = 0; n < 4; ++n){
                const int rr = n + kh, cc = l15 + kw;
                bx[n] = *(const bf16x8*)(lA + ((rr*18+cc)*16 + ((ch*4+lg) ^ (cc&7)))*16);
            }
            #pragma unroll
            for (int s = 0; s < 4; ++s){
                const int coA = wid*64 + s*16 + l15;
                bf16x8 aw = *(const bf16x8*)(wp2 + ((size_t)(f*4 + lg)*256 + coA)*8);
                #pragma unroll
                for (int n = 0; n < 4; ++n)
                    acc[s][n] = __builtin_amdgcn_mfma_f32_16x16x32_bf16(aw, bx[n], acc[s][n], 0,0,0);
            }
        }
    }

    const int ow = tow + l15;
    const bool owok = ow < 30;
    #pragma unroll
    for (int s = 0; s < 4; ++s){
        #pragma unroll
        for (int r = 0; r < 4; ++r){
            const int co = wid*64 + s*16 + lg*4 + r;
            float sb = g_[co] / sqrtf(v_[co] + 1e-5f);
            float bs = (bias[co] - m_[co])*sb + bb[co];
            float th = 0.f;
            #pragma unroll
            for (int n = 0; n < 4; ++n){
                if (owok && (toh + n) < 30)
                    th += lrelu_f(acc[s][n][r] + bs);
            }
            th += __shfl_xor(th, 1);
            th += __shfl_xor(th, 2);
            th += __shfl_xor(th, 4);
            th += __shfl_xor(th, 8);
            if (l15 == 0)
                partial[((size_t)(b*16 + tile))*256 + co] = th;
        }
    }
}

// ---------------- K2red -------------------------------------------------------
__global__ __launch_bounds__(256) void k_enc2red(
    const float* __restrict__ partial, float* __restrict__ fvec)
{
    int idx = blockIdx.x*256 + threadIdx.x;    // [0,1024)
    int b = idx >> 8, co = idx & 255;
    float s = 0.f;
    #pragma unroll
    for (int t = 0; t < 16; ++t)
        s += partial[((size_t)(b*16 + t))*256 + co];
    fvec[idx] = s * (1.f/900.f);
}

// ---------------- K3: MLP + kernel-prediction head ---------------------------
__global__ __launch_bounds__(256) void k_mlp(
    const float* __restrict__ fvec,
    const float* __restrict__ mw1, const float* __restrict__ mb1,
    const float* __restrict__ mw2, const float* __restrict__ mb2,
    const float* __restrict__ kw1, const float* __restrict__ kw2,
    float* __restrict__ kern)
{
    __shared__ float fs[256], h1[256], emb[256], k1[128];
    int b = blockIdx.x, t = threadIdx.x;
    fs[t] = fvec[b*256+t];
    __syncthreads();
    {
        float acc = mb1[t];
        const float* wr = mw1 + t*256;
        for (int i=0;i<256;++i) acc += fs[i]*wr[i];
        h1[t] = lrelu_f(acc);
    }
    __syncthreads();
    {
        float acc = mb2[t];
        const float* wr = mw2 + t*256;
        for (int i=0;i<256;++i) acc += h1[i]*wr[i];
        emb[t] = acc;
    }
    __syncthreads();
    if (t < 128){
        float acc = 0.f;
        const float* wr = kw1 + t*256;
        for (int i=0;i<256;++i) acc += emb[i]*wr[i];
        k1[t] = lrelu_f(acc);
    }
    __syncthreads();
    for (int o=t; o<576; o+=256){
        float acc = 0.f;
        const float* wr = kw2 + o*128;
        for (int i=0;i<128;++i) acc += k1[i]*wr[i];
        kern[b*576+o] = acc;
    }
}

// ---------------- K_wprepF: pack fuse weights (cw, caw1, caw2) ----------------
// cwf  @0    : [((ch*4+g)*64+co)*8+e] = cw[co][ch*32+g*8+e]        (4096)
// caw1f@4096 : [((ch*4+g)*32+co)*8+e] = caw1[co][ch*32+g*8+e]      (2048)
// caw2f@6144 : [(g*64+co)*8+e]        = caw2[co][g*8+e]            (2048)
__global__ __launch_bounds__(256) void k_wprepF(
    const float* __restrict__ cw, const float* __restrict__ caw1,
    const float* __restrict__ caw2, __hip_bfloat16* __restrict__ wpF)
{
    int i = blockIdx.x*256 + threadIdx.x;      // [0, 8192)
    if (i < 4096){
        int e = i&7, co = (i>>3)&63, g = (i>>9)&3, ch = i>>11;
        wpF[i] = __float2bfloat16(cw[co*64 + ch*32 + g*8 + e]);
    } else if (i < 6144){
        int j = i - 4096;
        int e = j&7, co = (j>>3)&31, g = (j>>8)&3, ch = j>>10;
        wpF[i] = __float2bfloat16(caw1[co*64 + ch*32 + g*8 + e]);
    } else if (i < 8192){
        int j = i - 6144;
        int e = j&7, co = (j>>3)&63, g = j>>9;
        wpF[i] = __float2bfloat16(caw2[co*32 + g*8 + e]);
    }
}

// ---------------- K4 v2: fused {dyn depthwise + 1x1 + CA + combine}, MFMA -----
// Weights from global prepped frags (wpF); LDS = lA + lD + lA1 + kern only.
// Depthwise vectorized: per-thread (px, ci-slot) with b128 LDS reads/writes.
__global__ __launch_bounds__(256) void k_fuse(
    const float* __restrict__ x, const float* __restrict__ kern,
    const __hip_bfloat16* __restrict__ wpF, const float* __restrict__ cb,
    __hip_bfloat16* __restrict__ buf)
{
    __shared__ __align__(16) char lA [6*18*128];   // 13824 B
    __shared__ __align__(16) char lD [64*128];     //  8192 B
    __shared__ __align__(16) char lA1[64*64];      //  4096 B
    __shared__ float kern_s[576];                  //  2304 B

    const int tid = threadIdx.x;
    const int wid = tid >> 6, lane = tid & 63;
    const int l15 = lane & 15, lg = lane >> 4;
    const int b = blockIdx.y;
    const int toh = (blockIdx.x >> 4) * 4;
    const int tow = (blockIdx.x & 15) * 16;
    const int row0 = toh - 1;
    const int col0 = tow - 1;

    // ---- stage x halo (vectorized f32x4 with guarded edge path) --------------
    const int astart = tow - 4;
    const bool cfast = (astart >= 0) && (astart + 24 <= 256);
    for (int i = tid; i < 6*64; i += 256){
        const int ci = i & 63, r = i >> 6;
        const int ih = row0 + r;
        if (ih < 0 || ih >= 256){
            #pragma unroll
            for (int c = 0; c < 18; ++c)
                *(unsigned short*)(lA + ((r*18+c)*8 + ((ci>>3)^(c&7)))*16 + (ci&7)*2) = 0;
        } else {
            const float* srow = x + ((size_t)(b*64+ci) << 16) + ih*256;
            if (cfast){
                f32x4 chk[6];
                #pragma unroll
                for (int k = 0; k < 6; ++k)
                    chk[k] = *(const f32x4*)(srow + astart + k*4);
                #pragma unroll
                for (int c = 0; c < 18; ++c){
                    const int idx = 3 + c;
                    unsigned short bits = bf_bits(chk[idx>>2][idx&3]);
                    *(unsigned short*)(lA + ((r*18+c)*8 + ((ci>>3)^(c&7)))*16 + (ci&7)*2) = bits;
                }
            } else {
                #pragma unroll
                for (int c = 0; c < 18; ++c){
                    int iw = col0 + c;
                    unsigned short bits = 0;
                    if (iw >= 0 && iw < 256) bits = bf_bits(srow[iw]);
                    *(unsigned short*)(lA + ((r*18+c)*8 + ((ci>>3)^(c&7)))*16 + (ci&7)*2) = bits;
                }
            }
        }
    }
    for (int i = tid; i < 576; i += 256) kern_s[i] = kern[b*576 + i];
    __syncthreads();

    // ---- a1 GEMM (caw1 . X) ---------------------------------------------------
    const int m1 = wid & 1;
    const int nb = (wid >> 1) * 2;
    f32x4 a1acc[2] = {{0.f,0.f,0.f,0.f},{0.f,0.f,0.f,0.f}};
    const int coA1 = m1*16 + l15;
    #pragma unroll
    for (int ch = 0; ch < 2; ++ch){
        bf16x8 aA = *(const bf16x8*)(wpF + 4096 + ((ch*4+lg)*32 + coA1)*8);
        #pragma unroll
        for (int t = 0; t < 2; ++t){
            int n = nb + t;
            int cc = l15 + 1, rr = n + 1;
            bf16x8 bX = *(const bf16x8*)(lA + ((rr*18+cc)*8 + ((ch*4+lg) ^ (cc&7)))*16);
            a1acc[t] = __builtin_amdgcn_mfma_f32_16x16x32_bf16(aA, bX, a1acc[t], 0,0,0);
        }
    }

    // ---- depthwise -> lD (vectorized: (px, slot) pairs, b128 reads/writes) ---
    {
        const int px = tid & 63;
        const int s0 = tid >> 6;
        const int prow = px >> 4, pcol = px & 15;
        #pragma unroll
        for (int t = 0; t < 2; ++t){
            const int sl = s0 + t*4;
            u16x8 xv[3][3];
            #pragma unroll
            for (int kh = 0; kh < 3; ++kh)
                #pragma unroll
                for (int kw = 0; kw < 3; ++kw){
                    const int r = prow + kh, c = pcol + kw;
                    xv[kh][kw] = *(const u16x8*)(lA + ((r*18+c)*8 + (sl ^ (c&7)))*16);
                }
            u16x8 outv;
            #pragma unroll
            for (int e = 0; e < 8; ++e){
                const int ci = sl*8 + e;
                const float* kr = kern_s + ci*9;
                float acc = 0.f;
                #pragma unroll
                for (int kh = 0; kh < 3; ++kh)
                    #pragma unroll
                    for (int kw = 0; kw < 3; ++kw)
                        acc += u16_to_f(xv[kh][kw][e]) * kr[kh*3+kw];
                outv[e] = bf_bits(lrelu_f(acc));
            }
            *(u16x8*)(lD + (px*8 + (sl ^ (px&7)))*16) = outv;
        }
    }

    // ---- a1 -> lrelu -> lA1 ---------------------------------------------------
    #pragma unroll
    for (int t = 0; t < 2; ++t){
        int n = nb + t;
        int px = n*16 + l15;
        #pragma unroll
        for (int r = 0; r < 4; ++r){
            int j = m1*16 + lg*4 + r;
            *(unsigned short*)(lA1 + (px*4 + ((j>>3) ^ (px&3)))*16 + (j&7)*2)
                = bf_bits(lrelu_f(a1acc[t][r]));
        }
    }
    __syncthreads();

    // ---- dyn & att GEMMs ------------------------------------------------------
    f32x4 dynacc[4] = {{0.f,0.f,0.f,0.f},{0.f,0.f,0.f,0.f},{0.f,0.f,0.f,0.f},{0.f,0.f,0.f,0.f}};
    f32x4 attacc[4] = {{0.f,0.f,0.f,0.f},{0.f,0.f,0.f,0.f},{0.f,0.f,0.f,0.f},{0.f,0.f,0.f,0.f}};
    const int coA = wid*16 + l15;
    #pragma unroll
    for (int ch = 0; ch < 2; ++ch){
        bf16x8 aW = *(const bf16x8*)(wpF + ((ch*4+lg)*64 + coA)*8);
        #pragma unroll
        for (int n = 0; n < 4; ++n){
            int px = n*16 + l15;
            bf16x8 bD = *(const bf16x8*)(lD + (px*8 + ((ch*4+lg) ^ (px&7)))*16);
            dynacc[n] = __builtin_amdgcn_mfma_f32_16x16x32_bf16(aW, bD, dynacc[n], 0,0,0);
        }
    }
    {
        bf16x8 aW2 = *(const bf16x8*)(wpF + 6144 + (lg*64 + coA)*8);
        #pragma unroll
        for (int n = 0; n < 4; ++n){
            int px = n*16 + l15;
            bf16x8 bA1 = *(const bf16x8*)(lA1 + (px*4 + (lg ^ (px&3)))*16);
            attacc[n] = __builtin_amdgcn_mfma_f32_16x16x32_bf16(aW2, bA1, attacc[n], 0,0,0);
        }
    }

    // ---- epilogue -------------------------------------------------------------
    #pragma unroll
    for (int n = 0; n < 4; ++n){
        int oh = toh + n, ow = tow + l15;
        #pragma unroll
        for (int r = 0; r < 4; ++r){
            int co = wid*16 + lg*4 + r;
            size_t oi = ((size_t)(b*64+co) << 16) + oh*256 + ow;
            float att = fmaxf(attacc[n][r], 0.f);
            float v = lrelu_f(dynacc[n][r] + cb[co] + x[oi]*att);
            buf[oi] = __float2bfloat16(v);
        }
    }
}

// ---------------- K_wprep: pack conv weights into MFMA A-fragment layout ------
__global__ __launch_bounds__(256) void k_wprep(
    const float* __restrict__ w, __hip_bfloat16* __restrict__ wp)
{
    int i = blockIdx.x*256 + threadIdx.x;      // [0, 36864)
    int e   = i & 7;
    int coA = (i >> 3) & 63;
    int g   = (i >> 9) & 3;
    int f   = i >> 11;
    int ch  = (f >= 9) ? 1 : 0;
    int pos = f - 9*ch;
    wp[i] = __float2bfloat16(w[coA*576 + (ch*32 + g*8 + e)*9 + pos]);
}

// ---------------- K5 v3: MFMA implicit-GEMM conv ------------------------------
template<typename TIN, int STRIDE, int RESMODE, int ACT, int OUTBF>
__global__ __launch_bounds__(256) void k_conv_mfma(
    const TIN* __restrict__ in, const __hip_bfloat16* __restrict__ wp,
    const float* __restrict__ bias, const void* __restrict__ res,
    void* __restrict__ outp, int H, int W, int Ho, int Wo)
{
    constexpr int TH   = (STRIDE==1) ? 16 : 8;
    constexpr int ROWS = (STRIDE==1) ? TH+2 : 2*TH+1;   // 18 / 17
    constexpr int COLS = (STRIDE==1) ? 18 : 33;
    constexpr int EPC  = (sizeof(TIN)==2) ? 8 : 4;
    constexpr int NC   = (COLS + 2*EPC - 2) / EPC;
    __shared__ __align__(16) char lA[ROWS*COLS*128];
    const int tid = threadIdx.x;
    const int wid = tid >> 6, lane = tid & 63;
    const int l15 = lane & 15, g = lane >> 4;
    const int b   = blockIdx.y;
    const int tilesW = Wo >> 4;
    const int toh = (blockIdx.x / tilesW) * TH;
    const int tow = (blockIdx.x % tilesW) * 16;
    const int row0 = toh*STRIDE - 1;
    const int col0 = tow*STRIDE - 1;

    bf16x8 aw[18];
    const int coA = wid*16 + l15;
    #pragma unroll
    for (int f = 0; f < 18; ++f)
        aw[f] = *(const bf16x8*)(wp + ((f*4 + g)*64 + coA)*8);

    const int astart = tow*STRIDE - EPC;
    const bool cfast = (astart >= 0) && (astart + NC*EPC <= W);
    for (int i = tid; i < ROWS*64; i += 256){
        const int ci = i & 63, r = i >> 6;
        const int ih = row0 + r;
        if (ih < 0 || ih >= H){
            #pragma unroll
            for (int c = 0; c < COLS; ++c)
                *(unsigned short*)(lA + ((r*COLS+c)*8 + ((ci>>3)^(c&7)))*16 + (ci&7)*2) = 0;
        } else {
            const TIN* srow = in + ((size_t)(b*64+ci))*H*W + (size_t)ih*W;
            if (cfast){
                if constexpr (sizeof(TIN) == 2){
                    u16x8 chk[NC];
                    #pragma unroll
                    for (int k = 0; k < NC; ++k)
                        chk[k] = *(const u16x8*)(srow + astart + k*8);
                    #pragma unroll
                    for (int c = 0; c < COLS; ++c){
                        const int idx = 7 + c;
                        unsigned short bits = chk[idx>>3][idx&7];
                        *(unsigned short*)(lA + ((r*COLS+c)*8 + ((ci>>3)^(c&7)))*16 + (ci&7)*2) = bits;
                    }
                } else {
                    f32x4 chk[NC];
                    #pragma unroll
                    for (int k = 0; k < NC; ++k)
                        chk[k] = *(const f32x4*)(srow + astart + k*4);
                    #pragma unroll
                    for (int c = 0; c < COLS; ++c){
                        const int idx = 3 + c;
                        unsigned short bits = bf_bits(chk[idx>>2][idx&3]);
                        *(unsigned short*)(lA + ((r*COLS+c)*8 + ((ci>>3)^(c&7)))*16 + (ci&7)*2) = bits;
                    }
                }
            } else {
                #pragma unroll
                for (int c = 0; c < COLS; ++c){
                    int iw = col0 + c;
                    unsigned short bits = 0;
                    if (iw >= 0 && iw < W) bits = bf_bits(srow[iw]);
                    *(unsigned short*)(lA + ((r*COLS+c)*8 + ((ci>>3)^(c&7)))*16 + (ci&7)*2) = bits;
                }
            }
        }
    }
    __syncthreads();

    float bv[4];
    #pragma unroll
    for (int r = 0; r < 4; ++r) bv[r] = bias[wid*16 + g*4 + r];
    const float*          resF = (const float*)res;
    const __hip_bfloat16* resB = (const __hip_bfloat16*)res;

    if constexpr (STRIDE == 1){
        bf16x8 Bw[3][2][3];
        auto ldrow = [&](int rr, int slot){
            #pragma unroll
            for (int ch = 0; ch < 2; ++ch)
                #pragma unroll
                for (int kw = 0; kw < 3; ++kw){
                    const int cc = l15 + kw;
                    Bw[slot][ch][kw] = *(const bf16x8*)(lA + ((rr*COLS + cc)*8 + ((ch*4+g) ^ (cc&7)))*16);
                }
        };
        ldrow(0, 0);
        ldrow(1, 1);
        #pragma unroll
        for (int n = 0; n < TH; ++n){
            ldrow(n+2, (n+2)%3);
            f32x4 acc = {0.f,0.f,0.f,0.f};
            #pragma unroll
            for (int kh = 0; kh < 3; ++kh)
                #pragma unroll
                for (int ch = 0; ch < 2; ++ch)
                    #pragma unroll
                    for (int kw = 0; kw < 3; ++kw)
                        acc = __builtin_amdgcn_mfma_f32_16x16x32_bf16(
                                aw[ch*9 + kh*3 + kw], Bw[(n+kh)%3][ch][kw], acc, 0, 0, 0);
            const int oh = toh + n, ow = tow + l15;
            #pragma unroll
            for (int r = 0; r < 4; ++r){
                int co = wid*16 + g*4 + r;
                size_t oi = ((size_t)(b*64+co)*Ho + oh)*Wo + ow;
                float v = acc[r] + bv[r];
                if (ACT) v = fmaxf(v, 0.f);
                if (RESMODE == 1) v += resF[oi];
                if (RESMODE == 2) v += __bfloat162float(resB[oi]);
                if (OUTBF) ((__hip_bfloat16*)outp)[oi] = __float2bfloat16(v);
                else       ((float*)outp)[oi] = v;
            }
        }
    } else {
        #pragma unroll
        for (int n = 0; n < TH; ++n){
            f32x4 acc = {0.f,0.f,0.f,0.f};
            #pragma unroll
            for (int ch = 0; ch < 2; ++ch)
                #pragma unroll
                for (int pos = 0; pos < 9; ++pos){
                    const int kh = pos/3, kw = pos - 3*(pos/3);
                    const int cc = l15*STRIDE + kw;
                    const int rr = n*STRIDE + kh;
                    bf16x8 bx = *(const bf16x8*)(lA + ((rr*COLS + cc)*8 + ((ch*4+g) ^ (cc&7)))*16);
                    acc = __builtin_amdgcn_mfma_f32_16x16x32_bf16(aw[ch*9+pos], bx, acc, 0, 0, 0);
                }
            const int oh = toh + n, ow = tow + l15;
            #pragma unroll
            for (int r = 0; r < 4; ++r){
                int co = wid*16 + g*4 + r;
                size_t oi = ((size_t)(b*64+co)*Ho + oh)*Wo + ow;
                float v = acc[r] + bv[r];
                if (ACT) v = fmaxf(v, 0.f);
                if (RESMODE == 1) v += resF[oi];
                if (RESMODE == 2) v += __bfloat162float(resB[oi]);
                if (OUTBF) ((__hip_bfloat16*)outp)[oi] = __float2bfloat16(v);
                else       ((float*)outp)[oi] = v;
            }
        }
    }
}

// ---------------- host ---------------------------------------------------------
extern "C" void kernel_launch(void* const* d_in, const int* in_sizes, int n_in,
                              void* d_out, int out_size, void* d_ws, size_t ws_size,
                              hipStream_t stream) {
    const float* x    = (const float*)d_in[0];
    const float* y    = (const float*)d_in[1];
    const float* ew1  = (const float*)d_in[2];
    const float* eb1  = (const float*)d_in[3];
    const float* bn1g = (const float*)d_in[4];
    const float* bn1b = (const float*)d_in[5];
    const float* bn1m = (const float*)d_in[6];
    const float* bn1v = (const float*)d_in[7];
    const float* ew2  = (const float*)d_in[8];
    const float* eb2  = (const float*)d_in[9];
    const float* bn2g = (const float*)d_in[10];
    const float* bn2b = (const float*)d_in[11];
    const float* bn2m = (const float*)d_in[12];
    const float* bn2v = (const float*)d_in[13];
    const float* mw1  = (const float*)d_in[14];
    const float* mb1  = (const float*)d_in[15];
    const float* mw2  = (const float*)d_in[16];
    const float* mb2  = (const float*)d_in[17];
    const float* kw1  = (const float*)d_in[18];
    const float* kw2  = (const float*)d_in[19];
    const float* cw   = (const float*)d_in[20];
    const float* cb   = (const float*)d_in[21];
    const float* caw1 = (const float*)d_in[22];
    const float* caw2 = (const float*)d_in[23];
    const float* c1w  = (const float*)d_in[24];
    const float* c1b  = (const float*)d_in[25];
    const float* c2w  = (const float*)d_in[26];
    const float* c2b  = (const float*)d_in[27];
    const float* r1w  = (const float*)d_in[28];
    const float* r1b  = (const float*)d_in[29];
    const float* r2w  = (const float*)d_in[30];
    const float* r2b  = (const float*)d_in[31];

    // ws layout (proven >= 33.57 MB):
    //   buf bf16 [0, 33554432)  (k_fuse -> c1; dead after c1)
    //     e1b bf16 [0, 1048576)  (enc1m -> enc2m, dead before k_fuse)
    //     wp2 @ 2097152 (589824 B), part @ 2686976 (65536 B)
    //     after c1: t2 bf16 [0, 8388608), u2 [8388608, 16777216),
    //               t3 [16777216, 18874368), u3 [18874368, 20971520),
    //               wpB (3 x 147456 B) @ 29360128
    //   fv f32 @ 33554432, kern f32 @ 33558528
    char* wsc = (char*)d_ws;
    __hip_bfloat16* buf = (__hip_bfloat16*)wsc;
    __hip_bfloat16* e1b = (__hip_bfloat16*)wsc;
    __hip_bfloat16* wp2 = (__hip_bfloat16*)(wsc + 2097152);
    float*          part= (float*)(wsc + 2686976);
    __hip_bfloat16* t2  = (__hip_bfloat16*)wsc;
    __hip_bfloat16* u2  = (__hip_bfloat16*)(wsc + 8388608);
    __hip_bfloat16* t3  = (__hip_bfloat16*)(wsc + 16777216);
    __hip_bfloat16* u3  = (__hip_bfloat16*)(wsc + 18874368);
    __hip_bfloat16* wpB0= (__hip_bfloat16*)(wsc + 29360128);
    __hip_bfloat16* wpB1= (__hip_bfloat16*)(wsc + 29360128 + 147456);
    __hip_bfloat16* wpB2= (__hip_bfloat16*)(wsc + 29360128 + 294912);
    float*          fv  = (float*)(wsc + 33554432);
    float*          kern= (float*)(wsc + 33558528);

    float* ob   = (float*)d_out;            // out  (4,64,256,256) f32
    float* ob1  = ob + 16777216;            // out2 (4,64,128,128) f32
    float* ob2  = ob + 20971520;            // out3 (4,64,64,64)   f32
    // transient weight buffers inside d_out's out3 region (dead until the
    // final conv, consumed long before it):
    __hip_bfloat16* wpF = (__hip_bfloat16*)((char*)d_out + 83886080);  // 16 KB
    __hip_bfloat16* wp1 = (__hip_bfloat16*)((char*)d_out + 84934656);  // 144 KB
    __hip_bfloat16* wpA = (__hip_bfloat16*)((char*)d_out + 87932928);  // 144 KB

    k_wprep<<<dim3(144),256,0,stream>>>(c1w, wpA);
    k_wprep1<<<dim3(288),256,0,stream>>>(ew1, bn1g, bn1v, wp1);
    k_wprep2<<<dim3(1152),256,0,stream>>>(ew2, bn2g, bn2v, wp2);
    k_wprepF<<<dim3(32),256,0,stream>>>(cw, caw1, caw2, wpF);
    k_enc1m<<<dim3(16,4),256,0,stream>>>(y, wp1, eb1, bn1g, bn1b, bn1m, bn1v, e1b);
    k_enc2m<<<dim3(16,4),256,0,stream>>>(e1b, wp2, eb2, bn2g, bn2b, bn2m, bn2v, part);
    k_enc2red<<<dim3(4),256,0,stream>>>(part, fv);
    k_mlp<<<dim3(4),256,0,stream>>>(fv, mw1, mb1, mw2, mb2, kw1, kw2, kern);
    k_fuse<<<dim3(1024,4),256,0,stream>>>(x, kern, wpF, cb, buf);

    // out0 = conv3x3(pre) + bias + x  -> f32 d_out   (16x16 tiles)
    k_conv_mfma<__hip_bfloat16,1,1,0,0><<<dim3(256,4),256,0,stream>>>(buf, wpA, c1b, x, ob, 256,256,256,256);
    // prep remaining weights into the now-dead buf tail
    k_wprep<<<dim3(144),256,0,stream>>>(c2w, wpB0);
    k_wprep<<<dim3(144),256,0,stream>>>(r1w, wpB1);
    k_wprep<<<dim3(144),256,0,stream>>>(r2w, wpB2);
    // t2 = conv3x3 s2 (out0 f32) -> bf16             (8x16 tiles: 16*8)
    k_conv_mfma<float,2,0,0,1><<<dim3(128,4),256,0,stream>>>(ob, wpB0, c2b, nullptr, t2, 256,256,128,128);
    // u2 = relu(conv3x3(t2)) -> bf16                 (8*8)
    k_conv_mfma<__hip_bfloat16,1,0,1,1><<<dim3(64,4),256,0,stream>>>(t2, wpB1, r1b, nullptr, u2, 128,128,128,128);
    // out2 = t2 + conv3x3(u2) -> f32 d_out
    k_conv_mfma<__hip_bfloat16,1,2,0,0><<<dim3(64,4),256,0,stream>>>(u2, wpB2, r2b, t2, ob1, 128,128,128,128);
    // t3 = conv3x3 s2 (out2 f32) -> bf16             (8*4)
    k_conv_mfma<float,2,0,0,1><<<dim3(32,4),256,0,stream>>>(ob1, wpB0, c2b, nullptr, t3, 128,128,64,64);
    // u3 = relu(conv3x3(t3)) -> bf16                 (4*4)
    k_conv_mfma<__hip_bfloat16,1,0,1,1><<<dim3(16,4),256,0,stream>>>(t3, wpB1, r1b, nullptr, u3, 64,64,64,64);
    // out3 = t3 + conv3x3(u3) -> f32 d_out
    k_conv_mfma<__hip_bfloat16,1,2,0,0><<<dim3(16,4),256,0,stream>>>(u3, wpB2, r2b, t3, ob2, 64,64,64,64);
}

// Round 18
// 500.950 us; speedup vs baseline: 2.1448x; 1.0793x over previous
//
#include <hip/hip_runtime.h>
#include <hip/hip_bf16.h>
#include <cstddef>
#include <cstdint>

#define DEV __device__ __forceinline__

DEV float lrelu_f(float z){ return z >= 0.f ? z : 0.1f*z; }

typedef __bf16 bf16x8 __attribute__((ext_vector_type(8)));
typedef float  f32x4  __attribute__((ext_vector_type(4)));
typedef unsigned short u16x8 __attribute__((ext_vector_type(8)));

DEV unsigned short bf_bits(float v){
    __hip_bfloat16 h = __float2bfloat16(v);
    unsigned short s; __builtin_memcpy(&s, &h, 2); return s;
}
DEV unsigned short bf_bits(__hip_bfloat16 v){
    unsigned short s; __builtin_memcpy(&s, &v, 2); return s;
}
DEV float u16_to_f(unsigned short s){
    unsigned int u = ((unsigned int)s) << 16;
    float f; __builtin_memcpy(&f, &u, 4); return f;
}

// ---------------- merged weight prep (wpA, wp1, wp2, wpF) ---------------------
__global__ __launch_bounds__(256) void k_prep_all(
    const float* __restrict__ c1w,
    const float* __restrict__ ew1, const float* __restrict__ bn1g, const float* __restrict__ bn1v,
    const float* __restrict__ ew2, const float* __restrict__ bn2g, const float* __restrict__ bn2v,
    const float* __restrict__ cw, const float* __restrict__ caw1, const float* __restrict__ caw2,
    __hip_bfloat16* __restrict__ wpA, __hip_bfloat16* __restrict__ wp1,
    __hip_bfloat16* __restrict__ wp2, __hip_bfloat16* __restrict__ wpF)
{
    const int blk = blockIdx.x, tid = threadIdx.x;
    if (blk < 144){
        int i = blk*256 + tid;                 // wpA: c1w frag pack
        int e = i & 7, coA = (i>>3)&63, g = (i>>9)&3, f = i>>11;
        int ch = (f>=9)?1:0, pos = f-9*ch;
        wpA[i] = __float2bfloat16(c1w[coA*576 + (ch*32+g*8+e)*9 + pos]);
    } else if (blk < 432){
        int i = (blk-144)*256 + tid;           // wp1: ew1 * bn1 scale
        int e = i & 7, co = (i>>3)&127, g = (i>>10)&3, f = i>>12;
        int ch = (f>=9)?1:0, pos = f-9*ch;
        float s = bn1g[co] / sqrtf(bn1v[co] + 1e-5f);
        wp1[i] = __float2bfloat16(ew1[co*576 + (ch*32+g*8+e)*9 + pos] * s);
    } else if (blk < 1584){
        int i = (blk-432)*256 + tid;           // wp2: ew2 * bn2 scale
        int e = i & 7, co = (i>>3)&255, g = (i>>11)&3, f = i>>13;
        int ch = f/9, pos = f-9*ch;
        float s = bn2g[co] / sqrtf(bn2v[co] + 1e-5f);
        wp2[i] = __float2bfloat16(ew2[co*1152 + (ch*32+g*8+e)*9 + pos] * s);
    } else {
        int i = (blk-1584)*256 + tid;          // wpF
        if (i < 4096){
            int e = i&7, co = (i>>3)&63, g = (i>>9)&3, ch = i>>11;
            wpF[i] = __float2bfloat16(cw[co*64 + ch*32 + g*8 + e]);
        } else if (i < 6144){
            int j = i - 4096;
            int e = j&7, co = (j>>3)&31, g = (j>>8)&3, ch = j>>10;
            wpF[i] = __float2bfloat16(caw1[co*64 + ch*32 + g*8 + e]);
        } else {
            int j = i - 6144;
            int e = j&7, co = (j>>3)&63, g = j>>9;
            wpF[i] = __float2bfloat16(caw2[co*32 + g*8 + e]);
        }
    }
}

// ---------------- merged wpB prep (c2w, r1w, r2w) -----------------------------
__global__ __launch_bounds__(256) void k_wprepB(
    const float* __restrict__ c2w, const float* __restrict__ r1w,
    const float* __restrict__ r2w, __hip_bfloat16* __restrict__ wpB)
{
    int i = blockIdx.x*256 + threadIdx.x;      // [0, 110592)
    int sel = i / 36864;
    int j   = i - sel*36864;
    const float* w = (sel==0) ? c2w : (sel==1) ? r1w : r2w;
    int e = j & 7, coA = (j>>3)&63, g = (j>>9)&3, f = j>>11;
    int ch = (f>=9)?1:0, pos = f-9*ch;
    wpB[i] = __float2bfloat16(w[coA*576 + (ch*32+g*8+e)*9 + pos]);
}

// ---------------- K1 v2: enc1 as MFMA conv ------------------------------------
__global__ __launch_bounds__(256) void k_enc1m(
    const float* __restrict__ y, const __hip_bfloat16* __restrict__ wp1,
    const float* __restrict__ eb1, const float* __restrict__ bng,
    const float* __restrict__ bnb, const float* __restrict__ bnm,
    const float* __restrict__ bnv, __hip_bfloat16* __restrict__ e1b)
{
    __shared__ __align__(16) char lA[9*33*128];
    const int tid = threadIdx.x;
    const int wid = tid >> 6, lane = tid & 63;
    const int l15 = lane & 15, lg = lane >> 4;
    const int b = blockIdx.y, tile = blockIdx.x;
    const int toh = (tile >> 1) * 4;
    const int tow = (tile & 1) * 16;
    const int row0 = toh*2 - 1, col0 = tow*2 - 1;

    for (int i = tid; i < 9*33*64; i += 256){
        int c  = i % 33;
        int t  = i / 33;
        int r  = t % 9;
        int ci = t / 9;
        int ih = row0 + r, iw = col0 + c;
        unsigned short bits = 0;
        if (ih >= 0 && ih < 64 && iw >= 0 && iw < 64)
            bits = bf_bits(y[((size_t)(b*64+ci) << 12) + ih*64 + iw]);
        *(unsigned short*)(lA + ((r*33+c)*8 + ((ci>>3) ^ (c&7)))*16 + (ci&7)*2) = bits;
    }
    __syncthreads();

    f32x4 acc[2][4];
    #pragma unroll
    for (int s = 0; s < 2; ++s)
        #pragma unroll
        for (int n = 0; n < 4; ++n) acc[s][n] = (f32x4){0.f,0.f,0.f,0.f};

    #pragma unroll
    for (int ch = 0; ch < 2; ++ch){
        #pragma unroll
        for (int pos = 0; pos < 9; ++pos){
            const int f = ch*9 + pos;
            const int kh = pos/3, kw = pos - 3*(pos/3);
            bf16x8 bx[4];
            #pragma unroll
            for (int n = 0; n < 4; ++n){
                const int rr = n*2 + kh, cc = l15*2 + kw;
                bx[n] = *(const bf16x8*)(lA + ((rr*33+cc)*8 + ((ch*4+lg) ^ (cc&7)))*16);
            }
            #pragma unroll
            for (int s = 0; s < 2; ++s){
                const int coA = wid*32 + s*16 + l15;
                bf16x8 aw = *(const bf16x8*)(wp1 + ((size_t)(f*4 + lg)*128 + coA)*8);
                #pragma unroll
                for (int n = 0; n < 4; ++n)
                    acc[s][n] = __builtin_amdgcn_mfma_f32_16x16x32_bf16(aw, bx[n], acc[s][n], 0,0,0);
            }
        }
    }

    #pragma unroll
    for (int s = 0; s < 2; ++s){
        #pragma unroll
        for (int r = 0; r < 4; ++r){
            const int co = wid*32 + s*16 + lg*4 + r;
            float sb = bng[co] / sqrtf(bnv[co] + 1e-5f);
            float bs = (eb1[co] - bnm[co])*sb + bnb[co];
            #pragma unroll
            for (int n = 0; n < 4; ++n){
                int oh = toh + n, ow = tow + l15;
                e1b[((size_t)(b*128+co) << 10) + oh*32 + ow]
                    = __float2bfloat16(lrelu_f(acc[s][n][r] + bs));
            }
        }
    }
}

// ---------------- K2 v2: enc2 as MFMA conv + masked mean partials -------------
__global__ __launch_bounds__(256) void k_enc2m(
    const __hip_bfloat16* __restrict__ e1b, const __hip_bfloat16* __restrict__ wp2,
    const float* __restrict__ bias, const float* __restrict__ g_,
    const float* __restrict__ bb, const float* __restrict__ m_,
    const float* __restrict__ v_, float* __restrict__ partial)
{
    __shared__ __align__(16) char lA[6*18*16*16];
    const int tid = threadIdx.x;
    const int wid = tid >> 6, lane = tid & 63;
    const int l15 = lane & 15, lg = lane >> 4;
    const int b = blockIdx.y, tile = blockIdx.x;
    const int toh = (tile >> 1) * 4;
    const int tow = (tile & 1) * 16;

    for (int i = tid; i < 13824; i += 256){
        int c  = i % 18;
        int t  = i / 18;
        int r  = t % 6;
        int ci = t / 6;
        int ih = toh + r, iw = tow + c;
        unsigned short bits = 0;
        if (ih < 32 && iw < 32)
            bits = bf_bits(e1b[((size_t)(b*128+ci) << 10) + ih*32 + iw]);
        *(unsigned short*)(lA + ((r*18+c)*16 + ((ci>>3) ^ (c&7)))*16 + (ci&7)*2) = bits;
    }
    __syncthreads();

    f32x4 acc[4][4];
    #pragma unroll
    for (int s = 0; s < 4; ++s)
        #pragma unroll
        for (int n = 0; n < 4; ++n) acc[s][n] = (f32x4){0.f,0.f,0.f,0.f};

    #pragma unroll
    for (int ch = 0; ch < 4; ++ch){
        #pragma unroll
        for (int pos = 0; pos < 9; ++pos){
            const int f = ch*9 + pos;
            const int kh = pos/3, kw = pos - 3*(pos/3);
            bf16x8 bx[4];
            #pragma unroll
            for (int n = 0; n < 4; ++n){
                const int rr = n + kh, cc = l15 + kw;
                bx[n] = *(const bf16x8*)(lA + ((rr*18+cc)*16 + ((ch*4+lg) ^ (cc&7)))*16);
            }
            #pragma unroll
            for (int s = 0; s < 4; ++s){
                const int coA = wid*64 + s*16 + l15;
                bf16x8 aw = *(const bf16x8*)(wp2 + ((size_t)(f*4 + lg)*256 + coA)*8);
                #pragma unroll
                for (int n = 0; n < 4; ++n)
                    acc[s][n] = __builtin_amdgcn_mfma_f32_16x16x32_bf16(aw, bx[n], acc[s][n], 0,0,0);
            }
        }
    }

    const int ow = tow + l15;
    const bool owok = ow < 30;
    #pragma unroll
    for (int s = 0; s < 4; ++s){
        #pragma unroll
        for (int r = 0; r < 4; ++r){
            const int co = wid*64 + s*16 + lg*4 + r;
            float sb = g_[co] / sqrtf(v_[co] + 1e-5f);
            float bs = (bias[co] - m_[co])*sb + bb[co];
            float th = 0.f;
            #pragma unroll
            for (int n = 0; n < 4; ++n){
                if (owok && (toh + n) < 30)
                    th += lrelu_f(acc[s][n][r] + bs);
            }
            th += __shfl_xor(th, 1);
            th += __shfl_xor(th, 2);
            th += __shfl_xor(th, 4);
            th += __shfl_xor(th, 8);
            if (l15 == 0)
                partial[((size_t)(b*16 + tile))*256 + co] = th;
        }
    }
}

// ---------------- K3: MLP (+folded enc2 partial reduction) --------------------
__global__ __launch_bounds__(256) void k_mlp(
    const float* __restrict__ partial,
    const float* __restrict__ mw1, const float* __restrict__ mb1,
    const float* __restrict__ mw2, const float* __restrict__ mb2,
    const float* __restrict__ kw1, const float* __restrict__ kw2,
    float* __restrict__ kern)
{
    __shared__ float fs[256], h1[256], emb[256], k1[128];
    int b = blockIdx.x, t = threadIdx.x;
    {
        float s = 0.f;
        #pragma unroll
        for (int tt = 0; tt < 16; ++tt)
            s += partial[((size_t)(b*16 + tt))*256 + t];
        fs[t] = s * (1.f/900.f);
    }
    __syncthreads();
    {
        float acc = mb1[t];
        const float* wr = mw1 + t*256;
        for (int i=0;i<256;++i) acc += fs[i]*wr[i];
        h1[t] = lrelu_f(acc);
    }
    __syncthreads();
    {
        float acc = mb2[t];
        const float* wr = mw2 + t*256;
        for (int i=0;i<256;++i) acc += h1[i]*wr[i];
        emb[t] = acc;
    }
    __syncthreads();
    if (t < 128){
        float acc = 0.f;
        const float* wr = kw1 + t*256;
        for (int i=0;i<256;++i) acc += emb[i]*wr[i];
        k1[t] = lrelu_f(acc);
    }
    __syncthreads();
    for (int o=t; o<576; o+=256){
        float acc = 0.f;
        const float* wr = kw2 + o*128;
        for (int i=0;i<128;++i) acc += k1[i]*wr[i];
        kern[b*576+o] = acc;
    }
}

// ---------------- K4 v3: fused {dyn depthwise + 1x1 + CA + combine}, MFMA -----
// Epilogue x now read from LDS (bf16, ~2-way conflicts) - no global re-read.
__global__ __launch_bounds__(256) void k_fuse(
    const float* __restrict__ x, const float* __restrict__ kern,
    const __hip_bfloat16* __restrict__ wpF, const float* __restrict__ cb,
    __hip_bfloat16* __restrict__ buf)
{
    __shared__ __align__(16) char lA [6*18*128];
    __shared__ __align__(16) char lD [64*128];
    __shared__ __align__(16) char lA1[64*64];
    __shared__ float kern_s[576];

    const int tid = threadIdx.x;
    const int wid = tid >> 6, lane = tid & 63;
    const int l15 = lane & 15, lg = lane >> 4;
    const int b = blockIdx.y;
    const int toh = (blockIdx.x >> 4) * 4;
    const int tow = (blockIdx.x & 15) * 16;
    const int row0 = toh - 1;
    const int col0 = tow - 1;

    // ---- stage x halo (aligned chunks + scalar edge) -------------------------
    const bool cfast = (tow >= 1) && (tow + 20 <= 256);
    for (int i = tid; i < 6*64; i += 256){
        const int ci = i & 63, r = i >> 6;
        const int ih = row0 + r;
        if (ih < 0 || ih >= 256){
            #pragma unroll
            for (int c = 0; c < 18; ++c)
                *(unsigned short*)(lA + ((r*18+c)*8 + ((ci>>3)^(c&7)))*16 + (ci&7)*2) = 0;
        } else {
            const float* srow = x + ((size_t)(b*64+ci) << 16) + ih*256;
            if (cfast){
                float edge = srow[tow-1];
                f32x4 chk[5];
                #pragma unroll
                for (int k = 0; k < 5; ++k)
                    chk[k] = *(const f32x4*)(srow + tow + k*4);
                *(unsigned short*)(lA + ((r*18+0)*8 + ((ci>>3)^0))*16 + (ci&7)*2) = bf_bits(edge);
                #pragma unroll
                for (int c = 1; c < 18; ++c){
                    const int idx = c - 1;
                    unsigned short bits = bf_bits(chk[idx>>2][idx&3]);
                    *(unsigned short*)(lA + ((r*18+c)*8 + ((ci>>3)^(c&7)))*16 + (ci&7)*2) = bits;
                }
            } else {
                #pragma unroll
                for (int c = 0; c < 18; ++c){
                    int iw = col0 + c;
                    unsigned short bits = 0;
                    if (iw >= 0 && iw < 256) bits = bf_bits(srow[iw]);
                    *(unsigned short*)(lA + ((r*18+c)*8 + ((ci>>3)^(c&7)))*16 + (ci&7)*2) = bits;
                }
            }
        }
    }
    for (int i = tid; i < 576; i += 256) kern_s[i] = kern[b*576 + i];
    __syncthreads();

    // ---- a1 GEMM (caw1 . X) ---------------------------------------------------
    const int m1 = wid & 1;
    const int nb = (wid >> 1) * 2;
    f32x4 a1acc[2] = {{0.f,0.f,0.f,0.f},{0.f,0.f,0.f,0.f}};
    const int coA1 = m1*16 + l15;
    #pragma unroll
    for (int ch = 0; ch < 2; ++ch){
        bf16x8 aA = *(const bf16x8*)(wpF + 4096 + ((ch*4+lg)*32 + coA1)*8);
        #pragma unroll
        for (int t = 0; t < 2; ++t){
            int n = nb + t;
            int cc = l15 + 1, rr = n + 1;
            bf16x8 bX = *(const bf16x8*)(lA + ((rr*18+cc)*8 + ((ch*4+lg) ^ (cc&7)))*16);
            a1acc[t] = __builtin_amdgcn_mfma_f32_16x16x32_bf16(aA, bX, a1acc[t], 0,0,0);
        }
    }

    // ---- depthwise -> lD ------------------------------------------------------
    {
        const int px = tid & 63;
        const int s0 = tid >> 6;
        const int prow = px >> 4, pcol = px & 15;
        #pragma unroll
        for (int t = 0; t < 2; ++t){
            const int sl = s0 + t*4;
            u16x8 xv[3][3];
            #pragma unroll
            for (int kh = 0; kh < 3; ++kh)
                #pragma unroll
                for (int kw = 0; kw < 3; ++kw){
                    const int r = prow + kh, c = pcol + kw;
                    xv[kh][kw] = *(const u16x8*)(lA + ((r*18+c)*8 + (sl ^ (c&7)))*16);
                }
            u16x8 outv;
            #pragma unroll
            for (int e = 0; e < 8; ++e){
                const int ci = sl*8 + e;
                const float* kr = kern_s + ci*9;
                float acc = 0.f;
                #pragma unroll
                for (int kh = 0; kh < 3; ++kh)
                    #pragma unroll
                    for (int kw = 0; kw < 3; ++kw)
                        acc += u16_to_f(xv[kh][kw][e]) * kr[kh*3+kw];
                outv[e] = bf_bits(lrelu_f(acc));
            }
            *(u16x8*)(lD + (px*8 + (sl ^ (px&7)))*16) = outv;
        }
    }

    // ---- a1 -> lrelu -> lA1 ---------------------------------------------------
    #pragma unroll
    for (int t = 0; t < 2; ++t){
        int n = nb + t;
        int px = n*16 + l15;
        #pragma unroll
        for (int r = 0; r < 4; ++r){
            int j = m1*16 + lg*4 + r;
            *(unsigned short*)(lA1 + (px*4 + ((j>>3) ^ (px&3)))*16 + (j&7)*2)
                = bf_bits(lrelu_f(a1acc[t][r]));
        }
    }
    __syncthreads();

    // ---- dyn & att GEMMs ------------------------------------------------------
    f32x4 dynacc[4] = {{0.f,0.f,0.f,0.f},{0.f,0.f,0.f,0.f},{0.f,0.f,0.f,0.f},{0.f,0.f,0.f,0.f}};
    f32x4 attacc[4] = {{0.f,0.f,0.f,0.f},{0.f,0.f,0.f,0.f},{0.f,0.f,0.f,0.f},{0.f,0.f,0.f,0.f}};
    const int coA = wid*16 + l15;
    #pragma unroll
    for (int ch = 0; ch < 2; ++ch){
        bf16x8 aW = *(const bf16x8*)(wpF + ((ch*4+lg)*64 + coA)*8);
        #pragma unroll
        for (int n = 0; n < 4; ++n){
            int px = n*16 + l15;
            bf16x8 bD = *(const bf16x8*)(lD + (px*8 + ((ch*4+lg) ^ (px&7)))*16);
            dynacc[n] = __builtin_amdgcn_mfma_f32_16x16x32_bf16(aW, bD, dynacc[n], 0,0,0);
        }
    }
    {
        bf16x8 aW2 = *(const bf16x8*)(wpF + 6144 + (lg*64 + coA)*8);
        #pragma unroll
        for (int n = 0; n < 4; ++n){
            int px = n*16 + l15;
            bf16x8 bA1 = *(const bf16x8*)(lA1 + (px*4 + (lg ^ (px&3)))*16);
            attacc[n] = __builtin_amdgcn_mfma_f32_16x16x32_bf16(aW2, bA1, attacc[n], 0,0,0);
        }
    }

    // ---- epilogue: x from LDS (bf16) -----------------------------------------
    #pragma unroll
    for (int n = 0; n < 4; ++n){
        int oh = toh + n, ow = tow + l15;
        const int rr = n + 1, cc = l15 + 1;
        #pragma unroll
        for (int r = 0; r < 4; ++r){
            int co = wid*16 + lg*4 + r;
            size_t oi = ((size_t)(b*64+co) << 16) + oh*256 + ow;
            float xv = u16_to_f(*(const unsigned short*)(
                lA + ((rr*18+cc)*8 + ((co>>3) ^ (cc&7)))*16 + (co&7)*2));
            float att = fmaxf(attacc[n][r], 0.f);
            float v = lrelu_f(dynacc[n][r] + cb[co] + xv*att);
            buf[oi] = __float2bfloat16(v);
        }
    }
}

// ---------------- K5 v4: MFMA implicit-GEMM conv (TH param, aligned staging) --
template<typename TIN, int STRIDE, int TH, int RESMODE, int ACT, int OUTBF>
__global__ __launch_bounds__(256) void k_conv_mfma(
    const TIN* __restrict__ in, const __hip_bfloat16* __restrict__ wp,
    const float* __restrict__ bias, const void* __restrict__ res,
    void* __restrict__ outp, int H, int W, int Ho, int Wo)
{
    constexpr int ROWS = (STRIDE==1) ? TH+2 : 2*TH+1;
    constexpr int COLS = (STRIDE==1) ? 18 : 33;
    constexpr int EPC  = (sizeof(TIN)==2) ? 8 : 4;
    constexpr int NCH  = (COLS - 1 + EPC - 1) / EPC;   // chunks covering cols 1..COLS-1
    __shared__ __align__(16) char lA[ROWS*COLS*128];
    const int tid = threadIdx.x;
    const int wid = tid >> 6, lane = tid & 63;
    const int l15 = lane & 15, g = lane >> 4;
    const int b   = blockIdx.y;
    const int tilesW = Wo >> 4;
    const int toh = (blockIdx.x / tilesW) * TH;
    const int tow = (blockIdx.x % tilesW) * 16;
    const int row0 = toh*STRIDE - 1;
    const int col0 = tow*STRIDE - 1;

    bf16x8 aw[18];
    const int coA = wid*16 + l15;
    #pragma unroll
    for (int f = 0; f < 18; ++f)
        aw[f] = *(const bf16x8*)(wp + ((f*4 + g)*64 + coA)*8);

    const int base = tow*STRIDE;                       // 16B-aligned for both types
    const bool cfast = (base >= 1) && (base + NCH*EPC <= W);
    for (int i = tid; i < ROWS*64; i += 256){
        const int ci = i & 63, r = i >> 6;
        const int ih = row0 + r;
        if (ih < 0 || ih >= H){
            #pragma unroll
            for (int c = 0; c < COLS; ++c)
                *(unsigned short*)(lA + ((r*COLS+c)*8 + ((ci>>3)^(c&7)))*16 + (ci&7)*2) = 0;
        } else {
            const TIN* srow = in + ((size_t)(b*64+ci))*H*W + (size_t)ih*W;
            if (cfast){
                if constexpr (sizeof(TIN) == 2){
                    unsigned short edge = bf_bits(srow[base-1]);
                    u16x8 chk[NCH];
                    #pragma unroll
                    for (int k = 0; k < NCH; ++k)
                        chk[k] = *(const u16x8*)(srow + base + k*8);
                    *(unsigned short*)(lA + ((r*COLS+0)*8 + (ci>>3))*16 + (ci&7)*2) = edge;
                    #pragma unroll
                    for (int c = 1; c < COLS; ++c){
                        const int idx = c - 1;
                        unsigned short bits = chk[idx>>3][idx&7];
                        *(unsigned short*)(lA + ((r*COLS+c)*8 + ((ci>>3)^(c&7)))*16 + (ci&7)*2) = bits;
                    }
                } else {
                    unsigned short edge = bf_bits(srow[base-1]);
                    f32x4 chk[NCH];
                    #pragma unroll
                    for (int k = 0; k < NCH; ++k)
                        chk[k] = *(const f32x4*)(srow + base + k*4);
                    *(unsigned short*)(lA + ((r*COLS+0)*8 + (ci>>3))*16 + (ci&7)*2) = edge;
                    #pragma unroll
                    for (int c = 1; c < COLS; ++c){
                        const int idx = c - 1;
                        unsigned short bits = bf_bits(chk[idx>>2][idx&3]);
                        *(unsigned short*)(lA + ((r*COLS+c)*8 + ((ci>>3)^(c&7)))*16 + (ci&7)*2) = bits;
                    }
                }
            } else {
                #pragma unroll
                for (int c = 0; c < COLS; ++c){
                    int iw = col0 + c;
                    unsigned short bits = 0;
                    if (iw >= 0 && iw < W) bits = bf_bits(srow[iw]);
                    *(unsigned short*)(lA + ((r*COLS+c)*8 + ((ci>>3)^(c&7)))*16 + (ci&7)*2) = bits;
                }
            }
        }
    }
    __syncthreads();

    float bv[4];
    #pragma unroll
    for (int r = 0; r < 4; ++r) bv[r] = bias[wid*16 + g*4 + r];
    const float*          resF = (const float*)res;
    const __hip_bfloat16* resB = (const __hip_bfloat16*)res;

    if constexpr (STRIDE == 1){
        bf16x8 Bw[3][2][3];
        auto ldrow = [&](int rr, int slot){
            #pragma unroll
            for (int ch = 0; ch < 2; ++ch)
                #pragma unroll
                for (int kw = 0; kw < 3; ++kw){
                    const int cc = l15 + kw;
                    Bw[slot][ch][kw] = *(const bf16x8*)(lA + ((rr*COLS + cc)*8 + ((ch*4+g) ^ (cc&7)))*16);
                }
        };
        ldrow(0, 0);
        ldrow(1, 1);
        #pragma unroll
        for (int n = 0; n < TH; ++n){
            ldrow(n+2, (n+2)%3);
            f32x4 acc = {0.f,0.f,0.f,0.f};
            #pragma unroll
            for (int kh = 0; kh < 3; ++kh)
                #pragma unroll
                for (int ch = 0; ch < 2; ++ch)
                    #pragma unroll
                    for (int kw = 0; kw < 3; ++kw)
                        acc = __builtin_amdgcn_mfma_f32_16x16x32_bf16(
                                aw[ch*9 + kh*3 + kw], Bw[(n+kh)%3][ch][kw], acc, 0, 0, 0);
            const int oh = toh + n, ow = tow + l15;
            #pragma unroll
            for (int r = 0; r < 4; ++r){
                int co = wid*16 + g*4 + r;
                size_t oi = ((size_t)(b*64+co)*Ho + oh)*Wo + ow;
                float v = acc[r] + bv[r];
                if (ACT) v = fmaxf(v, 0.f);
                if (RESMODE == 1) v += resF[oi];
                if (RESMODE == 2) v += __bfloat162float(resB[oi]);
                if (OUTBF) ((__hip_bfloat16*)outp)[oi] = __float2bfloat16(v);
                else       ((float*)outp)[oi] = v;
            }
        }
    } else {
        #pragma unroll
        for (int n = 0; n < TH; ++n){
            f32x4 acc = {0.f,0.f,0.f,0.f};
            #pragma unroll
            for (int ch = 0; ch < 2; ++ch)
                #pragma unroll
                for (int pos = 0; pos < 9; ++pos){
                    const int kh = pos/3, kw = pos - 3*(pos/3);
                    const int cc = l15*STRIDE + kw;
                    const int rr = n*STRIDE + kh;
                    bf16x8 bx = *(const bf16x8*)(lA + ((rr*COLS + cc)*8 + ((ch*4+g) ^ (cc&7)))*16);
                    acc = __builtin_amdgcn_mfma_f32_16x16x32_bf16(aw[ch*9+pos], bx, acc, 0, 0, 0);
                }
            const int oh = toh + n, ow = tow + l15;
            #pragma unroll
            for (int r = 0; r < 4; ++r){
                int co = wid*16 + g*4 + r;
                size_t oi = ((size_t)(b*64+co)*Ho + oh)*Wo + ow;
                float v = acc[r] + bv[r];
                if (ACT) v = fmaxf(v, 0.f);
                if (RESMODE == 1) v += resF[oi];
                if (RESMODE == 2) v += __bfloat162float(resB[oi]);
                if (OUTBF) ((__hip_bfloat16*)outp)[oi] = __float2bfloat16(v);
                else       ((float*)outp)[oi] = v;
            }
        }
    }
}

// ---------------- host ---------------------------------------------------------
extern "C" void kernel_launch(void* const* d_in, const int* in_sizes, int n_in,
                              void* d_out, int out_size, void* d_ws, size_t ws_size,
                              hipStream_t stream) {
    const float* x    = (const float*)d_in[0];
    const float* y    = (const float*)d_in[1];
    const float* ew1  = (const float*)d_in[2];
    const float* eb1  = (const float*)d_in[3];
    const float* bn1g = (const float*)d_in[4];
    const float* bn1b = (const float*)d_in[5];
    const float* bn1m = (const float*)d_in[6];
    const float* bn1v = (const float*)d_in[7];
    const float* ew2  = (const float*)d_in[8];
    const float* eb2  = (const float*)d_in[9];
    const float* bn2g = (const float*)d_in[10];
    const float* bn2b = (const float*)d_in[11];
    const float* bn2m = (const float*)d_in[12];
    const float* bn2v = (const float*)d_in[13];
    const float* mw1  = (const float*)d_in[14];
    const float* mb1  = (const float*)d_in[15];
    const float* mw2  = (const float*)d_in[16];
    const float* mb2  = (const float*)d_in[17];
    const float* kw1  = (const float*)d_in[18];
    const float* kw2  = (const float*)d_in[19];
    const float* cw   = (const float*)d_in[20];
    const float* cb   = (const float*)d_in[21];
    const float* caw1 = (const float*)d_in[22];
    const float* caw2 = (const float*)d_in[23];
    const float* c1w  = (const float*)d_in[24];
    const float* c1b  = (const float*)d_in[25];
    const float* c2w  = (const float*)d_in[26];
    const float* c2b  = (const float*)d_in[27];
    const float* r1w  = (const float*)d_in[28];
    const float* r1b  = (const float*)d_in[29];
    const float* r2w  = (const float*)d_in[30];
    const float* r2b  = (const float*)d_in[31];

    // ws layout (proven >= 33.57 MB):
    //   buf bf16 [0, 33554432)  (k_fuse -> c1; dead after c1)
    //     e1b bf16 [0, 1048576), wp2 @ 2097152, part @ 2686976
    //     after c1: t2 bf16 [0, 8388608), u2 [8388608, 16777216),
    //               t3 [16777216, 18874368), u3 [18874368, 20971520),
    //               wpB (3 x 73728 B contiguous) @ 29360128
    //   kern f32 @ 33558528
    char* wsc = (char*)d_ws;
    __hip_bfloat16* buf = (__hip_bfloat16*)wsc;
    __hip_bfloat16* e1b = (__hip_bfloat16*)wsc;
    __hip_bfloat16* wp2 = (__hip_bfloat16*)(wsc + 2097152);
    float*          part= (float*)(wsc + 2686976);
    __hip_bfloat16* t2  = (__hip_bfloat16*)wsc;
    __hip_bfloat16* u2  = (__hip_bfloat16*)(wsc + 8388608);
    __hip_bfloat16* t3  = (__hip_bfloat16*)(wsc + 16777216);
    __hip_bfloat16* u3  = (__hip_bfloat16*)(wsc + 18874368);
    __hip_bfloat16* wpB = (__hip_bfloat16*)(wsc + 29360128);
    __hip_bfloat16* wpB0= wpB;
    __hip_bfloat16* wpB1= wpB + 36864;
    __hip_bfloat16* wpB2= wpB + 73728;
    float*          kern= (float*)(wsc + 33558528);

    float* ob   = (float*)d_out;            // out  (4,64,256,256) f32
    float* ob1  = ob + 16777216;            // out2 (4,64,128,128) f32
    float* ob2  = ob + 20971520;            // out3 (4,64,64,64)   f32
    __hip_bfloat16* wpF = (__hip_bfloat16*)((char*)d_out + 83886080);  // 16 KB
    __hip_bfloat16* wp1 = (__hip_bfloat16*)((char*)d_out + 84934656);  // 144 KB
    __hip_bfloat16* wpA = (__hip_bfloat16*)((char*)d_out + 87932928);  // 72 KB

    k_prep_all<<<dim3(1616),256,0,stream>>>(c1w, ew1, bn1g, bn1v, ew2, bn2g, bn2v,
                                            cw, caw1, caw2, wpA, wp1, wp2, wpF);
    k_enc1m<<<dim3(16,4),256,0,stream>>>(y, wp1, eb1, bn1g, bn1b, bn1m, bn1v, e1b);
    k_enc2m<<<dim3(16,4),256,0,stream>>>(e1b, wp2, eb2, bn2g, bn2b, bn2m, bn2v, part);
    k_mlp<<<dim3(4),256,0,stream>>>(part, mw1, mb1, mw2, mb2, kw1, kw2, kern);
    k_fuse<<<dim3(1024,4),256,0,stream>>>(x, kern, wpF, cb, buf);

    // out0 = conv3x3(pre) + bias + x  -> f32 d_out  (8x16 tiles, TH=8)
    k_conv_mfma<__hip_bfloat16,1,8,1,0,0><<<dim3(512,4),256,0,stream>>>(buf, wpA, c1b, x, ob, 256,256,256,256);
    k_wprepB<<<dim3(432),256,0,stream>>>(c2w, r1w, r2w, wpB);
    // t2 = conv3x3 s2 (out0 f32) -> bf16            (TH=4: 32x8 tiles)
    k_conv_mfma<float,2,4,0,0,1><<<dim3(256,4),256,0,stream>>>(ob, wpB0, c2b, nullptr, t2, 256,256,128,128);
    // u2 = relu(conv3x3(t2)) -> bf16                (TH=8: 16x8 tiles)
    k_conv_mfma<__hip_bfloat16,1,8,0,1,1><<<dim3(128,4),256,0,stream>>>(t2, wpB1, r1b, nullptr, u2, 128,128,128,128);
    // out2 = t2 + conv3x3(u2) -> f32 d_out
    k_conv_mfma<__hip_bfloat16,1,8,2,0,0><<<dim3(128,4),256,0,stream>>>(u2, wpB2, r2b, t2, ob1, 128,128,128,128);
    // t3 = conv3x3 s2 (out2 f32) -> bf16            (TH=4: 16x4 tiles)
    k_conv_mfma<float,2,4,0,0,1><<<dim3(64,4),256,0,stream>>>(ob1, wpB0, c2b, nullptr, t3, 128,128,64,64);
    // u3 = relu(conv3x3(t3)) -> bf16                (TH=8: 8x4 tiles)
    k_conv_mfma<__hip_bfloat16,1,8,0,1,1><<<dim3(32,4),256,0,stream>>>(t3, wpB1, r1b, nullptr, u3, 64,64,64,64);
    // out3 = t3 + conv3x3(u3) -> f32 d_out
    k_conv_mfma<__hip_bfloat16,1,8,2,0,0><<<dim3(32,4),256,0,stream>>>(u3, wpB2, r2b, t3, ob2, 64,64,64,64);
}

// Round 19
// 350.247 us; speedup vs baseline: 3.0677x; 1.4303x over previous
//
#include <hip/hip_runtime.h>
#include <hip/hip_bf16.h>
#include <cstddef>
#include <cstdint>

#define DEV __device__ __forceinline__

DEV float lrelu_f(float z){ return z >= 0.f ? z : 0.1f*z; }

typedef __bf16 bf16x8 __attribute__((ext_vector_type(8)));
typedef float  f32x4  __attribute__((ext_vector_type(4)));
typedef unsigned short u16x8 __attribute__((ext_vector_type(8)));

DEV unsigned short bf_bits(float v){
    __hip_bfloat16 h = __float2bfloat16(v);
    unsigned short s; __builtin_memcpy(&s, &h, 2); return s;
}
DEV unsigned short bf_bits(__hip_bfloat16 v){
    unsigned short s; __builtin_memcpy(&s, &v, 2); return s;
}
DEV float u16_to_f(unsigned short s){
    unsigned int u = ((unsigned int)s) << 16;
    float f; __builtin_memcpy(&f, &u, 4); return f;
}
// bijective XCD swizzle for gridDim.x % 8 == 0
DEV int xswz(int bx, int n){ return (bx & 7) * (n >> 3) + (bx >> 3); }

// ---------------- merged weight prep (wpA, wp1, wp2, wpF) ---------------------
__global__ __launch_bounds__(256) void k_prep_all(
    const float* __restrict__ c1w,
    const float* __restrict__ ew1, const float* __restrict__ bn1g, const float* __restrict__ bn1v,
    const float* __restrict__ ew2, const float* __restrict__ bn2g, const float* __restrict__ bn2v,
    const float* __restrict__ cw, const float* __restrict__ caw1, const float* __restrict__ caw2,
    __hip_bfloat16* __restrict__ wpA, __hip_bfloat16* __restrict__ wp1,
    __hip_bfloat16* __restrict__ wp2, __hip_bfloat16* __restrict__ wpF)
{
    const int blk = blockIdx.x, tid = threadIdx.x;
    if (blk < 144){
        int i = blk*256 + tid;
        int e = i & 7, coA = (i>>3)&63, g = (i>>9)&3, f = i>>11;
        int ch = (f>=9)?1:0, pos = f-9*ch;
        wpA[i] = __float2bfloat16(c1w[coA*576 + (ch*32+g*8+e)*9 + pos]);
    } else if (blk < 432){
        int i = (blk-144)*256 + tid;
        int e = i & 7, co = (i>>3)&127, g = (i>>10)&3, f = i>>12;
        int ch = (f>=9)?1:0, pos = f-9*ch;
        float s = bn1g[co] / sqrtf(bn1v[co] + 1e-5f);
        wp1[i] = __float2bfloat16(ew1[co*576 + (ch*32+g*8+e)*9 + pos] * s);
    } else if (blk < 1584){
        int i = (blk-432)*256 + tid;
        int e = i & 7, co = (i>>3)&255, g = (i>>11)&3, f = i>>13;
        int ch = f/9, pos = f-9*ch;
        float s = bn2g[co] / sqrtf(bn2v[co] + 1e-5f);
        wp2[i] = __float2bfloat16(ew2[co*1152 + (ch*32+g*8+e)*9 + pos] * s);
    } else {
        int i = (blk-1584)*256 + tid;
        if (i < 4096){
            int e = i&7, co = (i>>3)&63, g = (i>>9)&3, ch = i>>11;
            wpF[i] = __float2bfloat16(cw[co*64 + ch*32 + g*8 + e]);
        } else if (i < 6144){
            int j = i - 4096;
            int e = j&7, co = (j>>3)&31, g = (j>>8)&3, ch = j>>10;
            wpF[i] = __float2bfloat16(caw1[co*64 + ch*32 + g*8 + e]);
        } else {
            int j = i - 6144;
            int e = j&7, co = (j>>3)&63, g = j>>9;
            wpF[i] = __float2bfloat16(caw2[co*32 + g*8 + e]);
        }
    }
}

// ---------------- merged wpB prep (c2w, r1w, r2w) -----------------------------
__global__ __launch_bounds__(256) void k_wprepB(
    const float* __restrict__ c2w, const float* __restrict__ r1w,
    const float* __restrict__ r2w, __hip_bfloat16* __restrict__ wpB)
{
    int i = blockIdx.x*256 + threadIdx.x;
    int sel = i / 36864;
    int j   = i - sel*36864;
    const float* w = (sel==0) ? c2w : (sel==1) ? r1w : r2w;
    int e = j & 7, coA = (j>>3)&63, g = (j>>9)&3, f = j>>11;
    int ch = (f>=9)?1:0, pos = f-9*ch;
    wpB[i] = __float2bfloat16(w[coA*576 + (ch*32+g*8+e)*9 + pos]);
}

// ---------------- K1 v2: enc1 as MFMA conv ------------------------------------
__global__ __launch_bounds__(256) void k_enc1m(
    const float* __restrict__ y, const __hip_bfloat16* __restrict__ wp1,
    const float* __restrict__ eb1, const float* __restrict__ bng,
    const float* __restrict__ bnb, const float* __restrict__ bnm,
    const float* __restrict__ bnv, __hip_bfloat16* __restrict__ e1b)
{
    __shared__ __align__(16) char lA[9*33*128];
    const int tid = threadIdx.x;
    const int wid = tid >> 6, lane = tid & 63;
    const int l15 = lane & 15, lg = lane >> 4;
    const int b = blockIdx.y, tile = blockIdx.x;
    const int toh = (tile >> 1) * 4;
    const int tow = (tile & 1) * 16;
    const int row0 = toh*2 - 1, col0 = tow*2 - 1;

    for (int i = tid; i < 9*33*64; i += 256){
        int c  = i % 33;
        int t  = i / 33;
        int r  = t % 9;
        int ci = t / 9;
        int ih = row0 + r, iw = col0 + c;
        unsigned short bits = 0;
        if (ih >= 0 && ih < 64 && iw >= 0 && iw < 64)
            bits = bf_bits(y[((size_t)(b*64+ci) << 12) + ih*64 + iw]);
        *(unsigned short*)(lA + ((r*33+c)*8 + ((ci>>3) ^ (c&7)))*16 + (ci&7)*2) = bits;
    }
    __syncthreads();

    f32x4 acc[2][4];
    #pragma unroll
    for (int s = 0; s < 2; ++s)
        #pragma unroll
        for (int n = 0; n < 4; ++n) acc[s][n] = (f32x4){0.f,0.f,0.f,0.f};

    #pragma unroll
    for (int ch = 0; ch < 2; ++ch){
        #pragma unroll
        for (int pos = 0; pos < 9; ++pos){
            const int f = ch*9 + pos;
            const int kh = pos/3, kw = pos - 3*(pos/3);
            bf16x8 bx[4];
            #pragma unroll
            for (int n = 0; n < 4; ++n){
                const int rr = n*2 + kh, cc = l15*2 + kw;
                bx[n] = *(const bf16x8*)(lA + ((rr*33+cc)*8 + ((ch*4+lg) ^ (cc&7)))*16);
            }
            #pragma unroll
            for (int s = 0; s < 2; ++s){
                const int coA = wid*32 + s*16 + l15;
                bf16x8 aw = *(const bf16x8*)(wp1 + ((size_t)(f*4 + lg)*128 + coA)*8);
                #pragma unroll
                for (int n = 0; n < 4; ++n)
                    acc[s][n] = __builtin_amdgcn_mfma_f32_16x16x32_bf16(aw, bx[n], acc[s][n], 0,0,0);
            }
        }
    }

    #pragma unroll
    for (int s = 0; s < 2; ++s){
        #pragma unroll
        for (int r = 0; r < 4; ++r){
            const int co = wid*32 + s*16 + lg*4 + r;
            float sb = bng[co] / sqrtf(bnv[co] + 1e-5f);
            float bs = (eb1[co] - bnm[co])*sb + bnb[co];
            #pragma unroll
            for (int n = 0; n < 4; ++n){
                int oh = toh + n, ow = tow + l15;
                e1b[((size_t)(b*128+co) << 10) + oh*32 + ow]
                    = __float2bfloat16(lrelu_f(acc[s][n][r] + bs));
            }
        }
    }
}

// ---------------- K2 v2: enc2 as MFMA conv + masked mean partials -------------
__global__ __launch_bounds__(256) void k_enc2m(
    const __hip_bfloat16* __restrict__ e1b, const __hip_bfloat16* __restrict__ wp2,
    const float* __restrict__ bias, const float* __restrict__ g_,
    const float* __restrict__ bb, const float* __restrict__ m_,
    const float* __restrict__ v_, float* __restrict__ partial)
{
    __shared__ __align__(16) char lA[6*18*16*16];
    const int tid = threadIdx.x;
    const int wid = tid >> 6, lane = tid & 63;
    const int l15 = lane & 15, lg = lane >> 4;
    const int b = blockIdx.y, tile = blockIdx.x;
    const int toh = (tile >> 1) * 4;
    const int tow = (tile & 1) * 16;

    for (int i = tid; i < 13824; i += 256){
        int c  = i % 18;
        int t  = i / 18;
        int r  = t % 6;
        int ci = t / 6;
        int ih = toh + r, iw = tow + c;
        unsigned short bits = 0;
        if (ih < 32 && iw < 32)
            bits = bf_bits(e1b[((size_t)(b*128+ci) << 10) + ih*32 + iw]);
        *(unsigned short*)(lA + ((r*18+c)*16 + ((ci>>3) ^ (c&7)))*16 + (ci&7)*2) = bits;
    }
    __syncthreads();

    f32x4 acc[4][4];
    #pragma unroll
    for (int s = 0; s < 4; ++s)
        #pragma unroll
        for (int n = 0; n < 4; ++n) acc[s][n] = (f32x4){0.f,0.f,0.f,0.f};

    #pragma unroll
    for (int ch = 0; ch < 4; ++ch){
        #pragma unroll
        for (int pos = 0; pos < 9; ++pos){
            const int f = ch*9 + pos;
            const int kh = pos/3, kw = pos - 3*(pos/3);
            bf16x8 bx[4];
            #pragma unroll
            for (int n = 0; n < 4; ++n){
                const int rr = n + kh, cc = l15 + kw;
                bx[n] = *(const bf16x8*)(lA + ((rr*18+cc)*16 + ((ch*4+lg) ^ (cc&7)))*16);
            }
            #pragma unroll
            for (int s = 0; s < 4; ++s){
                const int coA = wid*64 + s*16 + l15;
                bf16x8 aw = *(const bf16x8*)(wp2 + ((size_t)(f*4 + lg)*256 + coA)*8);
                #pragma unroll
                for (int n = 0; n < 4; ++n)
                    acc[s][n] = __builtin_amdgcn_mfma_f32_16x16x32_bf16(aw, bx[n], acc[s][n], 0,0,0);
            }
        }
    }

    const int ow = tow + l15;
    const bool owok = ow < 30;
    #pragma unroll
    for (int s = 0; s < 4; ++s){
        #pragma unroll
        for (int r = 0; r < 4; ++r){
            const int co = wid*64 + s*16 + lg*4 + r;
            float sb = g_[co] / sqrtf(v_[co] + 1e-5f);
            float bs = (bias[co] - m_[co])*sb + bb[co];
            float th = 0.f;
            #pragma unroll
            for (int n = 0; n < 4; ++n){
                if (owok && (toh + n) < 30)
                    th += lrelu_f(acc[s][n][r] + bs);
            }
            th += __shfl_xor(th, 1);
            th += __shfl_xor(th, 2);
            th += __shfl_xor(th, 4);
            th += __shfl_xor(th, 8);
            if (l15 == 0)
                partial[((size_t)(b*16 + tile))*256 + co] = th;
        }
    }
}

// ---------------- K3: MLP (+folded enc2 partial reduction) --------------------
__global__ __launch_bounds__(256) void k_mlp(
    const float* __restrict__ partial,
    const float* __restrict__ mw1, const float* __restrict__ mb1,
    const float* __restrict__ mw2, const float* __restrict__ mb2,
    const float* __restrict__ kw1, const float* __restrict__ kw2,
    float* __restrict__ kern)
{
    __shared__ float fs[256], h1[256], emb[256], k1[128];
    int b = blockIdx.x, t = threadIdx.x;
    {
        float s = 0.f;
        #pragma unroll
        for (int tt = 0; tt < 16; ++tt)
            s += partial[((size_t)(b*16 + tt))*256 + t];
        fs[t] = s * (1.f/900.f);
    }
    __syncthreads();
    {
        float acc = mb1[t];
        const float* wr = mw1 + t*256;
        for (int i=0;i<256;++i) acc += fs[i]*wr[i];
        h1[t] = lrelu_f(acc);
    }
    __syncthreads();
    {
        float acc = mb2[t];
        const float* wr = mw2 + t*256;
        for (int i=0;i<256;++i) acc += h1[i]*wr[i];
        emb[t] = acc;
    }
    __syncthreads();
    if (t < 128){
        float acc = 0.f;
        const float* wr = kw1 + t*256;
        for (int i=0;i<256;++i) acc += emb[i]*wr[i];
        k1[t] = lrelu_f(acc);
    }
    __syncthreads();
    for (int o=t; o<576; o+=256){
        float acc = 0.f;
        const float* wr = kw2 + o*128;
        for (int i=0;i<128;++i) acc += k1[i]*wr[i];
        kern[b*576+o] = acc;
    }
}

// ---------------- K4 v3: fused {dyn depthwise + 1x1 + CA + combine}, MFMA -----
__global__ __launch_bounds__(256) void k_fuse(
    const float* __restrict__ x, const float* __restrict__ kern,
    const __hip_bfloat16* __restrict__ wpF, const float* __restrict__ cb,
    __hip_bfloat16* __restrict__ buf)
{
    __shared__ __align__(16) char lA [6*18*128];
    __shared__ __align__(16) char lD [64*128];
    __shared__ __align__(16) char lA1[64*64];
    __shared__ float kern_s[576];

    const int tid = threadIdx.x;
    const int wid = tid >> 6, lane = tid & 63;
    const int l15 = lane & 15, lg = lane >> 4;
    const int b = blockIdx.y;
    const int bx = xswz(blockIdx.x, gridDim.x);
    const int toh = (bx >> 4) * 4;
    const int tow = (bx & 15) * 16;
    const int row0 = toh - 1;
    const int col0 = tow - 1;

    const bool cfast = (tow >= 1) && (tow + 20 <= 256);
    for (int i = tid; i < 6*64; i += 256){
        const int ci = i & 63, r = i >> 6;
        const int ih = row0 + r;
        if (ih < 0 || ih >= 256){
            #pragma unroll
            for (int c = 0; c < 18; ++c)
                *(unsigned short*)(lA + ((r*18+c)*8 + ((ci>>3)^(c&7)))*16 + (ci&7)*2) = 0;
        } else {
            const float* srow = x + ((size_t)(b*64+ci) << 16) + ih*256;
            if (cfast){
                float edge = srow[tow-1];
                f32x4 chk[5];
                #pragma unroll
                for (int k = 0; k < 5; ++k)
                    chk[k] = *(const f32x4*)(srow + tow + k*4);
                *(unsigned short*)(lA + ((r*18+0)*8 + ((ci>>3)^0))*16 + (ci&7)*2) = bf_bits(edge);
                #pragma unroll
                for (int c = 1; c < 18; ++c){
                    const int idx = c - 1;
                    unsigned short bits = bf_bits(chk[idx>>2][idx&3]);
                    *(unsigned short*)(lA + ((r*18+c)*8 + ((ci>>3)^(c&7)))*16 + (ci&7)*2) = bits;
                }
            } else {
                #pragma unroll
                for (int c = 0; c < 18; ++c){
                    int iw = col0 + c;
                    unsigned short bits = 0;
                    if (iw >= 0 && iw < 256) bits = bf_bits(srow[iw]);
                    *(unsigned short*)(lA + ((r*18+c)*8 + ((ci>>3)^(c&7)))*16 + (ci&7)*2) = bits;
                }
            }
        }
    }
    for (int i = tid; i < 576; i += 256) kern_s[i] = kern[b*576 + i];
    __syncthreads();

    const int m1 = wid & 1;
    const int nb = (wid >> 1) * 2;
    f32x4 a1acc[2] = {{0.f,0.f,0.f,0.f},{0.f,0.f,0.f,0.f}};
    const int coA1 = m1*16 + l15;
    #pragma unroll
    for (int ch = 0; ch < 2; ++ch){
        bf16x8 aA = *(const bf16x8*)(wpF + 4096 + ((ch*4+lg)*32 + coA1)*8);
        #pragma unroll
        for (int t = 0; t < 2; ++t){
            int n = nb + t;
            int cc = l15 + 1, rr = n + 1;
            bf16x8 bX = *(const bf16x8*)(lA + ((rr*18+cc)*8 + ((ch*4+lg) ^ (cc&7)))*16);
            a1acc[t] = __builtin_amdgcn_mfma_f32_16x16x32_bf16(aA, bX, a1acc[t], 0,0,0);
        }
    }

    {
        const int px = tid & 63;
        const int s0 = tid >> 6;
        const int prow = px >> 4, pcol = px & 15;
        #pragma unroll
        for (int t = 0; t < 2; ++t){
            const int sl = s0 + t*4;
            u16x8 xv[3][3];
            #pragma unroll
            for (int kh = 0; kh < 3; ++kh)
                #pragma unroll
                for (int kw = 0; kw < 3; ++kw){
                    const int r = prow + kh, c = pcol + kw;
                    xv[kh][kw] = *(const u16x8*)(lA + ((r*18+c)*8 + (sl ^ (c&7)))*16);
                }
            u16x8 outv;
            #pragma unroll
            for (int e = 0; e < 8; ++e){
                const int ci = sl*8 + e;
                const float* kr = kern_s + ci*9;
                float acc = 0.f;
                #pragma unroll
                for (int kh = 0; kh < 3; ++kh)
                    #pragma unroll
                    for (int kw = 0; kw < 3; ++kw)
                        acc += u16_to_f(xv[kh][kw][e]) * kr[kh*3+kw];
                outv[e] = bf_bits(lrelu_f(acc));
            }
            *(u16x8*)(lD + (px*8 + (sl ^ (px&7)))*16) = outv;
        }
    }

    #pragma unroll
    for (int t = 0; t < 2; ++t){
        int n = nb + t;
        int px = n*16 + l15;
        #pragma unroll
        for (int r = 0; r < 4; ++r){
            int j = m1*16 + lg*4 + r;
            *(unsigned short*)(lA1 + (px*4 + ((j>>3) ^ (px&3)))*16 + (j&7)*2)
                = bf_bits(lrelu_f(a1acc[t][r]));
        }
    }
    __syncthreads();

    f32x4 dynacc[4] = {{0.f,0.f,0.f,0.f},{0.f,0.f,0.f,0.f},{0.f,0.f,0.f,0.f},{0.f,0.f,0.f,0.f}};
    f32x4 attacc[4] = {{0.f,0.f,0.f,0.f},{0.f,0.f,0.f,0.f},{0.f,0.f,0.f,0.f},{0.f,0.f,0.f,0.f}};
    const int coA = wid*16 + l15;
    #pragma unroll
    for (int ch = 0; ch < 2; ++ch){
        bf16x8 aW = *(const bf16x8*)(wpF + ((ch*4+lg)*64 + coA)*8);
        #pragma unroll
        for (int n = 0; n < 4; ++n){
            int px = n*16 + l15;
            bf16x8 bD = *(const bf16x8*)(lD + (px*8 + ((ch*4+lg) ^ (px&7)))*16);
            dynacc[n] = __builtin_amdgcn_mfma_f32_16x16x32_bf16(aW, bD, dynacc[n], 0,0,0);
        }
    }
    {
        bf16x8 aW2 = *(const bf16x8*)(wpF + 6144 + (lg*64 + coA)*8);
        #pragma unroll
        for (int n = 0; n < 4; ++n){
            int px = n*16 + l15;
            bf16x8 bA1 = *(const bf16x8*)(lA1 + (px*4 + (lg ^ (px&3)))*16);
            attacc[n] = __builtin_amdgcn_mfma_f32_16x16x32_bf16(aW2, bA1, attacc[n], 0,0,0);
        }
    }

    #pragma unroll
    for (int n = 0; n < 4; ++n){
        int oh = toh + n, ow = tow + l15;
        const int rr = n + 1, cc = l15 + 1;
        #pragma unroll
        for (int r = 0; r < 4; ++r){
            int co = wid*16 + lg*4 + r;
            size_t oi = ((size_t)(b*64+co) << 16) + oh*256 + ow;
            float xv = u16_to_f(*(const unsigned short*)(
                lA + ((rr*18+cc)*8 + ((co>>3) ^ (cc&7)))*16 + (co&7)*2));
            float att = fmaxf(attacc[n][r], 0.f);
            float v = lrelu_f(dynacc[n][r] + cb[co] + xv*att);
            buf[oi] = __float2bfloat16(v);
        }
    }
}

// ---------------- K5 v5: MFMA implicit-GEMM conv (TH param, XCD swizzle) ------
template<typename TIN, int STRIDE, int TH, int RESMODE, int ACT, int OUTBF>
__global__ __launch_bounds__(256) void k_conv_mfma(
    const TIN* __restrict__ in, const __hip_bfloat16* __restrict__ wp,
    const float* __restrict__ bias, const void* __restrict__ res,
    void* __restrict__ outp, int H, int W, int Ho, int Wo)
{
    constexpr int ROWS = (STRIDE==1) ? TH+2 : 2*TH+1;
    constexpr int COLS = (STRIDE==1) ? 18 : 33;
    constexpr int EPC  = (sizeof(TIN)==2) ? 8 : 4;
    constexpr int NCH  = (COLS - 1 + EPC - 1) / EPC;
    __shared__ __align__(16) char lA[ROWS*COLS*128];
    const int tid = threadIdx.x;
    const int wid = tid >> 6, lane = tid & 63;
    const int l15 = lane & 15, g = lane >> 4;
    const int b   = blockIdx.y;
    const int bx  = xswz(blockIdx.x, gridDim.x);
    const int tilesW = Wo >> 4;
    const int toh = (bx / tilesW) * TH;
    const int tow = (bx % tilesW) * 16;
    const int row0 = toh*STRIDE - 1;
    const int col0 = tow*STRIDE - 1;

    bf16x8 aw[18];
    const int coA = wid*16 + l15;
    #pragma unroll
    for (int f = 0; f < 18; ++f)
        aw[f] = *(const bf16x8*)(wp + ((f*4 + g)*64 + coA)*8);

    const int base = tow*STRIDE;
    const bool cfast = (base >= 1) && (base + NCH*EPC <= W);
    for (int i = tid; i < ROWS*64; i += 256){
        const int ci = i & 63, r = i >> 6;
        const int ih = row0 + r;
        if (ih < 0 || ih >= H){
            #pragma unroll
            for (int c = 0; c < COLS; ++c)
                *(unsigned short*)(lA + ((r*COLS+c)*8 + ((ci>>3)^(c&7)))*16 + (ci&7)*2) = 0;
        } else {
            const TIN* srow = in + ((size_t)(b*64+ci))*H*W + (size_t)ih*W;
            if (cfast){
                if constexpr (sizeof(TIN) == 2){
                    unsigned short edge = bf_bits(srow[base-1]);
                    u16x8 chk[NCH];
                    #pragma unroll
                    for (int k = 0; k < NCH; ++k)
                        chk[k] = *(const u16x8*)(srow + base + k*8);
                    *(unsigned short*)(lA + ((r*COLS+0)*8 + (ci>>3))*16 + (ci&7)*2) = edge;
                    #pragma unroll
                    for (int c = 1; c < COLS; ++c){
                        const int idx = c - 1;
                        unsigned short bits = chk[idx>>3][idx&7];
                        *(unsigned short*)(lA + ((r*COLS+c)*8 + ((ci>>3)^(c&7)))*16 + (ci&7)*2) = bits;
                    }
                } else {
                    unsigned short edge = bf_bits(srow[base-1]);
                    f32x4 chk[NCH];
                    #pragma unroll
                    for (int k = 0; k < NCH; ++k)
                        chk[k] = *(const f32x4*)(srow + base + k*4);
                    *(unsigned short*)(lA + ((r*COLS+0)*8 + (ci>>3))*16 + (ci&7)*2) = edge;
                    #pragma unroll
                    for (int c = 1; c < COLS; ++c){
                        const int idx = c - 1;
                        unsigned short bits = bf_bits(chk[idx>>2][idx&3]);
                        *(unsigned short*)(lA + ((r*COLS+c)*8 + ((ci>>3)^(c&7)))*16 + (ci&7)*2) = bits;
                    }
                }
            } else {
                #pragma unroll
                for (int c = 0; c < COLS; ++c){
                    int iw = col0 + c;
                    unsigned short bits = 0;
                    if (iw >= 0 && iw < W) bits = bf_bits(srow[iw]);
                    *(unsigned short*)(lA + ((r*COLS+c)*8 + ((ci>>3)^(c&7)))*16 + (ci&7)*2) = bits;
                }
            }
        }
    }
    __syncthreads();

    float bv[4];
    #pragma unroll
    for (int r = 0; r < 4; ++r) bv[r] = bias[wid*16 + g*4 + r];
    const float*          resF = (const float*)res;
    const __hip_bfloat16* resB = (const __hip_bfloat16*)res;

    if constexpr (STRIDE == 1){
        bf16x8 Bw[3][2][3];
        auto ldrow = [&](int rr, int slot){
            #pragma unroll
            for (int ch = 0; ch < 2; ++ch)
                #pragma unroll
                for (int kw = 0; kw < 3; ++kw){
                    const int cc = l15 + kw;
                    Bw[slot][ch][kw] = *(const bf16x8*)(lA + ((rr*COLS + cc)*8 + ((ch*4+g) ^ (cc&7)))*16);
                }
        };
        ldrow(0, 0);
        ldrow(1, 1);
        #pragma unroll
        for (int n = 0; n < TH; ++n){
            ldrow(n+2, (n+2)%3);
            f32x4 acc = {0.f,0.f,0.f,0.f};
            #pragma unroll
            for (int kh = 0; kh < 3; ++kh)
                #pragma unroll
                for (int ch = 0; ch < 2; ++ch)
                    #pragma unroll
                    for (int kw = 0; kw < 3; ++kw)
                        acc = __builtin_amdgcn_mfma_f32_16x16x32_bf16(
                                aw[ch*9 + kh*3 + kw], Bw[(n+kh)%3][ch][kw], acc, 0, 0, 0);
            const int oh = toh + n, ow = tow + l15;
            #pragma unroll
            for (int r = 0; r < 4; ++r){
                int co = wid*16 + g*4 + r;
                size_t oi = ((size_t)(b*64+co)*Ho + oh)*Wo + ow;
                float v = acc[r] + bv[r];
                if (ACT) v = fmaxf(v, 0.f);
                if (RESMODE == 1) v += resF[oi];
                if (RESMODE == 2) v += __bfloat162float(resB[oi]);
                if (OUTBF) ((__hip_bfloat16*)outp)[oi] = __float2bfloat16(v);
                else       ((float*)outp)[oi] = v;
            }
        }
    } else {
        #pragma unroll
        for (int n = 0; n < TH; ++n){
            f32x4 acc = {0.f,0.f,0.f,0.f};
            #pragma unroll
            for (int ch = 0; ch < 2; ++ch)
                #pragma unroll
                for (int pos = 0; pos < 9; ++pos){
                    const int kh = pos/3, kw = pos - 3*(pos/3);
                    const int cc = l15*STRIDE + kw;
                    const int rr = n*STRIDE + kh;
                    bf16x8 bx2 = *(const bf16x8*)(lA + ((rr*COLS + cc)*8 + ((ch*4+g) ^ (cc&7)))*16);
                    acc = __builtin_amdgcn_mfma_f32_16x16x32_bf16(aw[ch*9+pos], bx2, acc, 0, 0, 0);
                }
            const int oh = toh + n, ow = tow + l15;
            #pragma unroll
            for (int r = 0; r < 4; ++r){
                int co = wid*16 + g*4 + r;
                size_t oi = ((size_t)(b*64+co)*Ho + oh)*Wo + ow;
                float v = acc[r] + bv[r];
                if (ACT) v = fmaxf(v, 0.f);
                if (RESMODE == 1) v += resF[oi];
                if (RESMODE == 2) v += __bfloat162float(resB[oi]);
                if (OUTBF) ((__hip_bfloat16*)outp)[oi] = __float2bfloat16(v);
                else       ((float*)outp)[oi] = v;
            }
        }
    }
}

// ---------------- host ---------------------------------------------------------
extern "C" void kernel_launch(void* const* d_in, const int* in_sizes, int n_in,
                              void* d_out, int out_size, void* d_ws, size_t ws_size,
                              hipStream_t stream) {
    const float* x    = (const float*)d_in[0];
    const float* y    = (const float*)d_in[1];
    const float* ew1  = (const float*)d_in[2];
    const float* eb1  = (const float*)d_in[3];
    const float* bn1g = (const float*)d_in[4];
    const float* bn1b = (const float*)d_in[5];
    const float* bn1m = (const float*)d_in[6];
    const float* bn1v = (const float*)d_in[7];
    const float* ew2  = (const float*)d_in[8];
    const float* eb2  = (const float*)d_in[9];
    const float* bn2g = (const float*)d_in[10];
    const float* bn2b = (const float*)d_in[11];
    const float* bn2m = (const float*)d_in[12];
    const float* bn2v = (const float*)d_in[13];
    const float* mw1  = (const float*)d_in[14];
    const float* mb1  = (const float*)d_in[15];
    const float* mw2  = (const float*)d_in[16];
    const float* mb2  = (const float*)d_in[17];
    const float* kw1  = (const float*)d_in[18];
    const float* kw2  = (const float*)d_in[19];
    const float* cw   = (const float*)d_in[20];
    const float* cb   = (const float*)d_in[21];
    const float* caw1 = (const float*)d_in[22];
    const float* caw2 = (const float*)d_in[23];
    const float* c1w  = (const float*)d_in[24];
    const float* c1b  = (const float*)d_in[25];
    const float* c2w  = (const float*)d_in[26];
    const float* c2b  = (const float*)d_in[27];
    const float* r1w  = (const float*)d_in[28];
    const float* r1b  = (const float*)d_in[29];
    const float* r2w  = (const float*)d_in[30];
    const float* r2b  = (const float*)d_in[31];

    char* wsc = (char*)d_ws;
    __hip_bfloat16* buf = (__hip_bfloat16*)wsc;
    __hip_bfloat16* e1b = (__hip_bfloat16*)wsc;
    __hip_bfloat16* wp2 = (__hip_bfloat16*)(wsc + 2097152);
    float*          part= (float*)(wsc + 2686976);
    __hip_bfloat16* t2  = (__hip_bfloat16*)wsc;
    __hip_bfloat16* u2  = (__hip_bfloat16*)(wsc + 8388608);
    __hip_bfloat16* t3  = (__hip_bfloat16*)(wsc + 16777216);
    __hip_bfloat16* u3  = (__hip_bfloat16*)(wsc + 18874368);
    __hip_bfloat16* wpB = (__hip_bfloat16*)(wsc + 29360128);
    __hip_bfloat16* wpB0= wpB;
    __hip_bfloat16* wpB1= wpB + 36864;
    __hip_bfloat16* wpB2= wpB + 73728;
    float*          kern= (float*)(wsc + 33558528);

    float* ob   = (float*)d_out;            // out  (4,64,256,256) f32
    float* ob1  = ob + 16777216;            // out2 (4,64,128,128) f32
    float* ob2  = ob + 20971520;            // out3 (4,64,64,64)   f32
    __hip_bfloat16* wpF = (__hip_bfloat16*)((char*)d_out + 83886080);
    __hip_bfloat16* wp1 = (__hip_bfloat16*)((char*)d_out + 84934656);
    __hip_bfloat16* wpA = (__hip_bfloat16*)((char*)d_out + 87932928);

    k_prep_all<<<dim3(1616),256,0,stream>>>(c1w, ew1, bn1g, bn1v, ew2, bn2g, bn2v,
                                            cw, caw1, caw2, wpA, wp1, wp2, wpF);
    k_enc1m<<<dim3(16,4),256,0,stream>>>(y, wp1, eb1, bn1g, bn1b, bn1m, bn1v, e1b);
    k_enc2m<<<dim3(16,4),256,0,stream>>>(e1b, wp2, eb2, bn2g, bn2b, bn2m, bn2v, part);
    k_mlp<<<dim3(4),256,0,stream>>>(part, mw1, mb1, mw2, mb2, kw1, kw2, kern);
    k_fuse<<<dim3(1024,4),256,0,stream>>>(x, kern, wpF, cb, buf);

    // out0 = conv3x3(pre) + bias + x  -> f32 d_out  (TH=8: 32x16 tiles)
    k_conv_mfma<__hip_bfloat16,1,8,1,0,0><<<dim3(512,4),256,0,stream>>>(buf, wpA, c1b, x, ob, 256,256,256,256);
    k_wprepB<<<dim3(432),256,0,stream>>>(c2w, r1w, r2w, wpB);
    // t2 = conv3x3 s2 (out0 f32) -> bf16            (TH=2: 64x8 tiles)
    k_conv_mfma<float,2,2,0,0,1><<<dim3(512,4),256,0,stream>>>(ob, wpB0, c2b, nullptr, t2, 256,256,128,128);
    // u2 = relu(conv3x3(t2)) -> bf16                (TH=8: 16x8 tiles)
    k_conv_mfma<__hip_bfloat16,1,8,0,1,1><<<dim3(128,4),256,0,stream>>>(t2, wpB1, r1b, nullptr, u2, 128,128,128,128);
    // out2 = t2 + conv3x3(u2) -> f32 d_out
    k_conv_mfma<__hip_bfloat16,1,8,2,0,0><<<dim3(128,4),256,0,stream>>>(u2, wpB2, r2b, t2, ob1, 128,128,128,128);
    // t3 = conv3x3 s2 (out2 f32) -> bf16            (TH=2: 32x4 tiles)
    k_conv_mfma<float,2,2,0,0,1><<<dim3(128,4),256,0,stream>>>(ob1, wpB0, c2b, nullptr, t3, 128,128,64,64);
    // u3 = relu(conv3x3(t3)) -> bf16                (TH=8: 8x4 tiles)
    k_conv_mfma<__hip_bfloat16,1,8,0,1,1><<<dim3(32,4),256,0,stream>>>(t3, wpB1, r1b, nullptr, u3, 64,64,64,64);
    // out3 = t3 + conv3x3(u3) -> f32 d_out
    k_conv_mfma<__hip_bfloat16,1,8,2,0,0><<<dim3(32,4),256,0,stream>>>(u3, wpB2, r2b, t3, ob2, 64,64,64,64);
}

// Round 20
// 346.101 us; speedup vs baseline: 3.1044x; 1.0120x over previous
//
#include <hip/hip_runtime.h>
#include <hip/hip_bf16.h>
#include <cstddef>
#include <cstdint>

#define DEV __device__ __forceinline__

DEV float lrelu_f(float z){ return z >= 0.f ? z : 0.1f*z; }

typedef __bf16 bf16x8 __attribute__((ext_vector_type(8)));
typedef float  f32x4  __attribute__((ext_vector_type(4)));
typedef unsigned short u16x8 __attribute__((ext_vector_type(8)));

DEV unsigned short bf_bits(float v){
    __hip_bfloat16 h = __float2bfloat16(v);
    unsigned short s; __builtin_memcpy(&s, &h, 2); return s;
}
DEV unsigned short bf_bits(__hip_bfloat16 v){
    unsigned short s; __builtin_memcpy(&s, &v, 2); return s;
}
DEV float u16_to_f(unsigned short s){
    unsigned int u = ((unsigned int)s) << 16;
    float f; __builtin_memcpy(&f, &u, 4); return f;
}
// bijective XCD swizzle for gridDim.x % 8 == 0
DEV int xswz(int bx, int n){ return (bx & 7) * (n >> 3) + (bx >> 3); }

// ---------------- merged weight prep (wpA, wp1, wp2, wpF) ---------------------
__global__ __launch_bounds__(256) void k_prep_all(
    const float* __restrict__ c1w,
    const float* __restrict__ ew1, const float* __restrict__ bn1g, const float* __restrict__ bn1v,
    const float* __restrict__ ew2, const float* __restrict__ bn2g, const float* __restrict__ bn2v,
    const float* __restrict__ cw, const float* __restrict__ caw1, const float* __restrict__ caw2,
    __hip_bfloat16* __restrict__ wpA, __hip_bfloat16* __restrict__ wp1,
    __hip_bfloat16* __restrict__ wp2, __hip_bfloat16* __restrict__ wpF)
{
    const int blk = blockIdx.x, tid = threadIdx.x;
    if (blk < 144){
        int i = blk*256 + tid;
        int e = i & 7, coA = (i>>3)&63, g = (i>>9)&3, f = i>>11;
        int ch = (f>=9)?1:0, pos = f-9*ch;
        wpA[i] = __float2bfloat16(c1w[coA*576 + (ch*32+g*8+e)*9 + pos]);
    } else if (blk < 432){
        int i = (blk-144)*256 + tid;
        int e = i & 7, co = (i>>3)&127, g = (i>>10)&3, f = i>>12;
        int ch = (f>=9)?1:0, pos = f-9*ch;
        float s = bn1g[co] / sqrtf(bn1v[co] + 1e-5f);
        wp1[i] = __float2bfloat16(ew1[co*576 + (ch*32+g*8+e)*9 + pos] * s);
    } else if (blk < 1584){
        int i = (blk-432)*256 + tid;
        int e = i & 7, co = (i>>3)&255, g = (i>>11)&3, f = i>>13;
        int ch = f/9, pos = f-9*ch;
        float s = bn2g[co] / sqrtf(bn2v[co] + 1e-5f);
        wp2[i] = __float2bfloat16(ew2[co*1152 + (ch*32+g*8+e)*9 + pos] * s);
    } else {
        int i = (blk-1584)*256 + tid;
        if (i < 4096){
            int e = i&7, co = (i>>3)&63, g = (i>>9)&3, ch = i>>11;
            wpF[i] = __float2bfloat16(cw[co*64 + ch*32 + g*8 + e]);
        } else if (i < 6144){
            int j = i - 4096;
            int e = j&7, co = (j>>3)&31, g = (j>>8)&3, ch = j>>10;
            wpF[i] = __float2bfloat16(caw1[co*64 + ch*32 + g*8 + e]);
        } else {
            int j = i - 6144;
            int e = j&7, co = (j>>3)&63, g = j>>9;
            wpF[i] = __float2bfloat16(caw2[co*32 + g*8 + e]);
        }
    }
}

// ---------------- merged wpB prep (c2w, r1w, r2w) -----------------------------
__global__ __launch_bounds__(256) void k_wprepB(
    const float* __restrict__ c2w, const float* __restrict__ r1w,
    const float* __restrict__ r2w, __hip_bfloat16* __restrict__ wpB)
{
    int i = blockIdx.x*256 + threadIdx.x;
    int sel = i / 36864;
    int j   = i - sel*36864;
    const float* w = (sel==0) ? c2w : (sel==1) ? r1w : r2w;
    int e = j & 7, coA = (j>>3)&63, g = (j>>9)&3, f = j>>11;
    int ch = (f>=9)?1:0, pos = f-9*ch;
    wpB[i] = __float2bfloat16(w[coA*576 + (ch*32+g*8+e)*9 + pos]);
}

// ---------------- K1 v2: enc1 as MFMA conv ------------------------------------
__global__ __launch_bounds__(256) void k_enc1m(
    const float* __restrict__ y, const __hip_bfloat16* __restrict__ wp1,
    const float* __restrict__ eb1, const float* __restrict__ bng,
    const float* __restrict__ bnb, const float* __restrict__ bnm,
    const float* __restrict__ bnv, __hip_bfloat16* __restrict__ e1b)
{
    __shared__ __align__(16) char lA[9*33*128];
    const int tid = threadIdx.x;
    const int wid = tid >> 6, lane = tid & 63;
    const int l15 = lane & 15, lg = lane >> 4;
    const int b = blockIdx.y, tile = blockIdx.x;
    const int toh = (tile >> 1) * 4;
    const int tow = (tile & 1) * 16;
    const int row0 = toh*2 - 1, col0 = tow*2 - 1;

    for (int i = tid; i < 9*33*64; i += 256){
        int c  = i % 33;
        int t  = i / 33;
        int r  = t % 9;
        int ci = t / 9;
        int ih = row0 + r, iw = col0 + c;
        unsigned short bits = 0;
        if (ih >= 0 && ih < 64 && iw >= 0 && iw < 64)
            bits = bf_bits(y[((size_t)(b*64+ci) << 12) + ih*64 + iw]);
        *(unsigned short*)(lA + ((r*33+c)*8 + ((ci>>3) ^ (c&7)))*16 + (ci&7)*2) = bits;
    }
    __syncthreads();

    f32x4 acc[2][4];
    #pragma unroll
    for (int s = 0; s < 2; ++s)
        #pragma unroll
        for (int n = 0; n < 4; ++n) acc[s][n] = (f32x4){0.f,0.f,0.f,0.f};

    #pragma unroll
    for (int ch = 0; ch < 2; ++ch){
        #pragma unroll
        for (int pos = 0; pos < 9; ++pos){
            const int f = ch*9 + pos;
            const int kh = pos/3, kw = pos - 3*(pos/3);
            bf16x8 bx[4];
            #pragma unroll
            for (int n = 0; n < 4; ++n){
                const int rr = n*2 + kh, cc = l15*2 + kw;
                bx[n] = *(const bf16x8*)(lA + ((rr*33+cc)*8 + ((ch*4+lg) ^ (cc&7)))*16);
            }
            #pragma unroll
            for (int s = 0; s < 2; ++s){
                const int coA = wid*32 + s*16 + l15;
                bf16x8 aw = *(const bf16x8*)(wp1 + ((size_t)(f*4 + lg)*128 + coA)*8);
                #pragma unroll
                for (int n = 0; n < 4; ++n)
                    acc[s][n] = __builtin_amdgcn_mfma_f32_16x16x32_bf16(aw, bx[n], acc[s][n], 0,0,0);
            }
        }
    }

    #pragma unroll
    for (int s = 0; s < 2; ++s){
        #pragma unroll
        for (int r = 0; r < 4; ++r){
            const int co = wid*32 + s*16 + lg*4 + r;
            float sb = bng[co] / sqrtf(bnv[co] + 1e-5f);
            float bs = (eb1[co] - bnm[co])*sb + bnb[co];
            #pragma unroll
            for (int n = 0; n < 4; ++n){
                int oh = toh + n, ow = tow + l15;
                e1b[((size_t)(b*128+co) << 10) + oh*32 + ow]
                    = __float2bfloat16(lrelu_f(acc[s][n][r] + bs));
            }
        }
    }
}

// ---------------- K2 v2: enc2 as MFMA conv + masked mean partials -------------
__global__ __launch_bounds__(256) void k_enc2m(
    const __hip_bfloat16* __restrict__ e1b, const __hip_bfloat16* __restrict__ wp2,
    const float* __restrict__ bias, const float* __restrict__ g_,
    const float* __restrict__ bb, const float* __restrict__ m_,
    const float* __restrict__ v_, float* __restrict__ partial)
{
    __shared__ __align__(16) char lA[6*18*16*16];
    const int tid = threadIdx.x;
    const int wid = tid >> 6, lane = tid & 63;
    const int l15 = lane & 15, lg = lane >> 4;
    const int b = blockIdx.y, tile = blockIdx.x;
    const int toh = (tile >> 1) * 4;
    const int tow = (tile & 1) * 16;

    for (int i = tid; i < 13824; i += 256){
        int c  = i % 18;
        int t  = i / 18;
        int r  = t % 6;
        int ci = t / 6;
        int ih = toh + r, iw = tow + c;
        unsigned short bits = 0;
        if (ih < 32 && iw < 32)
            bits = bf_bits(e1b[((size_t)(b*128+ci) << 10) + ih*32 + iw]);
        *(unsigned short*)(lA + ((r*18+c)*16 + ((ci>>3) ^ (c&7)))*16 + (ci&7)*2) = bits;
    }
    __syncthreads();

    f32x4 acc[4][4];
    #pragma unroll
    for (int s = 0; s < 4; ++s)
        #pragma unroll
        for (int n = 0; n < 4; ++n) acc[s][n] = (f32x4){0.f,0.f,0.f,0.f};

    #pragma unroll
    for (int ch = 0; ch < 4; ++ch){
        #pragma unroll
        for (int pos = 0; pos < 9; ++pos){
            const int f = ch*9 + pos;
            const int kh = pos/3, kw = pos - 3*(pos/3);
            bf16x8 bx[4];
            #pragma unroll
            for (int n = 0; n < 4; ++n){
                const int rr = n + kh, cc = l15 + kw;
                bx[n] = *(const bf16x8*)(lA + ((rr*18+cc)*16 + ((ch*4+lg) ^ (cc&7)))*16);
            }
            #pragma unroll
            for (int s = 0; s < 4; ++s){
                const int coA = wid*64 + s*16 + l15;
                bf16x8 aw = *(const bf16x8*)(wp2 + ((size_t)(f*4 + lg)*256 + coA)*8);
                #pragma unroll
                for (int n = 0; n < 4; ++n)
                    acc[s][n] = __builtin_amdgcn_mfma_f32_16x16x32_bf16(aw, bx[n], acc[s][n], 0,0,0);
            }
        }
    }

    const int ow = tow + l15;
    const bool owok = ow < 30;
    #pragma unroll
    for (int s = 0; s < 4; ++s){
        #pragma unroll
        for (int r = 0; r < 4; ++r){
            const int co = wid*64 + s*16 + lg*4 + r;
            float sb = g_[co] / sqrtf(v_[co] + 1e-5f);
            float bs = (bias[co] - m_[co])*sb + bb[co];
            float th = 0.f;
            #pragma unroll
            for (int n = 0; n < 4; ++n){
                if (owok && (toh + n) < 30)
                    th += lrelu_f(acc[s][n][r] + bs);
            }
            th += __shfl_xor(th, 1);
            th += __shfl_xor(th, 2);
            th += __shfl_xor(th, 4);
            th += __shfl_xor(th, 8);
            if (l15 == 0)
                partial[((size_t)(b*16 + tile))*256 + co] = th;
        }
    }
}

// ---------------- K3: MLP (+folded enc2 partial reduction) --------------------
__global__ __launch_bounds__(256) void k_mlp(
    const float* __restrict__ partial,
    const float* __restrict__ mw1, const float* __restrict__ mb1,
    const float* __restrict__ mw2, const float* __restrict__ mb2,
    const float* __restrict__ kw1, const float* __restrict__ kw2,
    float* __restrict__ kern)
{
    __shared__ float fs[256], h1[256], emb[256], k1[128];
    int b = blockIdx.x, t = threadIdx.x;
    {
        float s = 0.f;
        #pragma unroll
        for (int tt = 0; tt < 16; ++tt)
            s += partial[((size_t)(b*16 + tt))*256 + t];
        fs[t] = s * (1.f/900.f);
    }
    __syncthreads();
    {
        float acc = mb1[t];
        const float* wr = mw1 + t*256;
        for (int i=0;i<256;++i) acc += fs[i]*wr[i];
        h1[t] = lrelu_f(acc);
    }
    __syncthreads();
    {
        float acc = mb2[t];
        const float* wr = mw2 + t*256;
        for (int i=0;i<256;++i) acc += h1[i]*wr[i];
        emb[t] = acc;
    }
    __syncthreads();
    if (t < 128){
        float acc = 0.f;
        const float* wr = kw1 + t*256;
        for (int i=0;i<256;++i) acc += emb[i]*wr[i];
        k1[t] = lrelu_f(acc);
    }
    __syncthreads();
    for (int o=t; o<576; o+=256){
        float acc = 0.f;
        const float* wr = kw2 + o*128;
        for (int i=0;i<128;++i) acc += k1[i]*wr[i];
        kern[b*576+o] = acc;
    }
}

// ---------------- K4 v4: fused stage, dw via DIAGONAL MFMA --------------------
__global__ __launch_bounds__(256) void k_fuse(
    const float* __restrict__ x, const float* __restrict__ kern,
    const __hip_bfloat16* __restrict__ wpF, const float* __restrict__ cb,
    __hip_bfloat16* __restrict__ buf)
{
    __shared__ __align__(16) char lA [6*18*128];   // 13824 B
    __shared__ __align__(16) char lD [64*128];     //  8192 B
    __shared__ __align__(16) char lA1[64*80];      //  5120 B (padded stride)
    __shared__ float kern_s[576];

    const int tid = threadIdx.x;
    const int wid = tid >> 6, lane = tid & 63;
    const int l15 = lane & 15, lg = lane >> 4;
    const int b = blockIdx.y;
    const int bx = xswz(blockIdx.x, gridDim.x);
    const int toh = (bx >> 4) * 4;
    const int tow = (bx & 15) * 16;
    const int row0 = toh - 1;
    const int col0 = tow - 1;

    // ---- stage x halo ---------------------------------------------------------
    const bool cfast = (tow >= 1) && (tow + 20 <= 256);
    for (int i = tid; i < 6*64; i += 256){
        const int ci = i & 63, r = i >> 6;
        const int ih = row0 + r;
        if (ih < 0 || ih >= 256){
            #pragma unroll
            for (int c = 0; c < 18; ++c)
                *(unsigned short*)(lA + ((r*18+c)*8 + ((ci>>3)^(c&7)))*16 + (ci&7)*2) = 0;
        } else {
            const float* srow = x + ((size_t)(b*64+ci) << 16) + ih*256;
            if (cfast){
                float edge = srow[tow-1];
                f32x4 chk[5];
                #pragma unroll
                for (int k = 0; k < 5; ++k)
                    chk[k] = *(const f32x4*)(srow + tow + k*4);
                *(unsigned short*)(lA + ((r*18+0)*8 + ((ci>>3)^0))*16 + (ci&7)*2) = bf_bits(edge);
                #pragma unroll
                for (int c = 1; c < 18; ++c){
                    const int idx = c - 1;
                    unsigned short bits = bf_bits(chk[idx>>2][idx&3]);
                    *(unsigned short*)(lA + ((r*18+c)*8 + ((ci>>3)^(c&7)))*16 + (ci&7)*2) = bits;
                }
            } else {
                #pragma unroll
                for (int c = 0; c < 18; ++c){
                    int iw = col0 + c;
                    unsigned short bits = 0;
                    if (iw >= 0 && iw < 256) bits = bf_bits(srow[iw]);
                    *(unsigned short*)(lA + ((r*18+c)*8 + ((ci>>3)^(c&7)))*16 + (ci&7)*2) = bits;
                }
            }
        }
    }
    for (int i = tid; i < 576; i += 256) kern_s[i] = kern[b*576 + i];
    __syncthreads();

    // ---- a1 GEMM (caw1 . X) ---------------------------------------------------
    const int m1 = wid & 1;
    const int nb = (wid >> 1) * 2;
    f32x4 a1acc[2] = {{0.f,0.f,0.f,0.f},{0.f,0.f,0.f,0.f}};
    const int coA1 = m1*16 + l15;
    #pragma unroll
    for (int ch = 0; ch < 2; ++ch){
        bf16x8 aA = *(const bf16x8*)(wpF + 4096 + ((ch*4+lg)*32 + coA1)*8);
        #pragma unroll
        for (int t = 0; t < 2; ++t){
            int n = nb + t;
            int cc = l15 + 1, rr = n + 1;
            bf16x8 bX = *(const bf16x8*)(lA + ((rr*18+cc)*8 + ((ch*4+lg) ^ (cc&7)))*16);
            a1acc[t] = __builtin_amdgcn_mfma_f32_16x16x32_bf16(aA, bX, a1acc[t], 0,0,0);
        }
    }

    // ---- depthwise via diagonal MFMA -----------------------------------------
    // wave wid computes dw for ci in [wid*16, wid*16+16), all 64 px.
    {
        const int ch_w = wid >> 1;
        const int lghit = ((wid & 1) << 1) | (l15 >> 3);
        const int ehit  = l15 & 7;
        const int ci_self = wid*16 + l15;
        const bool lact = (lg == lghit);
        f32x4 dwc[4] = {{0.f,0.f,0.f,0.f},{0.f,0.f,0.f,0.f},{0.f,0.f,0.f,0.f},{0.f,0.f,0.f,0.f}};
        #pragma unroll
        for (int kh = 0; kh < 3; ++kh){
            #pragma unroll
            for (int kw = 0; kw < 3; ++kw){
                unsigned short kv = lact ? bf_bits(kern_s[ci_self*9 + kh*3 + kw]) : (unsigned short)0;
                u16x8 au;
                #pragma unroll
                for (int e = 0; e < 8; ++e) au[e] = (e == ehit) ? kv : (unsigned short)0;
                bf16x8 adw; __builtin_memcpy(&adw, &au, 16);
                #pragma unroll
                for (int n = 0; n < 4; ++n){
                    const int rr = n + kh, cc = l15 + kw;
                    bf16x8 bX = *(const bf16x8*)(lA + ((rr*18+cc)*8 + ((ch_w*4+lg) ^ (cc&7)))*16);
                    dwc[n] = __builtin_amdgcn_mfma_f32_16x16x32_bf16(adw, bX, dwc[n], 0,0,0);
                }
            }
        }
        // lrelu -> lD (bf16, B-frag layout for the dyn GEMM)
        #pragma unroll
        for (int n = 0; n < 4; ++n){
            int px = n*16 + l15;
            #pragma unroll
            for (int r = 0; r < 4; ++r){
                int ci = wid*16 + lg*4 + r;
                *(unsigned short*)(lD + (px*8 + ((ci>>3) ^ (px&7)))*16 + (ci&7)*2)
                    = bf_bits(lrelu_f(dwc[n][r]));
            }
        }
    }

    // ---- a1 -> lrelu -> lA1 (padded 80B stride) ------------------------------
    #pragma unroll
    for (int t = 0; t < 2; ++t){
        int n = nb + t;
        int px = n*16 + l15;
        #pragma unroll
        for (int r = 0; r < 4; ++r){
            int j = m1*16 + lg*4 + r;
            *(unsigned short*)(lA1 + (px*5 + ((j>>3) ^ (px&3)))*16 + (j&7)*2)
                = bf_bits(lrelu_f(a1acc[t][r]));
        }
    }
    __syncthreads();

    // ---- dyn & att GEMMs ------------------------------------------------------
    f32x4 dynacc[4] = {{0.f,0.f,0.f,0.f},{0.f,0.f,0.f,0.f},{0.f,0.f,0.f,0.f},{0.f,0.f,0.f,0.f}};
    f32x4 attacc[4] = {{0.f,0.f,0.f,0.f},{0.f,0.f,0.f,0.f},{0.f,0.f,0.f,0.f},{0.f,0.f,0.f,0.f}};
    const int coA = wid*16 + l15;
    #pragma unroll
    for (int ch = 0; ch < 2; ++ch){
        bf16x8 aW = *(const bf16x8*)(wpF + ((ch*4+lg)*64 + coA)*8);
        #pragma unroll
        for (int n = 0; n < 4; ++n){
            int px = n*16 + l15;
            bf16x8 bD = *(const bf16x8*)(lD + (px*8 + ((ch*4+lg) ^ (px&7)))*16);
            dynacc[n] = __builtin_amdgcn_mfma_f32_16x16x32_bf16(aW, bD, dynacc[n], 0,0,0);
        }
    }
    {
        bf16x8 aW2 = *(const bf16x8*)(wpF + 6144 + (lg*64 + coA)*8);
        #pragma unroll
        for (int n = 0; n < 4; ++n){
            int px = n*16 + l15;
            bf16x8 bA1 = *(const bf16x8*)(lA1 + (px*5 + (lg ^ (px&3)))*16);
            attacc[n] = __builtin_amdgcn_mfma_f32_16x16x32_bf16(aW2, bA1, attacc[n], 0,0,0);
        }
    }

    // ---- epilogue: x from LDS (bf16) -----------------------------------------
    #pragma unroll
    for (int n = 0; n < 4; ++n){
        int oh = toh + n, ow = tow + l15;
        const int rr = n + 1, cc = l15 + 1;
        #pragma unroll
        for (int r = 0; r < 4; ++r){
            int co = wid*16 + lg*4 + r;
            size_t oi = ((size_t)(b*64+co) << 16) + oh*256 + ow;
            float xv = u16_to_f(*(const unsigned short*)(
                lA + ((rr*18+cc)*8 + ((co>>3) ^ (cc&7)))*16 + (co&7)*2));
            float att = fmaxf(attacc[n][r], 0.f);
            float v = lrelu_f(dynacc[n][r] + cb[co] + xv*att);
            buf[oi] = __float2bfloat16(v);
        }
    }
}

// ---------------- K5 v5: MFMA implicit-GEMM conv (TH param, XCD swizzle) ------
template<typename TIN, int STRIDE, int TH, int RESMODE, int ACT, int OUTBF>
__global__ __launch_bounds__(256) void k_conv_mfma(
    const TIN* __restrict__ in, const __hip_bfloat16* __restrict__ wp,
    const float* __restrict__ bias, const void* __restrict__ res,
    void* __restrict__ outp, int H, int W, int Ho, int Wo)
{
    constexpr int ROWS = (STRIDE==1) ? TH+2 : 2*TH+1;
    constexpr int COLS = (STRIDE==1) ? 18 : 33;
    constexpr int EPC  = (sizeof(TIN)==2) ? 8 : 4;
    constexpr int NCH  = (COLS - 1 + EPC - 1) / EPC;
    __shared__ __align__(16) char lA[ROWS*COLS*128];
    const int tid = threadIdx.x;
    const int wid = tid >> 6, lane = tid & 63;
    const int l15 = lane & 15, g = lane >> 4;
    const int b   = blockIdx.y;
    const int bx  = xswz(blockIdx.x, gridDim.x);
    const int tilesW = Wo >> 4;
    const int toh = (bx / tilesW) * TH;
    const int tow = (bx % tilesW) * 16;
    const int row0 = toh*STRIDE - 1;
    const int col0 = tow*STRIDE - 1;

    bf16x8 aw[18];
    const int coA = wid*16 + l15;
    #pragma unroll
    for (int f = 0; f < 18; ++f)
        aw[f] = *(const bf16x8*)(wp + ((f*4 + g)*64 + coA)*8);

    const int base = tow*STRIDE;
    const bool cfast = (base >= 1) && (base + NCH*EPC <= W);
    for (int i = tid; i < ROWS*64; i += 256){
        const int ci = i & 63, r = i >> 6;
        const int ih = row0 + r;
        if (ih < 0 || ih >= H){
            #pragma unroll
            for (int c = 0; c < COLS; ++c)
                *(unsigned short*)(lA + ((r*COLS+c)*8 + ((ci>>3)^(c&7)))*16 + (ci&7)*2) = 0;
        } else {
            const TIN* srow = in + ((size_t)(b*64+ci))*H*W + (size_t)ih*W;
            if (cfast){
                if constexpr (sizeof(TIN) == 2){
                    unsigned short edge = bf_bits(srow[base-1]);
                    u16x8 chk[NCH];
                    #pragma unroll
                    for (int k = 0; k < NCH; ++k)
                        chk[k] = *(const u16x8*)(srow + base + k*8);
                    *(unsigned short*)(lA + ((r*COLS+0)*8 + (ci>>3))*16 + (ci&7)*2) = edge;
                    #pragma unroll
                    for (int c = 1; c < COLS; ++c){
                        const int idx = c - 1;
                        unsigned short bits = chk[idx>>3][idx&7];
                        *(unsigned short*)(lA + ((r*COLS+c)*8 + ((ci>>3)^(c&7)))*16 + (ci&7)*2) = bits;
                    }
                } else {
                    unsigned short edge = bf_bits(srow[base-1]);
                    f32x4 chk[NCH];
                    #pragma unroll
                    for (int k = 0; k < NCH; ++k)
                        chk[k] = *(const f32x4*)(srow + base + k*4);
                    *(unsigned short*)(lA + ((r*COLS+0)*8 + (ci>>3))*16 + (ci&7)*2) = edge;
                    #pragma unroll
                    for (int c = 1; c < COLS; ++c){
                        const int idx = c - 1;
                        unsigned short bits = bf_bits(chk[idx>>2][idx&3]);
                        *(unsigned short*)(lA + ((r*COLS+c)*8 + ((ci>>3)^(c&7)))*16 + (ci&7)*2) = bits;
                    }
                }
            } else {
                #pragma unroll
                for (int c = 0; c < COLS; ++c){
                    int iw = col0 + c;
                    unsigned short bits = 0;
                    if (iw >= 0 && iw < W) bits = bf_bits(srow[iw]);
                    *(unsigned short*)(lA + ((r*COLS+c)*8 + ((ci>>3)^(c&7)))*16 + (ci&7)*2) = bits;
                }
            }
        }
    }
    __syncthreads();

    float bv[4];
    #pragma unroll
    for (int r = 0; r < 4; ++r) bv[r] = bias[wid*16 + g*4 + r];
    const float*          resF = (const float*)res;
    const __hip_bfloat16* resB = (const __hip_bfloat16*)res;

    if constexpr (STRIDE == 1){
        bf16x8 Bw[3][2][3];
        auto ldrow = [&](int rr, int slot){
            #pragma unroll
            for (int ch = 0; ch < 2; ++ch)
                #pragma unroll
                for (int kw = 0; kw < 3; ++kw){
                    const int cc = l15 + kw;
                    Bw[slot][ch][kw] = *(const bf16x8*)(lA + ((rr*COLS + cc)*8 + ((ch*4+g) ^ (cc&7)))*16);
                }
        };
        ldrow(0, 0);
        ldrow(1, 1);
        #pragma unroll
        for (int n = 0; n < TH; ++n){
            ldrow(n+2, (n+2)%3);
            f32x4 acc = {0.f,0.f,0.f,0.f};
            #pragma unroll
            for (int kh = 0; kh < 3; ++kh)
                #pragma unroll
                for (int ch = 0; ch < 2; ++ch)
                    #pragma unroll
                    for (int kw = 0; kw < 3; ++kw)
                        acc = __builtin_amdgcn_mfma_f32_16x16x32_bf16(
                                aw[ch*9 + kh*3 + kw], Bw[(n+kh)%3][ch][kw], acc, 0, 0, 0);
            const int oh = toh + n, ow = tow + l15;
            #pragma unroll
            for (int r = 0; r < 4; ++r){
                int co = wid*16 + g*4 + r;
                size_t oi = ((size_t)(b*64+co)*Ho + oh)*Wo + ow;
                float v = acc[r] + bv[r];
                if (ACT) v = fmaxf(v, 0.f);
                if (RESMODE == 1) v += resF[oi];
                if (RESMODE == 2) v += __bfloat162float(resB[oi]);
                if (OUTBF) ((__hip_bfloat16*)outp)[oi] = __float2bfloat16(v);
                else       ((float*)outp)[oi] = v;
            }
        }
    } else {
        #pragma unroll
        for (int n = 0; n < TH; ++n){
            f32x4 acc = {0.f,0.f,0.f,0.f};
            #pragma unroll
            for (int ch = 0; ch < 2; ++ch)
                #pragma unroll
                for (int pos = 0; pos < 9; ++pos){
                    const int kh = pos/3, kw = pos - 3*(pos/3);
                    const int cc = l15*STRIDE + kw;
                    const int rr = n*STRIDE + kh;
                    bf16x8 bx2 = *(const bf16x8*)(lA + ((rr*COLS + cc)*8 + ((ch*4+g) ^ (cc&7)))*16);
                    acc = __builtin_amdgcn_mfma_f32_16x16x32_bf16(aw[ch*9+pos], bx2, acc, 0, 0, 0);
                }
            const int oh = toh + n, ow = tow + l15;
            #pragma unroll
            for (int r = 0; r < 4; ++r){
                int co = wid*16 + g*4 + r;
                size_t oi = ((size_t)(b*64+co)*Ho + oh)*Wo + ow;
                float v = acc[r] + bv[r];
                if (ACT) v = fmaxf(v, 0.f);
                if (RESMODE == 1) v += resF[oi];
                if (RESMODE == 2) v += __bfloat162float(resB[oi]);
                if (OUTBF) ((__hip_bfloat16*)outp)[oi] = __float2bfloat16(v);
                else       ((float*)outp)[oi] = v;
            }
        }
    }
}

// ---------------- host ---------------------------------------------------------
extern "C" void kernel_launch(void* const* d_in, const int* in_sizes, int n_in,
                              void* d_out, int out_size, void* d_ws, size_t ws_size,
                              hipStream_t stream) {
    const float* x    = (const float*)d_in[0];
    const float* y    = (const float*)d_in[1];
    const float* ew1  = (const float*)d_in[2];
    const float* eb1  = (const float*)d_in[3];
    const float* bn1g = (const float*)d_in[4];
    const float* bn1b = (const float*)d_in[5];
    const float* bn1m = (const float*)d_in[6];
    const float* bn1v = (const float*)d_in[7];
    const float* ew2  = (const float*)d_in[8];
    const float* eb2  = (const float*)d_in[9];
    const float* bn2g = (const float*)d_in[10];
    const float* bn2b = (const float*)d_in[11];
    const float* bn2m = (const float*)d_in[12];
    const float* bn2v = (const float*)d_in[13];
    const float* mw1  = (const float*)d_in[14];
    const float* mb1  = (const float*)d_in[15];
    const float* mw2  = (const float*)d_in[16];
    const float* mb2  = (const float*)d_in[17];
    const float* kw1  = (const float*)d_in[18];
    const float* kw2  = (const float*)d_in[19];
    const float* cw   = (const float*)d_in[20];
    const float* cb   = (const float*)d_in[21];
    const float* caw1 = (const float*)d_in[22];
    const float* caw2 = (const float*)d_in[23];
    const float* c1w  = (const float*)d_in[24];
    const float* c1b  = (const float*)d_in[25];
    const float* c2w  = (const float*)d_in[26];
    const float* c2b  = (const float*)d_in[27];
    const float* r1w  = (const float*)d_in[28];
    const float* r1b  = (const float*)d_in[29];
    const float* r2w  = (const float*)d_in[30];
    const float* r2b  = (const float*)d_in[31];

    char* wsc = (char*)d_ws;
    __hip_bfloat16* buf = (__hip_bfloat16*)wsc;
    __hip_bfloat16* e1b = (__hip_bfloat16*)wsc;
    __hip_bfloat16* wp2 = (__hip_bfloat16*)(wsc + 2097152);
    float*          part= (float*)(wsc + 2686976);
    __hip_bfloat16* t2  = (__hip_bfloat16*)wsc;
    __hip_bfloat16* u2  = (__hip_bfloat16*)(wsc + 8388608);
    __hip_bfloat16* t3  = (__hip_bfloat16*)(wsc + 16777216);
    __hip_bfloat16* u3  = (__hip_bfloat16*)(wsc + 18874368);
    __hip_bfloat16* wpB = (__hip_bfloat16*)(wsc + 29360128);
    __hip_bfloat16* wpB0= wpB;
    __hip_bfloat16* wpB1= wpB + 36864;
    __hip_bfloat16* wpB2= wpB + 73728;
    float*          kern= (float*)(wsc + 33558528);

    float* ob   = (float*)d_out;            // out  (4,64,256,256) f32
    float* ob1  = ob + 16777216;            // out2 (4,64,128,128) f32
    float* ob2  = ob + 20971520;            // out3 (4,64,64,64)   f32
    __hip_bfloat16* wpF = (__hip_bfloat16*)((char*)d_out + 83886080);
    __hip_bfloat16* wp1 = (__hip_bfloat16*)((char*)d_out + 84934656);
    __hip_bfloat16* wpA = (__hip_bfloat16*)((char*)d_out + 87932928);

    k_prep_all<<<dim3(1616),256,0,stream>>>(c1w, ew1, bn1g, bn1v, ew2, bn2g, bn2v,
                                            cw, caw1, caw2, wpA, wp1, wp2, wpF);
    k_enc1m<<<dim3(16,4),256,0,stream>>>(y, wp1, eb1, bn1g, bn1b, bn1m, bn1v, e1b);
    k_enc2m<<<dim3(16,4),256,0,stream>>>(e1b, wp2, eb2, bn2g, bn2b, bn2m, bn2v, part);
    k_mlp<<<dim3(4),256,0,stream>>>(part, mw1, mb1, mw2, mb2, kw1, kw2, kern);
    k_fuse<<<dim3(1024,4),256,0,stream>>>(x, kern, wpF, cb, buf);

    // out0 = conv3x3(pre) + bias + x  -> f32 d_out  (TH=8: 32x16 tiles)
    k_conv_mfma<__hip_bfloat16,1,8,1,0,0><<<dim3(512,4),256,0,stream>>>(buf, wpA, c1b, x, ob, 256,256,256,256);
    k_wprepB<<<dim3(432),256,0,stream>>>(c2w, r1w, r2w, wpB);
    // t2 = conv3x3 s2 (out0 f32) -> bf16            (TH=2: 64x8 tiles)
    k_conv_mfma<float,2,2,0,0,1><<<dim3(512,4),256,0,stream>>>(ob, wpB0, c2b, nullptr, t2, 256,256,128,128);
    // u2 = relu(conv3x3(t2)) -> bf16                (TH=8: 16x8 tiles)
    k_conv_mfma<__hip_bfloat16,1,8,0,1,1><<<dim3(128,4),256,0,stream>>>(t2, wpB1, r1b, nullptr, u2, 128,128,128,128);
    // out2 = t2 + conv3x3(u2) -> f32 d_out
    k_conv_mfma<__hip_bfloat16,1,8,2,0,0><<<dim3(128,4),256,0,stream>>>(u2, wpB2, r2b, t2, ob1, 128,128,128,128);
    // t3 = conv3x3 s2 (out2 f32) -> bf16            (TH=2: 32x4 tiles)
    k_conv_mfma<float,2,2,0,0,1><<<dim3(128,4),256,0,stream>>>(ob1, wpB0, c2b, nullptr, t3, 128,128,64,64);
    // u3 = relu(conv3x3(t3)) -> bf16                (TH=8: 8x4 tiles)
    k_conv_mfma<__hip_bfloat16,1,8,0,1,1><<<dim3(32,4),256,0,stream>>>(t3, wpB1, r1b, nullptr, u3, 64,64,64,64);
    // out3 = t3 + conv3x3(u3) -> f32 d_out
    k_conv_mfma<__hip_bfloat16,1,8,2,0,0><<<dim3(32,4),256,0,stream>>>(u3, wpB2, r2b, t3, ob2, 64,64,64,64);
}

// Round 21
// 341.907 us; speedup vs baseline: 3.1425x; 1.0123x over previous
//
#include <hip/hip_runtime.h>
#include <hip/hip_bf16.h>
#include <cstddef>
#include <cstdint>

#define DEV __device__ __forceinline__

DEV float lrelu_f(float z){ return z >= 0.f ? z : 0.1f*z; }

typedef __bf16 bf16x8 __attribute__((ext_vector_type(8)));
typedef float  f32x4  __attribute__((ext_vector_type(4)));
typedef unsigned short u16x8 __attribute__((ext_vector_type(8)));

DEV unsigned short bf_bits(float v){
    __hip_bfloat16 h = __float2bfloat16(v);
    unsigned short s; __builtin_memcpy(&s, &h, 2); return s;
}
DEV unsigned short bf_bits(__hip_bfloat16 v){
    unsigned short s; __builtin_memcpy(&s, &v, 2); return s;
}
DEV float u16_to_f(unsigned short s){
    unsigned int u = ((unsigned int)s) << 16;
    float f; __builtin_memcpy(&f, &u, 4); return f;
}
// bijective XCD swizzle for gridDim.x % 8 == 0
DEV int xswz(int bx, int n){ return (bx & 7) * (n >> 3) + (bx >> 3); }

// ---------------- merged weight prep (wpA, wp1, wp2, wpF) ---------------------
__global__ __launch_bounds__(256) void k_prep_all(
    const float* __restrict__ c1w,
    const float* __restrict__ ew1, const float* __restrict__ bn1g, const float* __restrict__ bn1v,
    const float* __restrict__ ew2, const float* __restrict__ bn2g, const float* __restrict__ bn2v,
    const float* __restrict__ cw, const float* __restrict__ caw1, const float* __restrict__ caw2,
    __hip_bfloat16* __restrict__ wpA, __hip_bfloat16* __restrict__ wp1,
    __hip_bfloat16* __restrict__ wp2, __hip_bfloat16* __restrict__ wpF)
{
    const int blk = blockIdx.x, tid = threadIdx.x;
    if (blk < 144){
        int i = blk*256 + tid;
        int e = i & 7, coA = (i>>3)&63, g = (i>>9)&3, f = i>>11;
        int ch = (f>=9)?1:0, pos = f-9*ch;
        wpA[i] = __float2bfloat16(c1w[coA*576 + (ch*32+g*8+e)*9 + pos]);
    } else if (blk < 432){
        int i = (blk-144)*256 + tid;
        int e = i & 7, co = (i>>3)&127, g = (i>>10)&3, f = i>>12;
        int ch = (f>=9)?1:0, pos = f-9*ch;
        float s = bn1g[co] / sqrtf(bn1v[co] + 1e-5f);
        wp1[i] = __float2bfloat16(ew1[co*576 + (ch*32+g*8+e)*9 + pos] * s);
    } else if (blk < 1584){
        int i = (blk-432)*256 + tid;
        int e = i & 7, co = (i>>3)&255, g = (i>>11)&3, f = i>>13;
        int ch = f/9, pos = f-9*ch;
        float s = bn2g[co] / sqrtf(bn2v[co] + 1e-5f);
        wp2[i] = __float2bfloat16(ew2[co*1152 + (ch*32+g*8+e)*9 + pos] * s);
    } else {
        int i = (blk-1584)*256 + tid;
        if (i < 4096){
            int e = i&7, co = (i>>3)&63, g = (i>>9)&3, ch = i>>11;
            wpF[i] = __float2bfloat16(cw[co*64 + ch*32 + g*8 + e]);
        } else if (i < 6144){
            int j = i - 4096;
            int e = j&7, co = (j>>3)&31, g = (j>>8)&3, ch = j>>10;
            wpF[i] = __float2bfloat16(caw1[co*64 + ch*32 + g*8 + e]);
        } else {
            int j = i - 6144;
            int e = j&7, co = (j>>3)&63, g = j>>9;
            wpF[i] = __float2bfloat16(caw2[co*32 + g*8 + e]);
        }
    }
}

// ---------------- merged wpB prep (c2w, r1w, r2w) -----------------------------
__global__ __launch_bounds__(256) void k_wprepB(
    const float* __restrict__ c2w, const float* __restrict__ r1w,
    const float* __restrict__ r2w, __hip_bfloat16* __restrict__ wpB)
{
    int i = blockIdx.x*256 + threadIdx.x;
    int sel = i / 36864;
    int j   = i - sel*36864;
    const float* w = (sel==0) ? c2w : (sel==1) ? r1w : r2w;
    int e = j & 7, coA = (j>>3)&63, g = (j>>9)&3, f = j>>11;
    int ch = (f>=9)?1:0, pos = f-9*ch;
    wpB[i] = __float2bfloat16(w[coA*576 + (ch*32+g*8+e)*9 + pos]);
}

// ---------------- K1 v2: enc1 as MFMA conv ------------------------------------
__global__ __launch_bounds__(256) void k_enc1m(
    const float* __restrict__ y, const __hip_bfloat16* __restrict__ wp1,
    const float* __restrict__ eb1, const float* __restrict__ bng,
    const float* __restrict__ bnb, const float* __restrict__ bnm,
    const float* __restrict__ bnv, __hip_bfloat16* __restrict__ e1b)
{
    __shared__ __align__(16) char lA[9*33*128];
    const int tid = threadIdx.x;
    const int wid = tid >> 6, lane = tid & 63;
    const int l15 = lane & 15, lg = lane >> 4;
    const int b = blockIdx.y, tile = blockIdx.x;
    const int toh = (tile >> 1) * 4;
    const int tow = (tile & 1) * 16;
    const int row0 = toh*2 - 1, col0 = tow*2 - 1;

    for (int i = tid; i < 9*33*64; i += 256){
        int c  = i % 33;
        int t  = i / 33;
        int r  = t % 9;
        int ci = t / 9;
        int ih = row0 + r, iw = col0 + c;
        unsigned short bits = 0;
        if (ih >= 0 && ih < 64 && iw >= 0 && iw < 64)
            bits = bf_bits(y[((size_t)(b*64+ci) << 12) + ih*64 + iw]);
        *(unsigned short*)(lA + ((r*33+c)*8 + ((ci>>3) ^ (c&7)))*16 + (ci&7)*2) = bits;
    }
    __syncthreads();

    f32x4 acc[2][4];
    #pragma unroll
    for (int s = 0; s < 2; ++s)
        #pragma unroll
        for (int n = 0; n < 4; ++n) acc[s][n] = (f32x4){0.f,0.f,0.f,0.f};

    #pragma unroll
    for (int ch = 0; ch < 2; ++ch){
        #pragma unroll
        for (int pos = 0; pos < 9; ++pos){
            const int f = ch*9 + pos;
            const int kh = pos/3, kw = pos - 3*(pos/3);
            bf16x8 bx[4];
            #pragma unroll
            for (int n = 0; n < 4; ++n){
                const int rr = n*2 + kh, cc = l15*2 + kw;
                bx[n] = *(const bf16x8*)(lA + ((rr*33+cc)*8 + ((ch*4+lg) ^ (cc&7)))*16);
            }
            #pragma unroll
            for (int s = 0; s < 2; ++s){
                const int coA = wid*32 + s*16 + l15;
                bf16x8 aw = *(const bf16x8*)(wp1 + ((size_t)(f*4 + lg)*128 + coA)*8);
                #pragma unroll
                for (int n = 0; n < 4; ++n)
                    acc[s][n] = __builtin_amdgcn_mfma_f32_16x16x32_bf16(aw, bx[n], acc[s][n], 0,0,0);
            }
        }
    }

    #pragma unroll
    for (int s = 0; s < 2; ++s){
        #pragma unroll
        for (int r = 0; r < 4; ++r){
            const int co = wid*32 + s*16 + lg*4 + r;
            float sb = bng[co] / sqrtf(bnv[co] + 1e-5f);
            float bs = (eb1[co] - bnm[co])*sb + bnb[co];
            #pragma unroll
            for (int n = 0; n < 4; ++n){
                int oh = toh + n, ow = tow + l15;
                e1b[((size_t)(b*128+co) << 10) + oh*32 + ow]
                    = __float2bfloat16(lrelu_f(acc[s][n][r] + bs));
            }
        }
    }
}

// ---------------- K2 v2: enc2 as MFMA conv + masked mean partials -------------
__global__ __launch_bounds__(256) void k_enc2m(
    const __hip_bfloat16* __restrict__ e1b, const __hip_bfloat16* __restrict__ wp2,
    const float* __restrict__ bias, const float* __restrict__ g_,
    const float* __restrict__ bb, const float* __restrict__ m_,
    const float* __restrict__ v_, float* __restrict__ partial)
{
    __shared__ __align__(16) char lA[6*18*16*16];
    const int tid = threadIdx.x;
    const int wid = tid >> 6, lane = tid & 63;
    const int l15 = lane & 15, lg = lane >> 4;
    const int b = blockIdx.y, tile = blockIdx.x;
    const int toh = (tile >> 1) * 4;
    const int tow = (tile & 1) * 16;

    for (int i = tid; i < 13824; i += 256){
        int c  = i % 18;
        int t  = i / 18;
        int r  = t % 6;
        int ci = t / 6;
        int ih = toh + r, iw = tow + c;
        unsigned short bits = 0;
        if (ih < 32 && iw < 32)
            bits = bf_bits(e1b[((size_t)(b*128+ci) << 10) + ih*32 + iw]);
        *(unsigned short*)(lA + ((r*18+c)*16 + ((ci>>3) ^ (c&7)))*16 + (ci&7)*2) = bits;
    }
    __syncthreads();

    f32x4 acc[4][4];
    #pragma unroll
    for (int s = 0; s < 4; ++s)
        #pragma unroll
        for (int n = 0; n < 4; ++n) acc[s][n] = (f32x4){0.f,0.f,0.f,0.f};

    #pragma unroll
    for (int ch = 0; ch < 4; ++ch){
        #pragma unroll
        for (int pos = 0; pos < 9; ++pos){
            const int f = ch*9 + pos;
            const int kh = pos/3, kw = pos - 3*(pos/3);
            bf16x8 bx[4];
            #pragma unroll
            for (int n = 0; n < 4; ++n){
                const int rr = n + kh, cc = l15 + kw;
                bx[n] = *(const bf16x8*)(lA + ((rr*18+cc)*16 + ((ch*4+lg) ^ (cc&7)))*16);
            }
            #pragma unroll
            for (int s = 0; s < 4; ++s){
                const int coA = wid*64 + s*16 + l15;
                bf16x8 aw = *(const bf16x8*)(wp2 + ((size_t)(f*4 + lg)*256 + coA)*8);
                #pragma unroll
                for (int n = 0; n < 4; ++n)
                    acc[s][n] = __builtin_amdgcn_mfma_f32_16x16x32_bf16(aw, bx[n], acc[s][n], 0,0,0);
            }
        }
    }

    const int ow = tow + l15;
    const bool owok = ow < 30;
    #pragma unroll
    for (int s = 0; s < 4; ++s){
        #pragma unroll
        for (int r = 0; r < 4; ++r){
            const int co = wid*64 + s*16 + lg*4 + r;
            float sb = g_[co] / sqrtf(v_[co] + 1e-5f);
            float bs = (bias[co] - m_[co])*sb + bb[co];
            float th = 0.f;
            #pragma unroll
            for (int n = 0; n < 4; ++n){
                if (owok && (toh + n) < 30)
                    th += lrelu_f(acc[s][n][r] + bs);
            }
            th += __shfl_xor(th, 1);
            th += __shfl_xor(th, 2);
            th += __shfl_xor(th, 4);
            th += __shfl_xor(th, 8);
            if (l15 == 0)
                partial[((size_t)(b*16 + tile))*256 + co] = th;
        }
    }
}

// ---------------- K3: MLP (+folded enc2 partial reduction) --------------------
__global__ __launch_bounds__(256) void k_mlp(
    const float* __restrict__ partial,
    const float* __restrict__ mw1, const float* __restrict__ mb1,
    const float* __restrict__ mw2, const float* __restrict__ mb2,
    const float* __restrict__ kw1, const float* __restrict__ kw2,
    float* __restrict__ kern)
{
    __shared__ float fs[256], h1[256], emb[256], k1[128];
    int b = blockIdx.x, t = threadIdx.x;
    {
        float s = 0.f;
        #pragma unroll
        for (int tt = 0; tt < 16; ++tt)
            s += partial[((size_t)(b*16 + tt))*256 + t];
        fs[t] = s * (1.f/900.f);
    }
    __syncthreads();
    {
        float acc = mb1[t];
        const float* wr = mw1 + t*256;
        for (int i=0;i<256;++i) acc += fs[i]*wr[i];
        h1[t] = lrelu_f(acc);
    }
    __syncthreads();
    {
        float acc = mb2[t];
        const float* wr = mw2 + t*256;
        for (int i=0;i<256;++i) acc += h1[i]*wr[i];
        emb[t] = acc;
    }
    __syncthreads();
    if (t < 128){
        float acc = 0.f;
        const float* wr = kw1 + t*256;
        for (int i=0;i<256;++i) acc += emb[i]*wr[i];
        k1[t] = lrelu_f(acc);
    }
    __syncthreads();
    for (int o=t; o<576; o+=256){
        float acc = 0.f;
        const float* wr = kw2 + o*128;
        for (int i=0;i<128;++i) acc += k1[i]*wr[i];
        kern[b*576+o] = acc;
    }
}

// ---------------- K4 v4: fused stage, dw via DIAGONAL MFMA --------------------
__global__ __launch_bounds__(256) void k_fuse(
    const float* __restrict__ x, const float* __restrict__ kern,
    const __hip_bfloat16* __restrict__ wpF, const float* __restrict__ cb,
    __hip_bfloat16* __restrict__ buf)
{
    __shared__ __align__(16) char lA [6*18*128];   // 13824 B
    __shared__ __align__(16) char lD [64*128];     //  8192 B
    __shared__ __align__(16) char lA1[64*80];      //  5120 B (padded stride)
    __shared__ float kern_s[576];

    const int tid = threadIdx.x;
    const int wid = tid >> 6, lane = tid & 63;
    const int l15 = lane & 15, lg = lane >> 4;
    const int b = blockIdx.y;
    const int bx = xswz(blockIdx.x, gridDim.x);
    const int toh = (bx >> 4) * 4;
    const int tow = (bx & 15) * 16;
    const int row0 = toh - 1;
    const int col0 = tow - 1;

    // ---- stage x halo ---------------------------------------------------------
    const bool cfast = (tow >= 1) && (tow + 20 <= 256);
    for (int i = tid; i < 6*64; i += 256){
        const int ci = i & 63, r = i >> 6;
        const int ih = row0 + r;
        if (ih < 0 || ih >= 256){
            #pragma unroll
            for (int c = 0; c < 18; ++c)
                *(unsigned short*)(lA + ((r*18+c)*8 + ((ci>>3)^(c&7)))*16 + (ci&7)*2) = 0;
        } else {
            const float* srow = x + ((size_t)(b*64+ci) << 16) + ih*256;
            if (cfast){
                float edge = srow[tow-1];
                f32x4 chk[5];
                #pragma unroll
                for (int k = 0; k < 5; ++k)
                    chk[k] = *(const f32x4*)(srow + tow + k*4);
                *(unsigned short*)(lA + ((r*18+0)*8 + ((ci>>3)^0))*16 + (ci&7)*2) = bf_bits(edge);
                #pragma unroll
                for (int c = 1; c < 18; ++c){
                    const int idx = c - 1;
                    unsigned short bits = bf_bits(chk[idx>>2][idx&3]);
                    *(unsigned short*)(lA + ((r*18+c)*8 + ((ci>>3)^(c&7)))*16 + (ci&7)*2) = bits;
                }
            } else {
                #pragma unroll
                for (int c = 0; c < 18; ++c){
                    int iw = col0 + c;
                    unsigned short bits = 0;
                    if (iw >= 0 && iw < 256) bits = bf_bits(srow[iw]);
                    *(unsigned short*)(lA + ((r*18+c)*8 + ((ci>>3)^(c&7)))*16 + (ci&7)*2) = bits;
                }
            }
        }
    }
    for (int i = tid; i < 576; i += 256) kern_s[i] = kern[b*576 + i];
    __syncthreads();

    // ---- a1 GEMM (caw1 . X) ---------------------------------------------------
    const int m1 = wid & 1;
    const int nb = (wid >> 1) * 2;
    f32x4 a1acc[2] = {{0.f,0.f,0.f,0.f},{0.f,0.f,0.f,0.f}};
    const int coA1 = m1*16 + l15;
    #pragma unroll
    for (int ch = 0; ch < 2; ++ch){
        bf16x8 aA = *(const bf16x8*)(wpF + 4096 + ((ch*4+lg)*32 + coA1)*8);
        #pragma unroll
        for (int t = 0; t < 2; ++t){
            int n = nb + t;
            int cc = l15 + 1, rr = n + 1;
            bf16x8 bX = *(const bf16x8*)(lA + ((rr*18+cc)*8 + ((ch*4+lg) ^ (cc&7)))*16);
            a1acc[t] = __builtin_amdgcn_mfma_f32_16x16x32_bf16(aA, bX, a1acc[t], 0,0,0);
        }
    }

    // ---- depthwise via diagonal MFMA -----------------------------------------
    {
        const int ch_w = wid >> 1;
        const int lghit = ((wid & 1) << 1) | (l15 >> 3);
        const int ehit  = l15 & 7;
        const int ci_self = wid*16 + l15;
        const bool lact = (lg == lghit);
        f32x4 dwc[4] = {{0.f,0.f,0.f,0.f},{0.f,0.f,0.f,0.f},{0.f,0.f,0.f,0.f},{0.f,0.f,0.f,0.f}};
        #pragma unroll
        for (int kh = 0; kh < 3; ++kh){
            #pragma unroll
            for (int kw = 0; kw < 3; ++kw){
                unsigned short kv = lact ? bf_bits(kern_s[ci_self*9 + kh*3 + kw]) : (unsigned short)0;
                u16x8 au;
                #pragma unroll
                for (int e = 0; e < 8; ++e) au[e] = (e == ehit) ? kv : (unsigned short)0;
                bf16x8 adw; __builtin_memcpy(&adw, &au, 16);
                #pragma unroll
                for (int n = 0; n < 4; ++n){
                    const int rr = n + kh, cc = l15 + kw;
                    bf16x8 bX = *(const bf16x8*)(lA + ((rr*18+cc)*8 + ((ch_w*4+lg) ^ (cc&7)))*16);
                    dwc[n] = __builtin_amdgcn_mfma_f32_16x16x32_bf16(adw, bX, dwc[n], 0,0,0);
                }
            }
        }
        #pragma unroll
        for (int n = 0; n < 4; ++n){
            int px = n*16 + l15;
            #pragma unroll
            for (int r = 0; r < 4; ++r){
                int ci = wid*16 + lg*4 + r;
                *(unsigned short*)(lD + (px*8 + ((ci>>3) ^ (px&7)))*16 + (ci&7)*2)
                    = bf_bits(lrelu_f(dwc[n][r]));
            }
        }
    }

    // ---- a1 -> lrelu -> lA1 (padded 80B stride) ------------------------------
    #pragma unroll
    for (int t = 0; t < 2; ++t){
        int n = nb + t;
        int px = n*16 + l15;
        #pragma unroll
        for (int r = 0; r < 4; ++r){
            int j = m1*16 + lg*4 + r;
            *(unsigned short*)(lA1 + (px*5 + ((j>>3) ^ (px&3)))*16 + (j&7)*2)
                = bf_bits(lrelu_f(a1acc[t][r]));
        }
    }
    __syncthreads();

    // ---- dyn & att GEMMs ------------------------------------------------------
    f32x4 dynacc[4] = {{0.f,0.f,0.f,0.f},{0.f,0.f,0.f,0.f},{0.f,0.f,0.f,0.f},{0.f,0.f,0.f,0.f}};
    f32x4 attacc[4] = {{0.f,0.f,0.f,0.f},{0.f,0.f,0.f,0.f},{0.f,0.f,0.f,0.f},{0.f,0.f,0.f,0.f}};
    const int coA = wid*16 + l15;
    #pragma unroll
    for (int ch = 0; ch < 2; ++ch){
        bf16x8 aW = *(const bf16x8*)(wpF + ((ch*4+lg)*64 + coA)*8);
        #pragma unroll
        for (int n = 0; n < 4; ++n){
            int px = n*16 + l15;
            bf16x8 bD = *(const bf16x8*)(lD + (px*8 + ((ch*4+lg) ^ (px&7)))*16);
            dynacc[n] = __builtin_amdgcn_mfma_f32_16x16x32_bf16(aW, bD, dynacc[n], 0,0,0);
        }
    }
    {
        bf16x8 aW2 = *(const bf16x8*)(wpF + 6144 + (lg*64 + coA)*8);
        #pragma unroll
        for (int n = 0; n < 4; ++n){
            int px = n*16 + l15;
            bf16x8 bA1 = *(const bf16x8*)(lA1 + (px*5 + (lg ^ (px&3)))*16);
            attacc[n] = __builtin_amdgcn_mfma_f32_16x16x32_bf16(aW2, bA1, attacc[n], 0,0,0);
        }
    }

    // ---- epilogue: x from LDS (bf16) -----------------------------------------
    #pragma unroll
    for (int n = 0; n < 4; ++n){
        int oh = toh + n, ow = tow + l15;
        const int rr = n + 1, cc = l15 + 1;
        #pragma unroll
        for (int r = 0; r < 4; ++r){
            int co = wid*16 + lg*4 + r;
            size_t oi = ((size_t)(b*64+co) << 16) + oh*256 + ow;
            float xv = u16_to_f(*(const unsigned short*)(
                lA + ((rr*18+cc)*8 + ((co>>3) ^ (cc&7)))*16 + (co&7)*2));
            float att = fmaxf(attacc[n][r], 0.f);
            float v = lrelu_f(dynacc[n][r] + cb[co] + xv*att);
            buf[oi] = __float2bfloat16(v);
        }
    }
}

// ---------------- K5 v5: MFMA implicit-GEMM conv (TH param, XCD swizzle) ------
template<typename TIN, int STRIDE, int TH, int RESMODE, int ACT, int OUTBF>
__global__ __launch_bounds__(256) void k_conv_mfma(
    const TIN* __restrict__ in, const __hip_bfloat16* __restrict__ wp,
    const float* __restrict__ bias, const void* __restrict__ res,
    void* __restrict__ outp, int H, int W, int Ho, int Wo)
{
    constexpr int ROWS = (STRIDE==1) ? TH+2 : 2*TH+1;
    constexpr int COLS = (STRIDE==1) ? 18 : 33;
    constexpr int EPC  = (sizeof(TIN)==2) ? 8 : 4;
    constexpr int NCH  = (COLS - 1 + EPC - 1) / EPC;
    __shared__ __align__(16) char lA[ROWS*COLS*128];
    const int tid = threadIdx.x;
    const int wid = tid >> 6, lane = tid & 63;
    const int l15 = lane & 15, g = lane >> 4;
    const int b   = blockIdx.y;
    const int bx  = xswz(blockIdx.x, gridDim.x);
    const int tilesW = Wo >> 4;
    const int toh = (bx / tilesW) * TH;
    const int tow = (bx % tilesW) * 16;
    const int row0 = toh*STRIDE - 1;
    const int col0 = tow*STRIDE - 1;

    bf16x8 aw[18];
    const int coA = wid*16 + l15;
    #pragma unroll
    for (int f = 0; f < 18; ++f)
        aw[f] = *(const bf16x8*)(wp + ((f*4 + g)*64 + coA)*8);

    const int base = tow*STRIDE;
    const bool cfast = (base >= 1) && (base + NCH*EPC <= W);
    for (int i = tid; i < ROWS*64; i += 256){
        const int ci = i & 63, r = i >> 6;
        const int ih = row0 + r;
        if (ih < 0 || ih >= H){
            #pragma unroll
            for (int c = 0; c < COLS; ++c)
                *(unsigned short*)(lA + ((r*COLS+c)*8 + ((ci>>3)^(c&7)))*16 + (ci&7)*2) = 0;
        } else {
            const TIN* srow = in + ((size_t)(b*64+ci))*H*W + (size_t)ih*W;
            if (cfast){
                if constexpr (sizeof(TIN) == 2){
                    unsigned short edge = bf_bits(srow[base-1]);
                    u16x8 chk[NCH];
                    #pragma unroll
                    for (int k = 0; k < NCH; ++k)
                        chk[k] = *(const u16x8*)(srow + base + k*8);
                    *(unsigned short*)(lA + ((r*COLS+0)*8 + (ci>>3))*16 + (ci&7)*2) = edge;
                    #pragma unroll
                    for (int c = 1; c < COLS; ++c){
                        const int idx = c - 1;
                        unsigned short bits = chk[idx>>3][idx&7];
                        *(unsigned short*)(lA + ((r*COLS+c)*8 + ((ci>>3)^(c&7)))*16 + (ci&7)*2) = bits;
                    }
                } else {
                    unsigned short edge = bf_bits(srow[base-1]);
                    f32x4 chk[NCH];
                    #pragma unroll
                    for (int k = 0; k < NCH; ++k)
                        chk[k] = *(const f32x4*)(srow + base + k*4);
                    *(unsigned short*)(lA + ((r*COLS+0)*8 + (ci>>3))*16 + (ci&7)*2) = edge;
                    #pragma unroll
                    for (int c = 1; c < COLS; ++c){
                        const int idx = c - 1;
                        unsigned short bits = bf_bits(chk[idx>>2][idx&3]);
                        *(unsigned short*)(lA + ((r*COLS+c)*8 + ((ci>>3)^(c&7)))*16 + (ci&7)*2) = bits;
                    }
                }
            } else {
                #pragma unroll
                for (int c = 0; c < COLS; ++c){
                    int iw = col0 + c;
                    unsigned short bits = 0;
                    if (iw >= 0 && iw < W) bits = bf_bits(srow[iw]);
                    *(unsigned short*)(lA + ((r*COLS+c)*8 + ((ci>>3)^(c&7)))*16 + (ci&7)*2) = bits;
                }
            }
        }
    }
    __syncthreads();

    float bv[4];
    #pragma unroll
    for (int r = 0; r < 4; ++r) bv[r] = bias[wid*16 + g*4 + r];
    const float*          resF = (const float*)res;
    const __hip_bfloat16* resB = (const __hip_bfloat16*)res;

    if constexpr (STRIDE == 1){
        bf16x8 Bw[3][2][3];
        auto ldrow = [&](int rr, int slot){
            #pragma unroll
            for (int ch = 0; ch < 2; ++ch)
                #pragma unroll
                for (int kw = 0; kw < 3; ++kw){
                    const int cc = l15 + kw;
                    Bw[slot][ch][kw] = *(const bf16x8*)(lA + ((rr*COLS + cc)*8 + ((ch*4+g) ^ (cc&7)))*16);
                }
        };
        ldrow(0, 0);
        ldrow(1, 1);
        #pragma unroll
        for (int n = 0; n < TH; ++n){
            ldrow(n+2, (n+2)%3);
            f32x4 acc = {0.f,0.f,0.f,0.f};
            #pragma unroll
            for (int kh = 0; kh < 3; ++kh)
                #pragma unroll
                for (int ch = 0; ch < 2; ++ch)
                    #pragma unroll
                    for (int kw = 0; kw < 3; ++kw)
                        acc = __builtin_amdgcn_mfma_f32_16x16x32_bf16(
                                aw[ch*9 + kh*3 + kw], Bw[(n+kh)%3][ch][kw], acc, 0, 0, 0);
            const int oh = toh + n, ow = tow + l15;
            #pragma unroll
            for (int r = 0; r < 4; ++r){
                int co = wid*16 + g*4 + r;
                size_t oi = ((size_t)(b*64+co)*Ho + oh)*Wo + ow;
                float v = acc[r] + bv[r];
                if (ACT) v = fmaxf(v, 0.f);
                if (RESMODE == 1) v += resF[oi];
                if (RESMODE == 2) v += __bfloat162float(resB[oi]);
                if (OUTBF) ((__hip_bfloat16*)outp)[oi] = __float2bfloat16(v);
                else       ((float*)outp)[oi] = v;
            }
        }
    } else {
        #pragma unroll
        for (int n = 0; n < TH; ++n){
            f32x4 acc = {0.f,0.f,0.f,0.f};
            #pragma unroll
            for (int ch = 0; ch < 2; ++ch)
                #pragma unroll
                for (int pos = 0; pos < 9; ++pos){
                    const int kh = pos/3, kw = pos - 3*(pos/3);
                    const int cc = l15*STRIDE + kw;
                    const int rr = n*STRIDE + kh;
                    bf16x8 bx2 = *(const bf16x8*)(lA + ((rr*COLS + cc)*8 + ((ch*4+g) ^ (cc&7)))*16);
                    acc = __builtin_amdgcn_mfma_f32_16x16x32_bf16(aw[ch*9+pos], bx2, acc, 0, 0, 0);
                }
            const int oh = toh + n, ow = tow + l15;
            #pragma unroll
            for (int r = 0; r < 4; ++r){
                int co = wid*16 + g*4 + r;
                size_t oi = ((size_t)(b*64+co)*Ho + oh)*Wo + ow;
                float v = acc[r] + bv[r];
                if (ACT) v = fmaxf(v, 0.f);
                if (RESMODE == 1) v += resF[oi];
                if (RESMODE == 2) v += __bfloat162float(resB[oi]);
                if (OUTBF) ((__hip_bfloat16*)outp)[oi] = __float2bfloat16(v);
                else       ((float*)outp)[oi] = v;
            }
        }
    }
}

// ---------------- host ---------------------------------------------------------
extern "C" void kernel_launch(void* const* d_in, const int* in_sizes, int n_in,
                              void* d_out, int out_size, void* d_ws, size_t ws_size,
                              hipStream_t stream) {
    const float* x    = (const float*)d_in[0];
    const float* y    = (const float*)d_in[1];
    const float* ew1  = (const float*)d_in[2];
    const float* eb1  = (const float*)d_in[3];
    const float* bn1g = (const float*)d_in[4];
    const float* bn1b = (const float*)d_in[5];
    const float* bn1m = (const float*)d_in[6];
    const float* bn1v = (const float*)d_in[7];
    const float* ew2  = (const float*)d_in[8];
    const float* eb2  = (const float*)d_in[9];
    const float* bn2g = (const float*)d_in[10];
    const float* bn2b = (const float*)d_in[11];
    const float* bn2m = (const float*)d_in[12];
    const float* bn2v = (const float*)d_in[13];
    const float* mw1  = (const float*)d_in[14];
    const float* mb1  = (const float*)d_in[15];
    const float* mw2  = (const float*)d_in[16];
    const float* mb2  = (const float*)d_in[17];
    const float* kw1  = (const float*)d_in[18];
    const float* kw2  = (const float*)d_in[19];
    const float* cw   = (const float*)d_in[20];
    const float* cb   = (const float*)d_in[21];
    const float* caw1 = (const float*)d_in[22];
    const float* caw2 = (const float*)d_in[23];
    const float* c1w  = (const float*)d_in[24];
    const float* c1b  = (const float*)d_in[25];
    const float* c2w  = (const float*)d_in[26];
    const float* c2b  = (const float*)d_in[27];
    const float* r1w  = (const float*)d_in[28];
    const float* r1b  = (const float*)d_in[29];
    const float* r2w  = (const float*)d_in[30];
    const float* r2b  = (const float*)d_in[31];

    char* wsc = (char*)d_ws;
    __hip_bfloat16* buf = (__hip_bfloat16*)wsc;
    __hip_bfloat16* e1b = (__hip_bfloat16*)wsc;
    __hip_bfloat16* wp2 = (__hip_bfloat16*)(wsc + 2097152);
    float*          part= (float*)(wsc + 2686976);
    __hip_bfloat16* t2  = (__hip_bfloat16*)wsc;
    __hip_bfloat16* u2  = (__hip_bfloat16*)(wsc + 8388608);
    __hip_bfloat16* t3  = (__hip_bfloat16*)(wsc + 16777216);
    __hip_bfloat16* u3  = (__hip_bfloat16*)(wsc + 18874368);
    __hip_bfloat16* wpB = (__hip_bfloat16*)(wsc + 29360128);
    __hip_bfloat16* wpB0= wpB;
    __hip_bfloat16* wpB1= wpB + 36864;
    __hip_bfloat16* wpB2= wpB + 73728;
    float*          kern= (float*)(wsc + 33558528);

    float* ob   = (float*)d_out;            // out  (4,64,256,256) f32
    float* ob1  = ob + 16777216;            // out2 (4,64,128,128) f32
    float* ob2  = ob + 20971520;            // out3 (4,64,64,64)   f32
    __hip_bfloat16* wpF = (__hip_bfloat16*)((char*)d_out + 83886080);
    __hip_bfloat16* wp1 = (__hip_bfloat16*)((char*)d_out + 84934656);
    __hip_bfloat16* wpA = (__hip_bfloat16*)((char*)d_out + 87932928);

    k_prep_all<<<dim3(1616),256,0,stream>>>(c1w, ew1, bn1g, bn1v, ew2, bn2g, bn2v,
                                            cw, caw1, caw2, wpA, wp1, wp2, wpF);
    k_enc1m<<<dim3(16,4),256,0,stream>>>(y, wp1, eb1, bn1g, bn1b, bn1m, bn1v, e1b);
    k_enc2m<<<dim3(16,4),256,0,stream>>>(e1b, wp2, eb2, bn2g, bn2b, bn2m, bn2v, part);
    k_mlp<<<dim3(4),256,0,stream>>>(part, mw1, mb1, mw2, mb2, kw1, kw2, kern);
    k_fuse<<<dim3(1024,4),256,0,stream>>>(x, kern, wpF, cb, buf);

    // out0 = conv3x3(pre) + bias + x  -> f32 d_out  (TH=4: 64x16 tiles)
    k_conv_mfma<__hip_bfloat16,1,4,1,0,0><<<dim3(1024,4),256,0,stream>>>(buf, wpA, c1b, x, ob, 256,256,256,256);
    k_wprepB<<<dim3(432),256,0,stream>>>(c2w, r1w, r2w, wpB);
    // t2 = conv3x3 s2 (out0 f32) -> bf16            (TH=2: 64x8 tiles)
    k_conv_mfma<float,2,2,0,0,1><<<dim3(512,4),256,0,stream>>>(ob, wpB0, c2b, nullptr, t2, 256,256,128,128);
    // u2 = relu(conv3x3(t2)) -> bf16                (TH=4: 32x8 tiles)
    k_conv_mfma<__hip_bfloat16,1,4,0,1,1><<<dim3(256,4),256,0,stream>>>(t2, wpB1, r1b, nullptr, u2, 128,128,128,128);
    // out2 = t2 + conv3x3(u2) -> f32 d_out
    k_conv_mfma<__hip_bfloat16,1,4,2,0,0><<<dim3(256,4),256,0,stream>>>(u2, wpB2, r2b, t2, ob1, 128,128,128,128);
    // t3 = conv3x3 s2 (out2 f32) -> bf16            (TH=2: 32x4 tiles)
    k_conv_mfma<float,2,2,0,0,1><<<dim3(128,4),256,0,stream>>>(ob1, wpB0, c2b, nullptr, t3, 128,128,64,64);
    // u3 = relu(conv3x3(t3)) -> bf16                (TH=4: 16x4 tiles)
    k_conv_mfma<__hip_bfloat16,1,4,0,1,1><<<dim3(64,4),256,0,stream>>>(t3, wpB1, r1b, nullptr, u3, 64,64,64,64);
    // out3 = t3 + conv3x3(u3) -> f32 d_out
    k_conv_mfma<__hip_bfloat16,1,4,2,0,0><<<dim3(64,4),256,0,stream>>>(u3, wpB2, r2b, t3, ob2, 64,64,64,64);
}